// Round 3
// baseline (332.120 us; speedup 1.0000x reference)
//
#include <hip/hip_runtime.h>
#include <hip/hip_bf16.h>

typedef __hip_bfloat16 bf16;
typedef __attribute__((ext_vector_type(8))) short short8;
typedef __attribute__((ext_vector_type(4))) float f32x4;
typedef float f32x4u __attribute__((ext_vector_type(4), aligned(4)));
typedef unsigned short ushort_t;

#define PI_F 3.14159265358979323846f
#define GPAD_Z 3111696L  // 1764*1764

#define GLOAD_LDS16(gp, lp)                                                    \
  __builtin_amdgcn_global_load_lds(                                            \
      (const __attribute__((address_space(1))) unsigned int*)(gp),             \
      (__attribute__((address_space(3))) unsigned int*)(lp), 16, 0, 0)

// ---------------------------------------------------------------------------
// K1: downsample (::2,::2) + transpose to [slice][q][384] bf16 with the
// three-term double-bf16 layout:
//   A-side (PTe): [hi | lo | hi],  B-side (MTe): [hi | hi | lo]
// so dot_{k<384} = hiA·hiB + loA·hiB + hiA·loB  (only loA·loB ~2^-18 dropped).
// Also per-pixel squared channel norms SQ[z][q] (fp32) for left/right.
// ---------------------------------------------------------------------------
__global__ __launch_bounds__(128) void prep_pt(const float* __restrict__ left,
                                               const float* __restrict__ right,
                                               const float* __restrict__ mid,
                                               bf16* __restrict__ PTe,
                                               bf16* __restrict__ MTe,
                                               float* __restrict__ SQ) {
  int q = blockIdx.x;          // 0..1599
  int y = blockIdx.y;          // 0..5
  int c = threadIdx.x;         // 0..127
  int qi = q / 40, qj = q - qi * 40;
  const float* src;
  bf16* dst;
  int b;
  bool aside = (y < 4);
  if (aside) {
    b = y & 1;
    src = (y < 2) ? left : right;
    dst = PTe + (long)y * 1664 * 384;
  } else {
    b = y - 4;
    src = mid;
    dst = MTe + (long)(y - 4) * 1664 * 384;
  }
  float v = src[(((long)b * 128 + c) * 80 + 2 * qi) * 80 + 2 * qj];
  bf16 hi = __float2bfloat16(v);
  bf16 lo = __float2bfloat16(v - __bfloat162float(hi));
  if (aside) {
    dst[(long)q * 384 + c] = hi;
    dst[(long)q * 384 + 128 + c] = lo;
    dst[(long)q * 384 + 256 + c] = hi;
  } else {
    dst[(long)q * 384 + c] = hi;
    dst[(long)q * 384 + 128 + c] = hi;
    dst[(long)q * 384 + 256 + c] = lo;
  }
  if (aside) {
    __shared__ float red[128];
    red[c] = v * v;
    __syncthreads();
    for (int s = 64; s > 0; s >>= 1) {
      if (c < s) red[c] += red[c + s];
      __syncthreads();
    }
    if (c == 0) SQ[y * 1600 + q] = red[0];
  }
}

// ---------------------------------------------------------------------------
// K2: invN[z][q] = rsqrt( 3x3 box of SQ (zero-padded) + 1152*EPS )
// ---------------------------------------------------------------------------
__global__ void invn_kernel(const float* __restrict__ SQ, float* __restrict__ INV) {
  int idx = blockIdx.x * 256 + threadIdx.x;
  if (idx >= 6400) return;
  int z = idx / 1600, q = idx - z * 1600;
  int qi = q / 40, qj = q - qi * 40;
  float s = 0.1152f;  // 128*3*3 * 1e-4
  #pragma unroll
  for (int di = -1; di <= 1; ++di)
    #pragma unroll
    for (int dj = -1; dj <= 1; ++dj) {
      int a = qi + di, b = qj + dj;
      if (a >= 0 && a < 40 && b >= 0 && b < 40) s += SQ[z * 1600 + a * 40 + b];
    }
  INV[idx] = rsqrtf(s);
}

// ---------------------------------------------------------------------------
// K2b: zero only the pad cells of Gpad ([42,42,42,42] layout, 1764x1764/z)
// ---------------------------------------------------------------------------
__global__ __launch_bounds__(256) void padzero_kernel(float* __restrict__ Gp) {
  int row = blockIdx.x;   // 0..1763
  int z = blockIdx.y;     // 0..3
  float* R = Gp + (long)z * GPAD_Z + (long)row * 1764;
  int r42 = row % 42;
  if (r42 == 0 || r42 == 41) {
    for (int c = threadIdx.x; c < 1764; c += 256) R[c] = 0.f;
  } else {
    for (int i = threadIdx.x; i < 84; i += 256) {
      int c = (i >> 1) * 42 + ((i & 1) ? 41 : 0);
      R[c] = 0.f;
    }
  }
}

// ---------------------------------------------------------------------------
// K3: bf16 MFMA GEMM (m97 structure, BK=32) — Gram GEMM only (K=384, cpad).
// ---------------------------------------------------------------------------
__global__ __launch_bounds__(256) void gemm_nt(const bf16* __restrict__ A,
                                               const bf16* __restrict__ B,
                                               float* __restrict__ C,
                                               int M, int N, int K,
                                               long Az, long Bz, long Cz,
                                               int bmod, int cpad) {
  int z = blockIdx.z;
  A += (long)z * Az;
  B += (long)(bmod ? (z & 1) : z) * Bz;
  C += (long)z * Cz;
  __shared__ bf16 As[128 * 32];  // row-major [row][32], 64 B rows, 8 KB
  __shared__ bf16 Bs[128 * 32];
  int lane = threadIdx.x & 63;
  int w = threadIdx.x >> 6;
  int mb = blockIdx.x * 128;
  int nb = blockIdx.y * 128;
  int lr = lane >> 2;
  int gb = (lane & 3) ^ ((lane >> 3) & 3);  // XOR swizzle at stage time
  int lm = lane & 15;
  int swz = (lm >> 1) & 3;
  int kb = lane >> 4;                  // 0..3 (k block of 8)
  int pos = (kb ^ swz) * 8;            // mirrored swizzle at read time
  int warow = (w >> 1) * 64;
  int wbrow = (w & 1) * 64;
  f32x4 acc[4][4];
  #pragma unroll
  for (int i = 0; i < 4; ++i)
    #pragma unroll
    for (int j = 0; j < 4; ++j) {
      f32x4 zv = {0.f, 0.f, 0.f, 0.f};
      acc[i][j] = zv;
    }
  for (int k0 = 0; k0 < K; k0 += 32) {
    __syncthreads();
    #pragma unroll
    for (int t = 0; t < 2; ++t) {
      int r = (w * 2 + t) * 16 + lr;   // 0..127
      GLOAD_LDS16(A + (long)(mb + r) * K + k0 + gb * 8, As + (w * 2 + t) * 512);
      GLOAD_LDS16(B + (long)(nb + r) * K + k0 + gb * 8, Bs + (w * 2 + t) * 512);
    }
    __syncthreads();
    short8 af[4], bfr[4];
    #pragma unroll
    for (int i = 0; i < 4; ++i) {
      af[i]  = *reinterpret_cast<const short8*>(As + (warow + i * 16 + lm) * 32 + pos);
      bfr[i] = *reinterpret_cast<const short8*>(Bs + (wbrow + i * 16 + lm) * 32 + pos);
    }
    #pragma unroll
    for (int i = 0; i < 4; ++i)
      #pragma unroll
      for (int j = 0; j < 4; ++j)
        acc[i][j] = __builtin_amdgcn_mfma_f32_16x16x32_bf16(af[i], bfr[j], acc[i][j], 0, 0, 0);
  }
  int m0 = mb + warow;
  int n0 = nb + wbrow;
  int col = lane & 15;
  int r0 = (lane >> 4) * 4;
  #pragma unroll
  for (int i = 0; i < 4; ++i)
    #pragma unroll
    for (int j = 0; j < 4; ++j) {
      int n = n0 + j * 16 + col;
      if (n < N) {
        int nc = cpad ? ((n / 40) * 42 + (n - (n / 40) * 40) + 43) : n;
        #pragma unroll
        for (int r = 0; r < 4; ++r) {
          int m = m0 + i * 16 + r0 + r;
          if (m < M) {
            long mr = cpad ? ((long)((m / 40) * 42 + (m - (m / 40) * 40) + 43) * 1764)
                           : ((long)m * N);
            C[mr + nc] = acc[i][j][r];
          }
        }
      }
    }
}

// ---------------------------------------------------------------------------
// K9: 256x256 8-phase bf16 GEMM (T2 st_16x32 swizzle + T3/T4 counted
// vmcnt(6) + T5 setprio). Verified round 1. Deconv GEMM. Unchanged.
// ---------------------------------------------------------------------------
#define BAR() __builtin_amdgcn_s_barrier()
#define LGKM0() asm volatile("s_waitcnt lgkmcnt(0)" ::: "memory")
#define STAGE_A(tt, h)                                                         \
  { long _k = (long)(tt) * 64;                                                 \
    char* _d = lds + (((tt) & 1) << 16) + (((h) * 8 + w) << 11);               \
    GLOAD_LDS16(a_row[h] + _k, _d);                                            \
    GLOAD_LDS16(a_row[h] + _k + 32, _d + 1024); }
#define STAGE_B(tt, h)                                                         \
  { long _k = (long)(tt) * 64;                                                 \
    char* _d = lds + (((tt) & 1) << 16) + 32768 + (((h) * 8 + w) << 11);       \
    GLOAD_LDS16(b_row[h] + _k, _d);                                            \
    GLOAD_LDS16(b_row[h] + _k + 32, _d + 1024); }
#define LD8(off) (*reinterpret_cast<const short8*>(lds + (off)))
#define LOAD_A(bufo, mh)                                                       \
  { _Pragma("unroll") for (int i = 0; i < 4; ++i)                              \
      { _Pragma("unroll") for (int kc = 0; kc < 2; ++kc)                       \
          a[i][kc] = LD8((bufo) + (((wm * 8 + (mh) * 4 + i) * 2 + kc) << 10) + rd_off); } }
#define LOAD_B(dst, bufo, nh)                                                  \
  { _Pragma("unroll") for (int j = 0; j < 2; ++j)                              \
      { _Pragma("unroll") for (int kc = 0; kc < 2; ++kc)                       \
          dst[j][kc] = LD8((bufo) + 32768 + (((wn * 4 + (nh) * 2 + j) * 2 + kc) << 10) + rd_off); } }
#define MFMA16(mh, nh, bset)                                                   \
  { _Pragma("unroll") for (int kc = 0; kc < 2; ++kc)                           \
      { _Pragma("unroll") for (int i = 0; i < 4; ++i)                          \
          { _Pragma("unroll") for (int j = 0; j < 2; ++j)                      \
              acc[(mh) * 4 + i][(nh) * 2 + j] = __builtin_amdgcn_mfma_f32_16x16x32_bf16( \
                  a[i][kc], bset[j][kc], acc[(mh) * 4 + i][(nh) * 2 + j], 0, 0, 0); } } }

__global__ __launch_bounds__(512, 2) void gemm256_nt(const bf16* __restrict__ A,
                                                     const bf16* __restrict__ B,
                                                     float* __restrict__ C,
                                                     int M, int N, int K,
                                                     long Az, long Bz, long Cz,
                                                     int nballoc) {
  __shared__ __align__(16) char lds[131072];  // [buf2][op2][32 subtiles x 1024B]
  int z = blockIdx.z;
  A += (long)z * Az;
  B += (long)z * Bz;
  C += (long)z * Cz;
  int tid = threadIdx.x;
  int lane = tid & 63;
  int w = tid >> 6;          // wave 0..7
  int wm = w >> 2;           // 0..1 (M half)
  int wn = w & 3;            // 0..3 (N quarter)
  int mb = blockIdx.x * 256;
  int nb = blockIdx.y * 256;
  int NT = K >> 6;

  // stage: LDS dest linear (base + lane*16); global source inverse-swizzled
  int srcb = (lane << 4) ^ (lane & 32);  // byte in 1024B subtile
  int r_src = srcb >> 6;                 // 0..15
  int c_src = (srcb & 63) >> 1;          // element 0..31 (x8 granules)
  const bf16* a_row[2];
  const bf16* b_row[2];
  #pragma unroll
  for (int h = 0; h < 2; ++h) {
    a_row[h] = A + (long)(mb + (h * 8 + w) * 16 + r_src) * K + c_src;
    int br = nb + (h * 8 + w) * 16 + r_src;
    if (br > nballoc - 1) br = nballoc - 1;  // N-tail: clamp inside allocation
    b_row[h] = B + (long)br * K + c_src;
  }
  // read: swizzled byte offset within subtile (4-way after st_16x32)
  int rd_off = (((lane & 15) << 6) | ((lane >> 4) << 4)) ^ ((lane & 8) << 2);

  short8 a[4][2], p0[2][2], p1[2][2];
  f32x4 acc[8][4];
  #pragma unroll
  for (int i = 0; i < 8; ++i)
    #pragma unroll
    for (int j = 0; j < 4; ++j) {
      f32x4 zv = {0.f, 0.f, 0.f, 0.f};
      acc[i][j] = zv;
    }

  // prologue: tile0 fully + tile1 {A0,A1,B0}; wait tile0 (3 half-tiles in flight)
  STAGE_A(0, 0); STAGE_A(0, 1); STAGE_B(0, 0); STAGE_B(0, 1);
  STAGE_A(1, 0); STAGE_A(1, 1); STAGE_B(1, 0);
  asm volatile("s_waitcnt vmcnt(6)" ::: "memory");
  BAR();

  for (int t = 0; t < NT; ++t) {
    int bufo = (t & 1) << 16;
    // phase 0: quadrant (m0,n0); stage B1 of t+1
    LOAD_A(bufo, 0);
    LOAD_B(p0, bufo, 0);
    if (t + 1 < NT) STAGE_B(t + 1, 1);
    BAR(); LGKM0();
    __builtin_amdgcn_s_setprio(1); MFMA16(0, 0, p0); __builtin_amdgcn_s_setprio(0);
    BAR();
    // phase 1: quadrant (m0,n1); A reused
    LOAD_B(p1, bufo, 1);
    BAR(); LGKM0();
    __builtin_amdgcn_s_setprio(1); MFMA16(0, 1, p1); __builtin_amdgcn_s_setprio(0);
    BAR();
    // phase 2: quadrant (m1,n1); B reused
    LOAD_A(bufo, 1);
    BAR(); LGKM0();
    __builtin_amdgcn_s_setprio(1); MFMA16(1, 1, p1); __builtin_amdgcn_s_setprio(0);
    BAR();
    // phase 3: quadrant (m1,n0)
    LOAD_B(p0, bufo, 0);
    BAR(); LGKM0();
    __builtin_amdgcn_s_setprio(1); MFMA16(1, 0, p0); __builtin_amdgcn_s_setprio(0);
    BAR();
    // boundary: stage t+2 {A0,A1,B0}, counted vmcnt(6)
    if (t + 2 < NT) {
      STAGE_A(t + 2, 0); STAGE_A(t + 2, 1); STAGE_B(t + 2, 0);
      asm volatile("s_waitcnt vmcnt(6)" ::: "memory");
      BAR();
    } else if (t + 1 < NT) {
      asm volatile("s_waitcnt vmcnt(0)" ::: "memory");  // one drain, last prefetch
      BAR();
    }
  }

  // epilogue: C/D frag = {col=lane&15, row=(lane>>4)*4+r}
  int col = lane & 15;
  int r0 = (lane >> 4) * 4;
  int m_base = mb + wm * 128;
  int n_base = nb + wn * 64;
  #pragma unroll
  for (int i = 0; i < 8; ++i)
    #pragma unroll
    for (int j = 0; j < 4; ++j) {
      int n = n_base + j * 16 + col;
      if (n < N) {
        #pragma unroll
        for (int r = 0; r < 4; ++r) {
          int m = m_base + i * 16 + r0 + r;
          C[(long)m * N + n] = acc[i][j][r];
        }
      }
    }
}

// ---------------------------------------------------------------------------
// helper: 9-tap diagonal patch sum at (q2,p2) in padded Gz (pads give zeros)
// ---------------------------------------------------------------------------
__device__ __forceinline__ float ps9(const float* __restrict__ Gz, int q2, int p2) {
  int qi2 = q2 / 40, qj2 = q2 - qi2 * 40;
  int pi2 = p2 / 40, pj2 = p2 - pi2 * 40;
  const float* base = Gz + (long)(qi2 * 42 + qj2 + 43) * 1764 + (pi2 * 42 + pj2 + 43);
  float t = 0.f;
  #pragma unroll
  for (int di = -1; di <= 1; ++di)
    #pragma unroll
    for (int dj = -1; dj <= 1; ++dj)
      t += base[(long)(di * 42 + dj) * 1765];
  return t;
}

// ---------------------------------------------------------------------------
// K4+K5 merged, v3: 8 outputs/thread (2 quads) + z-chunked XCD mapping so
// each XCD streams ONE z's ~2.5 MB Gpad row-band through its private L2.
// Same interior identity as v2: tap(d,di,dj) at offset (42di + (d+dj))*1765;
// colsum over di per diagonal shift s=d+dj (5 shifts x 2 f32x4 x 3 rows =
// 30 loads per 8 outputs), sliding 3-sums -> PS_d, out = sum_d INV[q+d]*PS_d.
// Crossing patches: (t=0,d=-1) iff pj0==0 -> psm_lo[0]; (t=7,d=+1) iff
// pj0==32 -> psp_hi[3]; both wholesale ps9 replacements (pads give zeros for
// the misread lanes, patch overwrites). Slow path for qj in {0,39}.
// Grid: 5000 1-D blocks; chunk c=b&7 -> (z=c>>1, q-half=c&1); HW assigns
// XCD = b%8 so chunk==XCD; s=b>>3 ascending q within the band.
// ---------------------------------------------------------------------------
__global__ __launch_bounds__(256) void s1fuse1_kernel(const float* __restrict__ Gp,
                                                      const float* __restrict__ INV,
                                                      float* __restrict__ S2) {
  int b = blockIdx.x;              // 0..4999
  int c = b & 7;                   // chunk == XCD
  int s = b >> 3;                  // 0..624
  int z = c >> 1;
  int qh = c & 1;
  unsigned int gid = (unsigned int)s * 256u + threadIdx.x;  // 0..159999
  int qr = gid / 200u;             // 0..799
  int g = gid - qr * 200u;         // 0..199
  int q = qh * 800 + qr;
  int p0 = g * 8;
  int qi = q / 40, qj = q - qi * 40;
  int pi = p0 / 40, pj0 = p0 - pi * 40;   // in {0,8,16,24,32}
  const float* Gz = Gp + (long)z * GPAD_Z;
  const float* IVz = INV + z * 1600;
  float* Srow = S2 + ((long)z * 1600 + q) * 1600 + p0;

  if (qj >= 1 && qj <= 38) {
    long base = (long)(qi * 42 + qj + 43) * 1764 + (pi * 42 + pj0 + 43);
    f32x4 psm_lo = {0.f,0.f,0.f,0.f}, psm_hi = {0.f,0.f,0.f,0.f};
    f32x4 ps0_lo = {0.f,0.f,0.f,0.f}, ps0_hi = {0.f,0.f,0.f,0.f};
    f32x4 psp_lo = {0.f,0.f,0.f,0.f}, psp_hi = {0.f,0.f,0.f,0.f};
    #pragma unroll
    for (int ss = 0; ss < 5; ++ss) {
      const float* pb = Gz + base + (long)(ss - 2) * 1765;
      f32x4 l0 = *(const f32x4u*)(pb - 42 * 1765);
      f32x4 l1 = *(const f32x4u*)(pb);
      f32x4 l2 = *(const f32x4u*)(pb + 42 * 1765);
      f32x4 h0 = *(const f32x4u*)(pb - 42 * 1765 + 4);
      f32x4 h1 = *(const f32x4u*)(pb + 4);
      f32x4 h2 = *(const f32x4u*)(pb + 42 * 1765 + 4);
      f32x4 cl = l0 + l1 + l2;
      f32x4 ch = h0 + h1 + h2;
      if (ss <= 2) { psm_lo += cl; psm_hi += ch; }
      if (ss >= 1 && ss <= 3) { ps0_lo += cl; ps0_hi += ch; }
      if (ss >= 2) { psp_lo += cl; psp_hi += ch; }
    }
    if (pj0 == 0) {            // crossing (t=0, d=-1): linear p wraps pi-row
      int p2 = p0 - 1;
      psm_lo[0] = (p2 >= 0) ? ps9(Gz, q - 1, p2) : 0.f;
    } else if (pj0 == 32) {    // crossing (t=7, d=+1)
      int p2 = p0 + 8;
      psp_hi[3] = (p2 < 1600) ? ps9(Gz, q + 1, p2) : 0.f;
    }
    float wm = IVz[q - 1], w0 = IVz[q], wp = IVz[q + 1];
    f32x4 out_lo = psm_lo * wm + ps0_lo * w0 + psp_lo * wp;
    f32x4 out_hi = psm_hi * wm + ps0_hi * w0 + psp_hi * wp;
    *reinterpret_cast<f32x4*>(Srow) = out_lo;
    *reinterpret_cast<f32x4*>(Srow + 4) = out_hi;
  } else {
    // slow path (qj in {0,39}; 5% of threads, q-contiguous waves)
    f32x4 out_lo, out_hi;
    #pragma unroll
    for (int t = 0; t < 8; ++t) {
      int p = p0 + t;
      float sacc = 0.f;
      #pragma unroll
      for (int d = -1; d <= 1; ++d) {
        int q2 = q + d, p2 = p + d;
        bool ok = ((unsigned)q2 < 1600u) && ((unsigned)p2 < 1600u);
        if (ok) sacc += IVz[q2] * ps9(Gz, q2, p2);
      }
      if (t < 4) out_lo[t] = sacc; else out_hi[t - 4] = sacc;
    }
    *reinterpret_cast<f32x4*>(Srow) = out_lo;
    *reinterpret_cast<f32x4*>(Srow + 4) = out_hi;
  }
}

// ---------------------------------------------------------------------------
// K6 v2: fuse pass 2, quad-vectorized (unchanged from round 2).
// ---------------------------------------------------------------------------
__global__ __launch_bounds__(256) void fuse2_kernel(const float* __restrict__ S2,
                                                    float* __restrict__ S3) {
  int z = blockIdx.y;
  int bx = blockIdx.x;
  int xc = bx & 7, rest = bx >> 3;
  int lid = (xc < 4 ? xc * 313 : 1252 + (xc - 4) * 312) + rest;
  unsigned int gid = (unsigned int)lid * 256u + threadIdx.x;
  int q = gid / 400u;
  int quad = gid - q * 400u;
  int p0 = quad * 4;
  const float* S = S2 + (long)z * 2560000;
  int il = q / 40, jl = q - il * 40;
  int im = p0 / 40, jm = p0 - im * 40;
  int u = jl * 40 + il;
  f32x4 acc = {0.f, 0.f, 0.f, 0.f};
  #pragma unroll
  for (int d = -1; d <= 1; ++d) {
    int u2 = u + d;
    if ((unsigned)u2 >= 1600u) continue;
    int q2 = (u2 % 40) * 40 + u2 / 40;
    int imd = im + d;
    if ((unsigned)imd < 40u) {
      acc += *reinterpret_cast<const f32x4*>(S + (long)q2 * 1600 + imd * 40 + jm);
    } else {
      #pragma unroll
      for (int t = 0; t < 4; ++t) {
        int v2 = (jm + t) * 40 + im + d;
        if ((unsigned)v2 < 1600u) {
          int p2 = (v2 % 40) * 40 + v2 / 40;
          acc[t] += S[(long)q2 * 1600 + p2];
        }
      }
    }
  }
  *reinterpret_cast<f32x4*>(S3 + ((long)z * 1600 + q) * 1600 + p0) = acc;
}

// ---------------------------------------------------------------------------
// K7a: softmax partials over q-chunks of 200, per (z,p)
// ---------------------------------------------------------------------------
__global__ __launch_bounds__(256) void smax_part(const float* __restrict__ S3,
                                                 float* __restrict__ Pm,
                                                 float* __restrict__ Ps) {
  int z = blockIdx.z, qc = blockIdx.y;
  int pl = threadIdx.x & 63;
  int ql = threadIdx.x >> 6;
  int p = blockIdx.x * 64 + pl;
  const float* S = S3 + (long)z * 2560000;
  float m = -1e30f, s = 0.f;
  for (int i = 0; i < 50; ++i) {
    int q = qc * 200 + i * 4 + ql;
    float x = 10.f * S[(long)q * 1600 + p];
    if (x > m) { s *= __expf(m - x); m = x; }
    s += __expf(x - m);
  }
  __shared__ float lm[4][64], ls[4][64];
  lm[ql][pl] = m;
  ls[ql][pl] = s;
  __syncthreads();
  if (ql == 0) {
    float M = m, SS = s;
    #pragma unroll
    for (int j = 1; j < 4; ++j) {
      float mj = lm[j][pl], sj = ls[j][pl];
      if (mj > M) { SS = SS * __expf(M - mj) + sj; M = mj; }
      else SS += sj * __expf(mj - M);
    }
    Pm[((long)z * 8 + qc) * 1600 + p] = M;
    Ps[((long)z * 8 + qc) * 1600 + p] = SS;
  }
}

// ---------------------------------------------------------------------------
// K7b: combine partials (folded, per p) -> normalize S3 -> bf16 ->
// LDS-transpose -> AT[p][q]
// ---------------------------------------------------------------------------
__global__ __launch_bounds__(256) void smax_write(const float* __restrict__ S3,
                                                  const float* __restrict__ Pm,
                                                  const float* __restrict__ Ps,
                                                  bf16* __restrict__ AT) {
  int z = blockIdx.z;
  int p0 = blockIdx.x * 64, q0 = blockIdx.y * 64;
  int pl = threadIdx.x & 63, ql = threadIdx.x >> 6;
  __shared__ float lfm[64], lfs[64];
  if (ql == 0) {
    int p = p0 + pl;
    float M = -1e30f;
    #pragma unroll
    for (int c = 0; c < 8; ++c) M = fmaxf(M, Pm[((long)z * 8 + c) * 1600 + p]);
    float S = 0.f;
    #pragma unroll
    for (int c = 0; c < 8; ++c)
      S += Ps[((long)z * 8 + c) * 1600 + p] * __expf(Pm[((long)z * 8 + c) * 1600 + p] - M);
    lfm[pl] = M;
    lfs[pl] = 1.f / S;
  }
  __syncthreads();
  __shared__ ushort_t T[64][66];
  float fm = lfm[pl];
  float fs = lfs[pl];
  const float* S = S3 + (long)z * 2560000;
  #pragma unroll
  for (int i = 0; i < 16; ++i) {
    int qq = ql + i * 4;
    float x = 10.f * S[(long)(q0 + qq) * 1600 + p0 + pl];
    bf16 h = __float2bfloat16(__expf(x - fm) * fs);
    T[pl][qq] = *reinterpret_cast<ushort_t*>(&h);
  }
  __syncthreads();
  int rp = threadIdx.x >> 5;  // 0..7
  int j = threadIdx.x & 31;
  #pragma unroll
  for (int pass = 0; pass < 8; ++pass) {
    int row = pass * 8 + rp;
    unsigned int vv = (unsigned int)T[row][2 * j] | ((unsigned int)T[row][2 * j + 1] << 16);
    *reinterpret_cast<unsigned int*>(AT + ((long)z * 1664 + p0 + row) * 1600 + q0 + 2 * j) = vv;
  }
}

// ---------------------------------------------------------------------------
// K8: RAWPT[z][(c,i,j)][q] = bf16(raw[b][c][2qi+i-1][2qj+j-1])
// ---------------------------------------------------------------------------
__global__ __launch_bounds__(256) void rawpt_kernel(const float* __restrict__ rawL,
                                                    const float* __restrict__ rawR,
                                                    bf16* __restrict__ RAWPT) {
  int z = blockIdx.z;
  int r = blockIdx.y * 4 + (threadIdx.x >> 6);
  int q = blockIdx.x * 64 + (threadIdx.x & 63);
  const float* raw = ((z < 2) ? rawL : rawR) + (long)(z & 1) * 819200;
  int c = r >> 4, i = (r >> 2) & 3, j = r & 3;
  int qi = q / 40, qj = q - qi * 40;
  int y = 2 * qi + i - 1, x = 2 * qj + j - 1;
  float v = 0.f;
  if (y >= 0 && y < 80 && x >= 0 && x < 80) v = raw[((long)c * 80 + y) * 80 + x];
  RAWPT[((long)z * 2048 + r) * 1600 + q] = __float2bfloat16(v);
}

// ---------------------------------------------------------------------------
// K10 v2: overlap-add paste, 8 consecutive x per thread, vectorized.
// For the 8-x block (x0 = 8-aligned, h = x0/2):
//   even x = x0+2k: terms (jp=3, jm=h-1+k) and (jp=1, jm=h+k)
//   odd  x = x0+2k+1: terms (jp=2, jm=h+k) and (jp=0, jm=h+k+1)
// -> per (side, a): 4 f32x4u row loads; lane masks at x0==0 (jm=-1) and
// x0==72 (jm=40). Sum over a in {0,1} with im-validity; cosine blend; 2
// f32x4 stores (interleave even/odd).
// ---------------------------------------------------------------------------
__global__ __launch_bounds__(256) void paste_kernel(const float* __restrict__ Z,
                                                    float* __restrict__ out) {
  int t8 = blockIdx.x * 256 + threadIdx.x;  // 0..204799, exact
  int g = t8 % 10;
  int r = t8 / 10;                           // (b,c,y)
  int x0 = g * 8;
  int h = x0 >> 1;
  int y = r % 80;
  int cc = (r / 80) % 128;
  int b = r / (80 * 128);
  int imA = (y - 1) >> 1, ipA = y - 2 * imA + 1;  // a=0:(imA,ipA) a=1:(imA+1,ipA-2)
  const long zs = 2048L * 1600;
  const float* ZL = Z + (long)b * zs;
  const float* ZR = Z + (long)(2 + b) * zs;
  f32x4 EL = {0.f,0.f,0.f,0.f}, OL = {0.f,0.f,0.f,0.f};
  f32x4 ER = {0.f,0.f,0.f,0.f}, OR_ = {0.f,0.f,0.f,0.f};
  #pragma unroll
  for (int a = 0; a < 2; ++a) {
    int im = imA + a;
    if ((unsigned)im > 39u) continue;
    int ip = ipA - 2 * a;
    long rb = (long)(cc * 16 + ip * 4) * 1600 + im * 40;
    f32x4 l3 = *(const f32x4u*)(ZL + rb + 3 * 1600 + h - 1);
    f32x4 l1 = *(const f32x4u*)(ZL + rb + 1 * 1600 + h);
    f32x4 l2 = *(const f32x4u*)(ZL + rb + 2 * 1600 + h);
    f32x4 l0 = *(const f32x4u*)(ZL + rb + 0 * 1600 + h + 1);
    f32x4 r3 = *(const f32x4u*)(ZR + rb + 3 * 1600 + h - 1);
    f32x4 r1 = *(const f32x4u*)(ZR + rb + 1 * 1600 + h);
    f32x4 r2 = *(const f32x4u*)(ZR + rb + 2 * 1600 + h);
    f32x4 r0 = *(const f32x4u*)(ZR + rb + 0 * 1600 + h + 1);
    if (x0 == 0) { l3[0] = 0.f; r3[0] = 0.f; }    // jm=-1 invalid
    if (x0 == 72) { l0[3] = 0.f; r0[3] = 0.f; }   // jm=40 invalid
    EL += l3 + l1; OL += l2 + l0;
    ER += r3 + r1; OR_ += r2 + r0;
  }
  f32x4 o0, o1;
  #pragma unroll
  for (int k = 0; k < 4; ++k) {
    int xe = x0 + 2 * k, xo = xe + 1;
    float ce = cosf(PI_F * xe / 79.f);
    float co = cosf(PI_F * xo / 79.f);
    float ve = 0.25f * (0.5f * (1.f + ce) * EL[k] + 0.5f * (1.f - ce) * ER[k]);
    float vo = 0.25f * (0.5f * (1.f + co) * OL[k] + 0.5f * (1.f - co) * OR_[k]);
    if (k < 2) { o0[2 * k] = ve; o0[2 * k + 1] = vo; }
    else { o1[2 * (k - 2)] = ve; o1[2 * (k - 2) + 1] = vo; }
  }
  float* dst = out + (long)r * 80 + x0;
  *reinterpret_cast<f32x4*>(dst) = o0;
  *reinterpret_cast<f32x4*>(dst + 4) = o1;
}

// ---------------------------------------------------------------------------
extern "C" void kernel_launch(void* const* d_in, const int* in_sizes, int n_in,
                              void* d_out, int out_size, void* d_ws, size_t ws_size,
                              hipStream_t stream) {
  const float* left  = (const float*)d_in[0];
  const float* right = (const float*)d_in[1];
  const float* mid   = (const float*)d_in[2];
  const float* rawL  = (const float*)d_in[3];
  const float* rawR  = (const float*)d_in[4];
  float* out = (float*)d_out;
  char* ws = (char*)d_ws;

  bf16*  PTe   = (bf16*)(ws + 0);              // [4][1664][384] bf16 (hi|lo|hi)
  bf16*  MTe   = (bf16*)(ws + 5111808);        // [2][1664][384] bf16 (hi|hi|lo)
  float* SQ    = (float*)(ws + 7667712);       // [4][1600]
  float* INV   = (float*)(ws + 7693312);       // [4][1600]
  float* Pm    = (float*)(ws + 7718912);       // [4][8][1600]
  float* Ps    = (float*)(ws + 7923712);       // [4][8][1600]
  float* X     = (float*)(ws + 8179712);       // 52.4 MB pool: Gpad -> S3 -> Z
  float* Y     = (float*)(ws + 60608512);      // 41.0 MB pool: S2 -> RAWPT
  bf16*  AT    = (bf16*)(ws + 101568512);      // [4][1664][1600] bf16 (ends ~122.9MB)
  bf16*  RAWPT = (bf16*)Y;                     // overlay (26.2 MB <= 41.0 MB)

  prep_pt<<<dim3(1600, 6, 1), 128, 0, stream>>>(left, right, mid, PTe, MTe, SQ);
  invn_kernel<<<25, 256, 0, stream>>>(SQ, INV);
  padzero_kernel<<<dim3(1764, 4), 256, 0, stream>>>(X);
  // Gram via three-term double-bf16 MFMA (K=384), writing padded 4D layout:
  gemm_nt<<<dim3(13, 13, 4), 256, 0, stream>>>(PTe, MTe, X, 1600, 1600, 384,
                                               1664L * 384, 1664L * 384, GPAD_Z, 1, 1);
  s1fuse1_kernel<<<5000, 256, 0, stream>>>(X, INV, Y);           // Gpad -> S2
  fuse2_kernel<<<dim3(2500, 4), 256, 0, stream>>>(Y, X);         // S2 -> S3
  smax_part<<<dim3(25, 8, 4), 256, 0, stream>>>(X, Pm, Ps);
  smax_write<<<dim3(25, 25, 4), 256, 0, stream>>>(X, Pm, Ps, AT);   // S3 -> AT
  rawpt_kernel<<<dim3(25, 512, 4), 256, 0, stream>>>(rawL, rawR, RAWPT);  // S2 dead
  // Deconv GEMM: 256x256 8-phase (T2+T3+T4+T5), M=2048 N=1600 K=1600, z=4
  gemm256_nt<<<dim3(8, 7, 4), 512, 0, stream>>>(RAWPT, AT, X, 2048, 1600, 1600,
                                                2048L * 1600, 1664L * 1600, 2048L * 1600, 1664);
  paste_kernel<<<800, 256, 0, stream>>>(X, out);
}

// Round 4
// 310.023 us; speedup vs baseline: 1.0713x; 1.0713x over previous
//
#include <hip/hip_runtime.h>
#include <hip/hip_bf16.h>

typedef __hip_bfloat16 bf16;
typedef __attribute__((ext_vector_type(8))) short short8;
typedef __attribute__((ext_vector_type(4))) float f32x4;
typedef float f32x4u __attribute__((ext_vector_type(4), aligned(4)));
typedef unsigned short ushort_t;

#define PI_F 3.14159265358979323846f
#define GPAD_Z 3111696L  // 1764*1764

#define GLOAD_LDS16(gp, lp)                                                    \
  __builtin_amdgcn_global_load_lds(                                            \
      (const __attribute__((address_space(1))) unsigned int*)(gp),             \
      (__attribute__((address_space(3))) unsigned int*)(lp), 16, 0, 0)

// ---------------------------------------------------------------------------
// K1: downsample (::2,::2) + transpose to [slice][q][384] bf16 with the
// three-term double-bf16 layout:
//   A-side (PTe): [hi | lo | hi],  B-side (MTe): [hi | hi | lo]
// so dot_{k<384} = hiA·hiB + loA·hiB + hiA·loB  (only loA·loB ~2^-18 dropped).
// Also per-pixel squared channel norms SQ[z][q] (fp32) for left/right.
// ---------------------------------------------------------------------------
__global__ __launch_bounds__(128) void prep_pt(const float* __restrict__ left,
                                               const float* __restrict__ right,
                                               const float* __restrict__ mid,
                                               bf16* __restrict__ PTe,
                                               bf16* __restrict__ MTe,
                                               float* __restrict__ SQ) {
  int q = blockIdx.x;          // 0..1599
  int y = blockIdx.y;          // 0..5
  int c = threadIdx.x;         // 0..127
  int qi = q / 40, qj = q - qi * 40;
  const float* src;
  bf16* dst;
  int b;
  bool aside = (y < 4);
  if (aside) {
    b = y & 1;
    src = (y < 2) ? left : right;
    dst = PTe + (long)y * 1664 * 384;
  } else {
    b = y - 4;
    src = mid;
    dst = MTe + (long)(y - 4) * 1664 * 384;
  }
  float v = src[(((long)b * 128 + c) * 80 + 2 * qi) * 80 + 2 * qj];
  bf16 hi = __float2bfloat16(v);
  bf16 lo = __float2bfloat16(v - __bfloat162float(hi));
  if (aside) {
    dst[(long)q * 384 + c] = hi;
    dst[(long)q * 384 + 128 + c] = lo;
    dst[(long)q * 384 + 256 + c] = hi;
  } else {
    dst[(long)q * 384 + c] = hi;
    dst[(long)q * 384 + 128 + c] = hi;
    dst[(long)q * 384 + 256 + c] = lo;
  }
  if (aside) {
    __shared__ float red[128];
    red[c] = v * v;
    __syncthreads();
    for (int s = 64; s > 0; s >>= 1) {
      if (c < s) red[c] += red[c + s];
      __syncthreads();
    }
    if (c == 0) SQ[y * 1600 + q] = red[0];
  }
}

// ---------------------------------------------------------------------------
// K2: invN[z][q] = rsqrt( 3x3 box of SQ (zero-padded) + 1152*EPS )
// ---------------------------------------------------------------------------
__global__ void invn_kernel(const float* __restrict__ SQ, float* __restrict__ INV) {
  int idx = blockIdx.x * 256 + threadIdx.x;
  if (idx >= 6400) return;
  int z = idx / 1600, q = idx - z * 1600;
  int qi = q / 40, qj = q - qi * 40;
  float s = 0.1152f;  // 128*3*3 * 1e-4
  #pragma unroll
  for (int di = -1; di <= 1; ++di)
    #pragma unroll
    for (int dj = -1; dj <= 1; ++dj) {
      int a = qi + di, b = qj + dj;
      if (a >= 0 && a < 40 && b >= 0 && b < 40) s += SQ[z * 1600 + a * 40 + b];
    }
  INV[idx] = rsqrtf(s);
}

// ---------------------------------------------------------------------------
// K2b: zero only the pad cells of Gpad ([42,42,42,42] layout, 1764x1764/z)
// ---------------------------------------------------------------------------
__global__ __launch_bounds__(256) void padzero_kernel(float* __restrict__ Gp) {
  int row = blockIdx.x;   // 0..1763
  int z = blockIdx.y;     // 0..3
  float* R = Gp + (long)z * GPAD_Z + (long)row * 1764;
  int r42 = row % 42;
  if (r42 == 0 || r42 == 41) {
    for (int c = threadIdx.x; c < 1764; c += 256) R[c] = 0.f;
  } else {
    for (int i = threadIdx.x; i < 84; i += 256) {
      int c = (i >> 1) * 42 + ((i & 1) ? 41 : 0);
      R[c] = 0.f;
    }
  }
}

// ---------------------------------------------------------------------------
// K3: bf16 MFMA GEMM (m97 structure, BK=32) — Gram GEMM only (K=384, cpad).
// ---------------------------------------------------------------------------
__global__ __launch_bounds__(256) void gemm_nt(const bf16* __restrict__ A,
                                               const bf16* __restrict__ B,
                                               float* __restrict__ C,
                                               int M, int N, int K,
                                               long Az, long Bz, long Cz,
                                               int bmod, int cpad) {
  int z = blockIdx.z;
  A += (long)z * Az;
  B += (long)(bmod ? (z & 1) : z) * Bz;
  C += (long)z * Cz;
  __shared__ bf16 As[128 * 32];  // row-major [row][32], 64 B rows, 8 KB
  __shared__ bf16 Bs[128 * 32];
  int lane = threadIdx.x & 63;
  int w = threadIdx.x >> 6;
  int mb = blockIdx.x * 128;
  int nb = blockIdx.y * 128;
  int lr = lane >> 2;
  int gb = (lane & 3) ^ ((lane >> 3) & 3);  // XOR swizzle at stage time
  int lm = lane & 15;
  int swz = (lm >> 1) & 3;
  int kb = lane >> 4;                  // 0..3 (k block of 8)
  int pos = (kb ^ swz) * 8;            // mirrored swizzle at read time
  int warow = (w >> 1) * 64;
  int wbrow = (w & 1) * 64;
  f32x4 acc[4][4];
  #pragma unroll
  for (int i = 0; i < 4; ++i)
    #pragma unroll
    for (int j = 0; j < 4; ++j) {
      f32x4 zv = {0.f, 0.f, 0.f, 0.f};
      acc[i][j] = zv;
    }
  for (int k0 = 0; k0 < K; k0 += 32) {
    __syncthreads();
    #pragma unroll
    for (int t = 0; t < 2; ++t) {
      int r = (w * 2 + t) * 16 + lr;   // 0..127
      GLOAD_LDS16(A + (long)(mb + r) * K + k0 + gb * 8, As + (w * 2 + t) * 512);
      GLOAD_LDS16(B + (long)(nb + r) * K + k0 + gb * 8, Bs + (w * 2 + t) * 512);
    }
    __syncthreads();
    short8 af[4], bfr[4];
    #pragma unroll
    for (int i = 0; i < 4; ++i) {
      af[i]  = *reinterpret_cast<const short8*>(As + (warow + i * 16 + lm) * 32 + pos);
      bfr[i] = *reinterpret_cast<const short8*>(Bs + (wbrow + i * 16 + lm) * 32 + pos);
    }
    #pragma unroll
    for (int i = 0; i < 4; ++i)
      #pragma unroll
      for (int j = 0; j < 4; ++j)
        acc[i][j] = __builtin_amdgcn_mfma_f32_16x16x32_bf16(af[i], bfr[j], acc[i][j], 0, 0, 0);
  }
  int m0 = mb + warow;
  int n0 = nb + wbrow;
  int col = lane & 15;
  int r0 = (lane >> 4) * 4;
  #pragma unroll
  for (int i = 0; i < 4; ++i)
    #pragma unroll
    for (int j = 0; j < 4; ++j) {
      int n = n0 + j * 16 + col;
      if (n < N) {
        int nc = cpad ? ((n / 40) * 42 + (n - (n / 40) * 40) + 43) : n;
        #pragma unroll
        for (int r = 0; r < 4; ++r) {
          int m = m0 + i * 16 + r0 + r;
          if (m < M) {
            long mr = cpad ? ((long)((m / 40) * 42 + (m - (m / 40) * 40) + 43) * 1764)
                           : ((long)m * N);
            C[mr + nc] = acc[i][j][r];
          }
        }
      }
    }
}

// ---------------------------------------------------------------------------
// K9: 256x256 8-phase bf16 GEMM (T2 st_16x32 swizzle + T3/T4 counted
// vmcnt(6) + T5 setprio). Verified round 1. Deconv GEMM. Unchanged.
// ---------------------------------------------------------------------------
#define BAR() __builtin_amdgcn_s_barrier()
#define LGKM0() asm volatile("s_waitcnt lgkmcnt(0)" ::: "memory")
#define STAGE_A(tt, h)                                                         \
  { long _k = (long)(tt) * 64;                                                 \
    char* _d = lds + (((tt) & 1) << 16) + (((h) * 8 + w) << 11);               \
    GLOAD_LDS16(a_row[h] + _k, _d);                                            \
    GLOAD_LDS16(a_row[h] + _k + 32, _d + 1024); }
#define STAGE_B(tt, h)                                                         \
  { long _k = (long)(tt) * 64;                                                 \
    char* _d = lds + (((tt) & 1) << 16) + 32768 + (((h) * 8 + w) << 11);       \
    GLOAD_LDS16(b_row[h] + _k, _d);                                            \
    GLOAD_LDS16(b_row[h] + _k + 32, _d + 1024); }
#define LD8(off) (*reinterpret_cast<const short8*>(lds + (off)))
#define LOAD_A(bufo, mh)                                                       \
  { _Pragma("unroll") for (int i = 0; i < 4; ++i)                              \
      { _Pragma("unroll") for (int kc = 0; kc < 2; ++kc)                       \
          a[i][kc] = LD8((bufo) + (((wm * 8 + (mh) * 4 + i) * 2 + kc) << 10) + rd_off); } }
#define LOAD_B(dst, bufo, nh)                                                  \
  { _Pragma("unroll") for (int j = 0; j < 2; ++j)                              \
      { _Pragma("unroll") for (int kc = 0; kc < 2; ++kc)                       \
          dst[j][kc] = LD8((bufo) + 32768 + (((wn * 4 + (nh) * 2 + j) * 2 + kc) << 10) + rd_off); } }
#define MFMA16(mh, nh, bset)                                                   \
  { _Pragma("unroll") for (int kc = 0; kc < 2; ++kc)                           \
      { _Pragma("unroll") for (int i = 0; i < 4; ++i)                          \
          { _Pragma("unroll") for (int j = 0; j < 2; ++j)                      \
              acc[(mh) * 4 + i][(nh) * 2 + j] = __builtin_amdgcn_mfma_f32_16x16x32_bf16( \
                  a[i][kc], bset[j][kc], acc[(mh) * 4 + i][(nh) * 2 + j], 0, 0, 0); } } }

__global__ __launch_bounds__(512, 2) void gemm256_nt(const bf16* __restrict__ A,
                                                     const bf16* __restrict__ B,
                                                     float* __restrict__ C,
                                                     int M, int N, int K,
                                                     long Az, long Bz, long Cz,
                                                     int nballoc) {
  __shared__ __align__(16) char lds[131072];  // [buf2][op2][32 subtiles x 1024B]
  int z = blockIdx.z;
  A += (long)z * Az;
  B += (long)z * Bz;
  C += (long)z * Cz;
  int tid = threadIdx.x;
  int lane = tid & 63;
  int w = tid >> 6;          // wave 0..7
  int wm = w >> 2;           // 0..1 (M half)
  int wn = w & 3;            // 0..3 (N quarter)
  int mb = blockIdx.x * 256;
  int nb = blockIdx.y * 256;
  int NT = K >> 6;

  // stage: LDS dest linear (base + lane*16); global source inverse-swizzled
  int srcb = (lane << 4) ^ (lane & 32);  // byte in 1024B subtile
  int r_src = srcb >> 6;                 // 0..15
  int c_src = (srcb & 63) >> 1;          // element 0..31 (x8 granules)
  const bf16* a_row[2];
  const bf16* b_row[2];
  #pragma unroll
  for (int h = 0; h < 2; ++h) {
    a_row[h] = A + (long)(mb + (h * 8 + w) * 16 + r_src) * K + c_src;
    int br = nb + (h * 8 + w) * 16 + r_src;
    if (br > nballoc - 1) br = nballoc - 1;  // N-tail: clamp inside allocation
    b_row[h] = B + (long)br * K + c_src;
  }
  // read: swizzled byte offset within subtile (4-way after st_16x32)
  int rd_off = (((lane & 15) << 6) | ((lane >> 4) << 4)) ^ ((lane & 8) << 2);

  short8 a[4][2], p0[2][2], p1[2][2];
  f32x4 acc[8][4];
  #pragma unroll
  for (int i = 0; i < 8; ++i)
    #pragma unroll
    for (int j = 0; j < 4; ++j) {
      f32x4 zv = {0.f, 0.f, 0.f, 0.f};
      acc[i][j] = zv;
    }

  // prologue: tile0 fully + tile1 {A0,A1,B0}; wait tile0 (3 half-tiles in flight)
  STAGE_A(0, 0); STAGE_A(0, 1); STAGE_B(0, 0); STAGE_B(0, 1);
  STAGE_A(1, 0); STAGE_A(1, 1); STAGE_B(1, 0);
  asm volatile("s_waitcnt vmcnt(6)" ::: "memory");
  BAR();

  for (int t = 0; t < NT; ++t) {
    int bufo = (t & 1) << 16;
    // phase 0: quadrant (m0,n0); stage B1 of t+1
    LOAD_A(bufo, 0);
    LOAD_B(p0, bufo, 0);
    if (t + 1 < NT) STAGE_B(t + 1, 1);
    BAR(); LGKM0();
    __builtin_amdgcn_s_setprio(1); MFMA16(0, 0, p0); __builtin_amdgcn_s_setprio(0);
    BAR();
    // phase 1: quadrant (m0,n1); A reused
    LOAD_B(p1, bufo, 1);
    BAR(); LGKM0();
    __builtin_amdgcn_s_setprio(1); MFMA16(0, 1, p1); __builtin_amdgcn_s_setprio(0);
    BAR();
    // phase 2: quadrant (m1,n1); B reused
    LOAD_A(bufo, 1);
    BAR(); LGKM0();
    __builtin_amdgcn_s_setprio(1); MFMA16(1, 1, p1); __builtin_amdgcn_s_setprio(0);
    BAR();
    // phase 3: quadrant (m1,n0)
    LOAD_B(p0, bufo, 0);
    BAR(); LGKM0();
    __builtin_amdgcn_s_setprio(1); MFMA16(1, 0, p0); __builtin_amdgcn_s_setprio(0);
    BAR();
    // boundary: stage t+2 {A0,A1,B0}, counted vmcnt(6)
    if (t + 2 < NT) {
      STAGE_A(t + 2, 0); STAGE_A(t + 2, 1); STAGE_B(t + 2, 0);
      asm volatile("s_waitcnt vmcnt(6)" ::: "memory");
      BAR();
    } else if (t + 1 < NT) {
      asm volatile("s_waitcnt vmcnt(0)" ::: "memory");  // one drain, last prefetch
      BAR();
    }
  }

  // epilogue: C/D frag = {col=lane&15, row=(lane>>4)*4+r}
  int col = lane & 15;
  int r0 = (lane >> 4) * 4;
  int m_base = mb + wm * 128;
  int n_base = nb + wn * 64;
  #pragma unroll
  for (int i = 0; i < 8; ++i)
    #pragma unroll
    for (int j = 0; j < 4; ++j) {
      int n = n_base + j * 16 + col;
      if (n < N) {
        #pragma unroll
        for (int r = 0; r < 4; ++r) {
          int m = m_base + i * 16 + r0 + r;
          C[(long)m * N + n] = acc[i][j][r];
        }
      }
    }
}

// ---------------------------------------------------------------------------
// helper: 9-tap diagonal patch sum at (q2,p2) in padded Gz (pads give zeros)
// ---------------------------------------------------------------------------
__device__ __forceinline__ float ps9(const float* __restrict__ Gz, int q2, int p2) {
  int qi2 = q2 / 40, qj2 = q2 - qi2 * 40;
  int pi2 = p2 / 40, pj2 = p2 - pi2 * 40;
  const float* base = Gz + (long)(qi2 * 42 + qj2 + 43) * 1764 + (pi2 * 42 + pj2 + 43);
  float t = 0.f;
  #pragma unroll
  for (int di = -1; di <= 1; ++di)
    #pragma unroll
    for (int dj = -1; dj <= 1; ++dj)
      t += base[(long)(di * 42 + dj) * 1765];
  return t;
}

// ---------------------------------------------------------------------------
// K4+K5 merged, v4: EXACT round-2 v2 per-thread body (4 outputs/thread,
// verified 61.4 µs) with an L2-chunked block mapping: 16 chunks =
// 4z x 4 q-quarters (400 q each; Gpad row-band ~430 rows x 7KB ~ 3.0 MB
// < 4 MB per-XCD L2). XCD x (= b%8) runs chunk x for its first 625 blocks
// (j < 625), then chunk x+8 — sequential chunk residency per XCD, full
// v2 parallelism (10000 blocks, 2.56M threads).
// ---------------------------------------------------------------------------
__global__ __launch_bounds__(256) void s1fuse1_kernel(const float* __restrict__ Gp,
                                                      const float* __restrict__ INV,
                                                      float* __restrict__ S2) {
  int b = blockIdx.x;              // 0..9999
  int x = b & 7;                   // XCD (HW: round-robin b%8)
  int j = b >> 3;                  // 0..1249 within XCD
  int half = (j >= 625) ? 1 : 0;
  int chunk = x + 8 * half;        // 0..15
  int z = chunk >> 2;
  int qq = chunk & 3;              // q-quarter
  int s_local = j - half * 625;    // 0..624
  unsigned int gid = (unsigned int)s_local * 256u + threadIdx.x;  // 0..159999
  int q_local = gid / 400u;        // 0..399
  int quad = gid - q_local * 400u; // 0..399
  int q = qq * 400 + q_local;
  int p0 = quad * 4;
  int qi = q / 40, qj = q - qi * 40;
  int pi = p0 / 40, pj0 = p0 - pi * 40;
  const float* Gz = Gp + (long)z * GPAD_Z;
  const float* IVz = INV + z * 1600;
  float* Srow = S2 + ((long)z * 1600 + q) * 1600 + p0;

  if (qj >= 1 && qj <= 38) {
    long R0C0 = (long)(qi * 42 + qj + 43) * 1764 + (pi * 42 + pj0 + 43);
    f32x4 cs[5];
    #pragma unroll
    for (int s = 0; s < 5; ++s) {
      const float* pb = Gz + R0C0 + (long)(s - 2) * 1765;
      f32x4 a0 = *(const f32x4u*)(pb - 42 * 1765);
      f32x4 a1 = *(const f32x4u*)(pb);
      f32x4 a2 = *(const f32x4u*)(pb + 42 * 1765);
      cs[s] = a0 + a1 + a2;
    }
    f32x4 c12 = cs[1] + cs[2];
    f32x4 c23 = cs[2] + cs[3];
    f32x4 psm = cs[0] + c12;   // PS at shift d=-1, lanes t=0..3
    f32x4 ps0 = c12 + cs[3];   // d=0
    f32x4 psp = c23 + cs[4];   // d=+1
    if (pj0 == 0) {            // crossing pair (t=0, d=-1): linear p wraps pi-row
      int p2 = p0 - 1;
      psm[0] = (p2 >= 0) ? ps9(Gz, q - 1, p2) : 0.f;
    } else if (pj0 == 36) {    // crossing pair (t=3, d=+1)
      int p2 = p0 + 4;
      psp[3] = (p2 < 1600) ? ps9(Gz, q + 1, p2) : 0.f;
    }
    float wm = IVz[q - 1], w0 = IVz[q], wp = IVz[q + 1];
    f32x4 outv = psm * wm + ps0 * w0 + psp * wp;
    *reinterpret_cast<f32x4*>(Srow) = outv;
  } else {
    // slow path (qj in {0,39}; ~5% of lanes)
    f32x4 outv;
    #pragma unroll
    for (int t = 0; t < 4; ++t) {
      int p = p0 + t;
      float s = 0.f;
      #pragma unroll
      for (int d = -1; d <= 1; ++d) {
        int q2 = q + d, p2 = p + d;
        bool ok = ((unsigned)q2 < 1600u) && ((unsigned)p2 < 1600u);
        if (ok) s += IVz[q2] * ps9(Gz, q2, p2);
      }
      outv[t] = s;
    }
    *reinterpret_cast<f32x4*>(Srow) = outv;
  }
}

// ---------------------------------------------------------------------------
// K6 v2: fuse pass 2, quad-vectorized (unchanged from round 2).
// ---------------------------------------------------------------------------
__global__ __launch_bounds__(256) void fuse2_kernel(const float* __restrict__ S2,
                                                    float* __restrict__ S3) {
  int z = blockIdx.y;
  int bx = blockIdx.x;
  int xc = bx & 7, rest = bx >> 3;
  int lid = (xc < 4 ? xc * 313 : 1252 + (xc - 4) * 312) + rest;
  unsigned int gid = (unsigned int)lid * 256u + threadIdx.x;
  int q = gid / 400u;
  int quad = gid - q * 400u;
  int p0 = quad * 4;
  const float* S = S2 + (long)z * 2560000;
  int il = q / 40, jl = q - il * 40;
  int im = p0 / 40, jm = p0 - im * 40;
  int u = jl * 40 + il;
  f32x4 acc = {0.f, 0.f, 0.f, 0.f};
  #pragma unroll
  for (int d = -1; d <= 1; ++d) {
    int u2 = u + d;
    if ((unsigned)u2 >= 1600u) continue;
    int q2 = (u2 % 40) * 40 + u2 / 40;
    int imd = im + d;
    if ((unsigned)imd < 40u) {
      acc += *reinterpret_cast<const f32x4*>(S + (long)q2 * 1600 + imd * 40 + jm);
    } else {
      #pragma unroll
      for (int t = 0; t < 4; ++t) {
        int v2 = (jm + t) * 40 + im + d;
        if ((unsigned)v2 < 1600u) {
          int p2 = (v2 % 40) * 40 + v2 / 40;
          acc[t] += S[(long)q2 * 1600 + p2];
        }
      }
    }
  }
  *reinterpret_cast<f32x4*>(S3 + ((long)z * 1600 + q) * 1600 + p0) = acc;
}

// ---------------------------------------------------------------------------
// K7a: softmax partials over q-chunks of 200, per (z,p)
// ---------------------------------------------------------------------------
__global__ __launch_bounds__(256) void smax_part(const float* __restrict__ S3,
                                                 float* __restrict__ Pm,
                                                 float* __restrict__ Ps) {
  int z = blockIdx.z, qc = blockIdx.y;
  int pl = threadIdx.x & 63;
  int ql = threadIdx.x >> 6;
  int p = blockIdx.x * 64 + pl;
  const float* S = S3 + (long)z * 2560000;
  float m = -1e30f, s = 0.f;
  for (int i = 0; i < 50; ++i) {
    int q = qc * 200 + i * 4 + ql;
    float x = 10.f * S[(long)q * 1600 + p];
    if (x > m) { s *= __expf(m - x); m = x; }
    s += __expf(x - m);
  }
  __shared__ float lm[4][64], ls[4][64];
  lm[ql][pl] = m;
  ls[ql][pl] = s;
  __syncthreads();
  if (ql == 0) {
    float M = m, SS = s;
    #pragma unroll
    for (int j = 1; j < 4; ++j) {
      float mj = lm[j][pl], sj = ls[j][pl];
      if (mj > M) { SS = SS * __expf(M - mj) + sj; M = mj; }
      else SS += sj * __expf(mj - M);
    }
    Pm[((long)z * 8 + qc) * 1600 + p] = M;
    Ps[((long)z * 8 + qc) * 1600 + p] = SS;
  }
}

// ---------------------------------------------------------------------------
// K7b: combine partials (folded, per p) -> normalize S3 -> bf16 ->
// LDS-transpose -> AT[p][q]
// ---------------------------------------------------------------------------
__global__ __launch_bounds__(256) void smax_write(const float* __restrict__ S3,
                                                  const float* __restrict__ Pm,
                                                  const float* __restrict__ Ps,
                                                  bf16* __restrict__ AT) {
  int z = blockIdx.z;
  int p0 = blockIdx.x * 64, q0 = blockIdx.y * 64;
  int pl = threadIdx.x & 63, ql = threadIdx.x >> 6;
  __shared__ float lfm[64], lfs[64];
  if (ql == 0) {
    int p = p0 + pl;
    float M = -1e30f;
    #pragma unroll
    for (int c = 0; c < 8; ++c) M = fmaxf(M, Pm[((long)z * 8 + c) * 1600 + p]);
    float S = 0.f;
    #pragma unroll
    for (int c = 0; c < 8; ++c)
      S += Ps[((long)z * 8 + c) * 1600 + p] * __expf(Pm[((long)z * 8 + c) * 1600 + p] - M);
    lfm[pl] = M;
    lfs[pl] = 1.f / S;
  }
  __syncthreads();
  __shared__ ushort_t T[64][66];
  float fm = lfm[pl];
  float fs = lfs[pl];
  const float* S = S3 + (long)z * 2560000;
  #pragma unroll
  for (int i = 0; i < 16; ++i) {
    int qq = ql + i * 4;
    float x = 10.f * S[(long)(q0 + qq) * 1600 + p0 + pl];
    bf16 h = __float2bfloat16(__expf(x - fm) * fs);
    T[pl][qq] = *reinterpret_cast<ushort_t*>(&h);
  }
  __syncthreads();
  int rp = threadIdx.x >> 5;  // 0..7
  int j = threadIdx.x & 31;
  #pragma unroll
  for (int pass = 0; pass < 8; ++pass) {
    int row = pass * 8 + rp;
    unsigned int vv = (unsigned int)T[row][2 * j] | ((unsigned int)T[row][2 * j + 1] << 16);
    *reinterpret_cast<unsigned int*>(AT + ((long)z * 1664 + p0 + row) * 1600 + q0 + 2 * j) = vv;
  }
}

// ---------------------------------------------------------------------------
// K8: RAWPT[z][(c,i,j)][q] = bf16(raw[b][c][2qi+i-1][2qj+j-1])
// ---------------------------------------------------------------------------
__global__ __launch_bounds__(256) void rawpt_kernel(const float* __restrict__ rawL,
                                                    const float* __restrict__ rawR,
                                                    bf16* __restrict__ RAWPT) {
  int z = blockIdx.z;
  int r = blockIdx.y * 4 + (threadIdx.x >> 6);
  int q = blockIdx.x * 64 + (threadIdx.x & 63);
  const float* raw = ((z < 2) ? rawL : rawR) + (long)(z & 1) * 819200;
  int c = r >> 4, i = (r >> 2) & 3, j = r & 3;
  int qi = q / 40, qj = q - qi * 40;
  int y = 2 * qi + i - 1, x = 2 * qj + j - 1;
  float v = 0.f;
  if (y >= 0 && y < 80 && x >= 0 && x < 80) v = raw[((long)c * 80 + y) * 80 + x];
  RAWPT[((long)z * 2048 + r) * 1600 + q] = __float2bfloat16(v);
}

// ---------------------------------------------------------------------------
// K10 v2: overlap-add paste, 8 consecutive x per thread, vectorized.
// (verified round 3)
// ---------------------------------------------------------------------------
__global__ __launch_bounds__(256) void paste_kernel(const float* __restrict__ Z,
                                                    float* __restrict__ out) {
  int t8 = blockIdx.x * 256 + threadIdx.x;  // 0..204799, exact
  int g = t8 % 10;
  int r = t8 / 10;                           // (b,c,y)
  int x0 = g * 8;
  int h = x0 >> 1;
  int y = r % 80;
  int cc = (r / 80) % 128;
  int b = r / (80 * 128);
  int imA = (y - 1) >> 1, ipA = y - 2 * imA + 1;  // a=0:(imA,ipA) a=1:(imA+1,ipA-2)
  const long zs = 2048L * 1600;
  const float* ZL = Z + (long)b * zs;
  const float* ZR = Z + (long)(2 + b) * zs;
  f32x4 EL = {0.f,0.f,0.f,0.f}, OL = {0.f,0.f,0.f,0.f};
  f32x4 ER = {0.f,0.f,0.f,0.f}, OR_ = {0.f,0.f,0.f,0.f};
  #pragma unroll
  for (int a = 0; a < 2; ++a) {
    int im = imA + a;
    if ((unsigned)im > 39u) continue;
    int ip = ipA - 2 * a;
    long rb = (long)(cc * 16 + ip * 4) * 1600 + im * 40;
    f32x4 l3 = *(const f32x4u*)(ZL + rb + 3 * 1600 + h - 1);
    f32x4 l1 = *(const f32x4u*)(ZL + rb + 1 * 1600 + h);
    f32x4 l2 = *(const f32x4u*)(ZL + rb + 2 * 1600 + h);
    f32x4 l0 = *(const f32x4u*)(ZL + rb + 0 * 1600 + h + 1);
    f32x4 r3 = *(const f32x4u*)(ZR + rb + 3 * 1600 + h - 1);
    f32x4 r1 = *(const f32x4u*)(ZR + rb + 1 * 1600 + h);
    f32x4 r2 = *(const f32x4u*)(ZR + rb + 2 * 1600 + h);
    f32x4 r0 = *(const f32x4u*)(ZR + rb + 0 * 1600 + h + 1);
    if (x0 == 0) { l3[0] = 0.f; r3[0] = 0.f; }    // jm=-1 invalid
    if (x0 == 72) { l0[3] = 0.f; r0[3] = 0.f; }   // jm=40 invalid
    EL += l3 + l1; OL += l2 + l0;
    ER += r3 + r1; OR_ += r2 + r0;
  }
  f32x4 o0, o1;
  #pragma unroll
  for (int k = 0; k < 4; ++k) {
    int xe = x0 + 2 * k, xo = xe + 1;
    float ce = cosf(PI_F * xe / 79.f);
    float co = cosf(PI_F * xo / 79.f);
    float ve = 0.25f * (0.5f * (1.f + ce) * EL[k] + 0.5f * (1.f - ce) * ER[k]);
    float vo = 0.25f * (0.5f * (1.f + co) * OL[k] + 0.5f * (1.f - co) * OR_[k]);
    if (k < 2) { o0[2 * k] = ve; o0[2 * k + 1] = vo; }
    else { o1[2 * (k - 2)] = ve; o1[2 * (k - 2) + 1] = vo; }
  }
  float* dst = out + (long)r * 80 + x0;
  *reinterpret_cast<f32x4*>(dst) = o0;
  *reinterpret_cast<f32x4*>(dst + 4) = o1;
}

// ---------------------------------------------------------------------------
extern "C" void kernel_launch(void* const* d_in, const int* in_sizes, int n_in,
                              void* d_out, int out_size, void* d_ws, size_t ws_size,
                              hipStream_t stream) {
  const float* left  = (const float*)d_in[0];
  const float* right = (const float*)d_in[1];
  const float* mid   = (const float*)d_in[2];
  const float* rawL  = (const float*)d_in[3];
  const float* rawR  = (const float*)d_in[4];
  float* out = (float*)d_out;
  char* ws = (char*)d_ws;

  bf16*  PTe   = (bf16*)(ws + 0);              // [4][1664][384] bf16 (hi|lo|hi)
  bf16*  MTe   = (bf16*)(ws + 5111808);        // [2][1664][384] bf16 (hi|hi|lo)
  float* SQ    = (float*)(ws + 7667712);       // [4][1600]
  float* INV   = (float*)(ws + 7693312);       // [4][1600]
  float* Pm    = (float*)(ws + 7718912);       // [4][8][1600]
  float* Ps    = (float*)(ws + 7923712);       // [4][8][1600]
  float* X     = (float*)(ws + 8179712);       // 52.4 MB pool: Gpad -> S3 -> Z
  float* Y     = (float*)(ws + 60608512);      // 41.0 MB pool: S2 -> RAWPT
  bf16*  AT    = (bf16*)(ws + 101568512);      // [4][1664][1600] bf16 (ends ~122.9MB)
  bf16*  RAWPT = (bf16*)Y;                     // overlay (26.2 MB <= 41.0 MB)

  prep_pt<<<dim3(1600, 6, 1), 128, 0, stream>>>(left, right, mid, PTe, MTe, SQ);
  invn_kernel<<<25, 256, 0, stream>>>(SQ, INV);
  padzero_kernel<<<dim3(1764, 4), 256, 0, stream>>>(X);
  // Gram via three-term double-bf16 MFMA (K=384), writing padded 4D layout:
  gemm_nt<<<dim3(13, 13, 4), 256, 0, stream>>>(PTe, MTe, X, 1600, 1600, 384,
                                               1664L * 384, 1664L * 384, GPAD_Z, 1, 1);
  s1fuse1_kernel<<<10000, 256, 0, stream>>>(X, INV, Y);          // Gpad -> S2
  fuse2_kernel<<<dim3(2500, 4), 256, 0, stream>>>(Y, X);         // S2 -> S3
  smax_part<<<dim3(25, 8, 4), 256, 0, stream>>>(X, Pm, Ps);
  smax_write<<<dim3(25, 25, 4), 256, 0, stream>>>(X, Pm, Ps, AT);   // S3 -> AT
  rawpt_kernel<<<dim3(25, 512, 4), 256, 0, stream>>>(rawL, rawR, RAWPT);  // S2 dead
  // Deconv GEMM: 256x256 8-phase (T2+T3+T4+T5), M=2048 N=1600 K=1600, z=4
  gemm256_nt<<<dim3(8, 7, 4), 512, 0, stream>>>(RAWPT, AT, X, 2048, 1600, 1600,
                                                2048L * 1600, 1664L * 1600, 2048L * 1600, 1664);
  paste_kernel<<<800, 256, 0, stream>>>(X, out);
}

// Round 5
// 304.661 us; speedup vs baseline: 1.0901x; 1.0176x over previous
//
#include <hip/hip_runtime.h>
#include <hip/hip_bf16.h>

typedef __hip_bfloat16 bf16;
typedef __attribute__((ext_vector_type(8))) short short8;
typedef __attribute__((ext_vector_type(4))) float f32x4;
typedef float f32x4u __attribute__((ext_vector_type(4), aligned(4)));
typedef unsigned short ushort_t;

#define PI_F 3.14159265358979323846f
#define GPAD_Z 3111696L  // 1764*1764

#define GLOAD_LDS16(gp, lp)                                                    \
  __builtin_amdgcn_global_load_lds(                                            \
      (const __attribute__((address_space(1))) unsigned int*)(gp),             \
      (__attribute__((address_space(3))) unsigned int*)(lp), 16, 0, 0)

// ---------------------------------------------------------------------------
// K1: downsample (::2,::2) + transpose to [slice][q][384] bf16 with the
// three-term double-bf16 layout. Also per-pixel squared norms SQ (l/r).
// ---------------------------------------------------------------------------
__global__ __launch_bounds__(128) void prep_pt(const float* __restrict__ left,
                                               const float* __restrict__ right,
                                               const float* __restrict__ mid,
                                               bf16* __restrict__ PTe,
                                               bf16* __restrict__ MTe,
                                               float* __restrict__ SQ) {
  int q = blockIdx.x;          // 0..1599
  int y = blockIdx.y;          // 0..5
  int c = threadIdx.x;         // 0..127
  int qi = q / 40, qj = q - qi * 40;
  const float* src;
  bf16* dst;
  int b;
  bool aside = (y < 4);
  if (aside) {
    b = y & 1;
    src = (y < 2) ? left : right;
    dst = PTe + (long)y * 1664 * 384;
  } else {
    b = y - 4;
    src = mid;
    dst = MTe + (long)(y - 4) * 1664 * 384;
  }
  float v = src[(((long)b * 128 + c) * 80 + 2 * qi) * 80 + 2 * qj];
  bf16 hi = __float2bfloat16(v);
  bf16 lo = __float2bfloat16(v - __bfloat162float(hi));
  if (aside) {
    dst[(long)q * 384 + c] = hi;
    dst[(long)q * 384 + 128 + c] = lo;
    dst[(long)q * 384 + 256 + c] = hi;
  } else {
    dst[(long)q * 384 + c] = hi;
    dst[(long)q * 384 + 128 + c] = hi;
    dst[(long)q * 384 + 256 + c] = lo;
  }
  if (aside) {
    __shared__ float red[128];
    red[c] = v * v;
    __syncthreads();
    for (int s = 64; s > 0; s >>= 1) {
      if (c < s) red[c] += red[c + s];
      __syncthreads();
    }
    if (c == 0) SQ[y * 1600 + q] = red[0];
  }
}

// ---------------------------------------------------------------------------
// K2: invN[z][q] = rsqrt( 3x3 box of SQ (zero-padded) + 1152*EPS )
// ---------------------------------------------------------------------------
__global__ void invn_kernel(const float* __restrict__ SQ, float* __restrict__ INV) {
  int idx = blockIdx.x * 256 + threadIdx.x;
  if (idx >= 6400) return;
  int z = idx / 1600, q = idx - z * 1600;
  int qi = q / 40, qj = q - qi * 40;
  float s = 0.1152f;  // 128*3*3 * 1e-4
  #pragma unroll
  for (int di = -1; di <= 1; ++di)
    #pragma unroll
    for (int dj = -1; dj <= 1; ++dj) {
      int a = qi + di, b = qj + dj;
      if (a >= 0 && a < 40 && b >= 0 && b < 40) s += SQ[z * 1600 + a * 40 + b];
    }
  INV[idx] = rsqrtf(s);
}

// ---------------------------------------------------------------------------
// K2b: zero only the pad cells of Gpad ([42,42,42,42] layout, 1764x1764/z)
// ---------------------------------------------------------------------------
__global__ __launch_bounds__(256) void padzero_kernel(float* __restrict__ Gp) {
  int row = blockIdx.x;   // 0..1763
  int z = blockIdx.y;     // 0..3
  float* R = Gp + (long)z * GPAD_Z + (long)row * 1764;
  int r42 = row % 42;
  if (r42 == 0 || r42 == 41) {
    for (int c = threadIdx.x; c < 1764; c += 256) R[c] = 0.f;
  } else {
    for (int i = threadIdx.x; i < 84; i += 256) {
      int c = (i >> 1) * 42 + ((i & 1) ? 41 : 0);
      R[c] = 0.f;
    }
  }
}

// ---------------------------------------------------------------------------
// K3: bf16 MFMA GEMM (m97 structure, BK=32) — Gram GEMM only (K=384, cpad).
// ---------------------------------------------------------------------------
__global__ __launch_bounds__(256) void gemm_nt(const bf16* __restrict__ A,
                                               const bf16* __restrict__ B,
                                               float* __restrict__ C,
                                               int M, int N, int K,
                                               long Az, long Bz, long Cz,
                                               int bmod, int cpad) {
  int z = blockIdx.z;
  A += (long)z * Az;
  B += (long)(bmod ? (z & 1) : z) * Bz;
  C += (long)z * Cz;
  __shared__ bf16 As[128 * 32];  // row-major [row][32], 64 B rows, 8 KB
  __shared__ bf16 Bs[128 * 32];
  int lane = threadIdx.x & 63;
  int w = threadIdx.x >> 6;
  int mb = blockIdx.x * 128;
  int nb = blockIdx.y * 128;
  int lr = lane >> 2;
  int gb = (lane & 3) ^ ((lane >> 3) & 3);  // XOR swizzle at stage time
  int lm = lane & 15;
  int swz = (lm >> 1) & 3;
  int kb = lane >> 4;                  // 0..3 (k block of 8)
  int pos = (kb ^ swz) * 8;            // mirrored swizzle at read time
  int warow = (w >> 1) * 64;
  int wbrow = (w & 1) * 64;
  f32x4 acc[4][4];
  #pragma unroll
  for (int i = 0; i < 4; ++i)
    #pragma unroll
    for (int j = 0; j < 4; ++j) {
      f32x4 zv = {0.f, 0.f, 0.f, 0.f};
      acc[i][j] = zv;
    }
  for (int k0 = 0; k0 < K; k0 += 32) {
    __syncthreads();
    #pragma unroll
    for (int t = 0; t < 2; ++t) {
      int r = (w * 2 + t) * 16 + lr;   // 0..127
      GLOAD_LDS16(A + (long)(mb + r) * K + k0 + gb * 8, As + (w * 2 + t) * 512);
      GLOAD_LDS16(B + (long)(nb + r) * K + k0 + gb * 8, Bs + (w * 2 + t) * 512);
    }
    __syncthreads();
    short8 af[4], bfr[4];
    #pragma unroll
    for (int i = 0; i < 4; ++i) {
      af[i]  = *reinterpret_cast<const short8*>(As + (warow + i * 16 + lm) * 32 + pos);
      bfr[i] = *reinterpret_cast<const short8*>(Bs + (wbrow + i * 16 + lm) * 32 + pos);
    }
    #pragma unroll
    for (int i = 0; i < 4; ++i)
      #pragma unroll
      for (int j = 0; j < 4; ++j)
        acc[i][j] = __builtin_amdgcn_mfma_f32_16x16x32_bf16(af[i], bfr[j], acc[i][j], 0, 0, 0);
  }
  int m0 = mb + warow;
  int n0 = nb + wbrow;
  int col = lane & 15;
  int r0 = (lane >> 4) * 4;
  #pragma unroll
  for (int i = 0; i < 4; ++i)
    #pragma unroll
    for (int j = 0; j < 4; ++j) {
      int n = n0 + j * 16 + col;
      if (n < N) {
        int nc = cpad ? ((n / 40) * 42 + (n - (n / 40) * 40) + 43) : n;
        #pragma unroll
        for (int r = 0; r < 4; ++r) {
          int m = m0 + i * 16 + r0 + r;
          if (m < M) {
            long mr = cpad ? ((long)((m / 40) * 42 + (m - (m / 40) * 40) + 43) * 1764)
                           : ((long)m * N);
            C[mr + nc] = acc[i][j][r];
          }
        }
      }
    }
}

// ---------------------------------------------------------------------------
// K9: 256x256 8-phase bf16 GEMM. Round-4 change: XCD-aware block remap so
// XCD x owns (z = x>>1, M-half = x&1), iterating N-major: each XCD fetches
// every B panel once (B HBM traffic 170->42 MB) and keeps A-half (3.3 MB) +
// B panel (0.8 MB) L2-resident. Grid stays dim3(8,7,4); HW XCD = linear%8.
// ---------------------------------------------------------------------------
#define BAR() __builtin_amdgcn_s_barrier()
#define LGKM0() asm volatile("s_waitcnt lgkmcnt(0)" ::: "memory")
#define STAGE_A(tt, h)                                                         \
  { long _k = (long)(tt) * 64;                                                 \
    char* _d = lds + (((tt) & 1) << 16) + (((h) * 8 + w) << 11);               \
    GLOAD_LDS16(a_row[h] + _k, _d);                                            \
    GLOAD_LDS16(a_row[h] + _k + 32, _d + 1024); }
#define STAGE_B(tt, h)                                                         \
  { long _k = (long)(tt) * 64;                                                 \
    char* _d = lds + (((tt) & 1) << 16) + 32768 + (((h) * 8 + w) << 11);       \
    GLOAD_LDS16(b_row[h] + _k, _d);                                            \
    GLOAD_LDS16(b_row[h] + _k + 32, _d + 1024); }
#define LD8(off) (*reinterpret_cast<const short8*>(lds + (off)))
#define LOAD_A(bufo, mh)                                                       \
  { _Pragma("unroll") for (int i = 0; i < 4; ++i)                              \
      { _Pragma("unroll") for (int kc = 0; kc < 2; ++kc)                       \
          a[i][kc] = LD8((bufo) + (((wm * 8 + (mh) * 4 + i) * 2 + kc) << 10) + rd_off); } }
#define LOAD_B(dst, bufo, nh)                                                  \
  { _Pragma("unroll") for (int j = 0; j < 2; ++j)                              \
      { _Pragma("unroll") for (int kc = 0; kc < 2; ++kc)                       \
          dst[j][kc] = LD8((bufo) + 32768 + (((wn * 4 + (nh) * 2 + j) * 2 + kc) << 10) + rd_off); } }
#define MFMA16(mh, nh, bset)                                                   \
  { _Pragma("unroll") for (int kc = 0; kc < 2; ++kc)                           \
      { _Pragma("unroll") for (int i = 0; i < 4; ++i)                          \
          { _Pragma("unroll") for (int j = 0; j < 2; ++j)                      \
              acc[(mh) * 4 + i][(nh) * 2 + j] = __builtin_amdgcn_mfma_f32_16x16x32_bf16( \
                  a[i][kc], bset[j][kc], acc[(mh) * 4 + i][(nh) * 2 + j], 0, 0, 0); } } }

__global__ __launch_bounds__(512, 2) void gemm256_nt(const bf16* __restrict__ A,
                                                     const bf16* __restrict__ B,
                                                     float* __restrict__ C,
                                                     int M, int N, int K,
                                                     long Az, long Bz, long Cz,
                                                     int nballoc) {
  __shared__ __align__(16) char lds[131072];  // [buf2][op2][32 subtiles x 1024B]
  // XCD remap: linear id l, XCD = l&7 -> z = x>>1, M-half = x&1; j = l>>3:
  // N-tile = j>>2 (slow), M-sub = j&3 (fast) -> 4 M-tiles share each B panel.
  int l = blockIdx.x + (blockIdx.y << 3) + blockIdx.z * 56;
  int x = l & 7;
  int j7 = l >> 3;             // 0..27
  int z = x >> 1;
  int mb = (((x & 1) << 2) + (j7 & 3)) * 256;
  int nb = (j7 >> 2) * 256;
  A += (long)z * Az;
  B += (long)z * Bz;
  C += (long)z * Cz;
  int tid = threadIdx.x;
  int lane = tid & 63;
  int w = tid >> 6;          // wave 0..7
  int wm = w >> 2;           // 0..1 (M half)
  int wn = w & 3;            // 0..3 (N quarter)
  int NT = K >> 6;

  // stage: LDS dest linear (base + lane*16); global source inverse-swizzled
  int srcb = (lane << 4) ^ (lane & 32);  // byte in 1024B subtile
  int r_src = srcb >> 6;                 // 0..15
  int c_src = (srcb & 63) >> 1;          // element 0..31 (x8 granules)
  const bf16* a_row[2];
  const bf16* b_row[2];
  #pragma unroll
  for (int h = 0; h < 2; ++h) {
    a_row[h] = A + (long)(mb + (h * 8 + w) * 16 + r_src) * K + c_src;
    int br = nb + (h * 8 + w) * 16 + r_src;
    if (br > nballoc - 1) br = nballoc - 1;  // N-tail: clamp inside allocation
    b_row[h] = B + (long)br * K + c_src;
  }
  // read: swizzled byte offset within subtile (4-way after st_16x32)
  int rd_off = (((lane & 15) << 6) | ((lane >> 4) << 4)) ^ ((lane & 8) << 2);

  short8 a[4][2], p0[2][2], p1[2][2];
  f32x4 acc[8][4];
  #pragma unroll
  for (int i = 0; i < 8; ++i)
    #pragma unroll
    for (int j = 0; j < 4; ++j) {
      f32x4 zv = {0.f, 0.f, 0.f, 0.f};
      acc[i][j] = zv;
    }

  // prologue: tile0 fully + tile1 {A0,A1,B0}; wait tile0 (3 half-tiles in flight)
  STAGE_A(0, 0); STAGE_A(0, 1); STAGE_B(0, 0); STAGE_B(0, 1);
  STAGE_A(1, 0); STAGE_A(1, 1); STAGE_B(1, 0);
  asm volatile("s_waitcnt vmcnt(6)" ::: "memory");
  BAR();

  for (int t = 0; t < NT; ++t) {
    int bufo = (t & 1) << 16;
    // phase 0: quadrant (m0,n0); stage B1 of t+1
    LOAD_A(bufo, 0);
    LOAD_B(p0, bufo, 0);
    if (t + 1 < NT) STAGE_B(t + 1, 1);
    BAR(); LGKM0();
    __builtin_amdgcn_s_setprio(1); MFMA16(0, 0, p0); __builtin_amdgcn_s_setprio(0);
    BAR();
    // phase 1: quadrant (m0,n1); A reused
    LOAD_B(p1, bufo, 1);
    BAR(); LGKM0();
    __builtin_amdgcn_s_setprio(1); MFMA16(0, 1, p1); __builtin_amdgcn_s_setprio(0);
    BAR();
    // phase 2: quadrant (m1,n1); B reused
    LOAD_A(bufo, 1);
    BAR(); LGKM0();
    __builtin_amdgcn_s_setprio(1); MFMA16(1, 1, p1); __builtin_amdgcn_s_setprio(0);
    BAR();
    // phase 3: quadrant (m1,n0)
    LOAD_B(p0, bufo, 0);
    BAR(); LGKM0();
    __builtin_amdgcn_s_setprio(1); MFMA16(1, 0, p0); __builtin_amdgcn_s_setprio(0);
    BAR();
    // boundary: stage t+2 {A0,A1,B0}, counted vmcnt(6)
    if (t + 2 < NT) {
      STAGE_A(t + 2, 0); STAGE_A(t + 2, 1); STAGE_B(t + 2, 0);
      asm volatile("s_waitcnt vmcnt(6)" ::: "memory");
      BAR();
    } else if (t + 1 < NT) {
      asm volatile("s_waitcnt vmcnt(0)" ::: "memory");  // one drain, last prefetch
      BAR();
    }
  }

  // epilogue: C/D frag = {col=lane&15, row=(lane>>4)*4+r}
  int col = lane & 15;
  int r0 = (lane >> 4) * 4;
  int m_base = mb + wm * 128;
  int n_base = nb + wn * 64;
  #pragma unroll
  for (int i = 0; i < 8; ++i)
    #pragma unroll
    for (int j = 0; j < 4; ++j) {
      int n = n_base + j * 16 + col;
      if (n < N) {
        #pragma unroll
        for (int r = 0; r < 4; ++r) {
          int m = m_base + i * 16 + r0 + r;
          C[(long)m * N + n] = acc[i][j][r];
        }
      }
    }
}

// ---------------------------------------------------------------------------
// helper: 9-tap diagonal patch sum at (q2,p2) in padded Gz (pads give zeros)
// ---------------------------------------------------------------------------
__device__ __forceinline__ float ps9(const float* __restrict__ Gz, int q2, int p2) {
  int qi2 = q2 / 40, qj2 = q2 - qi2 * 40;
  int pi2 = p2 / 40, pj2 = p2 - pi2 * 40;
  const float* base = Gz + (long)(qi2 * 42 + qj2 + 43) * 1764 + (pi2 * 42 + pj2 + 43);
  float t = 0.f;
  #pragma unroll
  for (int di = -1; di <= 1; ++di)
    #pragma unroll
    for (int dj = -1; dj <= 1; ++dj)
      t += base[(long)(di * 42 + dj) * 1765];
  return t;
}

// ---------------------------------------------------------------------------
// K4+K5 v5 FAST: LDS-tiled H42 sharing. H42[r][c] = Gz[r-42][c-42] + Gz[r][c]
// + Gz[r+42][c+42] (== v2's a0+a1+a2, bit-identical). out(q,p) = sum_s
// H42[R+s][C0+t+s] * coef_s, so H42 IS shareable across q (v2's cs wasn't,
// column-diagonal). Block = (z, qi, qj-half of 19, pi-group of 4): stages
// 23x174 H42 tile (16 KB LDS) via f32x4 loads (47 wave-loads vs v2's ~190
// per equal work), computes 19x160 outputs from LDS. Crossing patches
// (pj0==0 / pj0==36) = 3 LDS reads each; v2's garbage-read cells map only
// to patched lanes (edges verified). Slow rows qj in {0,39} -> K4b below.
// ---------------------------------------------------------------------------
__global__ __launch_bounds__(256) void s1fuse1_fast(const float* __restrict__ Gp,
                                                    const float* __restrict__ INV,
                                                    float* __restrict__ S2) {
  __shared__ float Hs[23][176];
  __shared__ float IVs[21];
  int b = blockIdx.x;              // 0..3199
  int g = b % 10;                  // pi-group (pi0 = 4g)
  int half = (b / 10) & 1;
  int qi = (b / 20) % 40;
  int z = b / 800;
  int qj0 = half ? 20 : 1;
  int tau0 = qj0 - 2;              // -1 or 18
  int colL = 168 * g + 39;
  const float* Gz = Gp + (long)z * GPAD_Z;
  const float* IVz = INV + z * 1600;
  int tid = threadIdx.x;

  // stage H42 tile: 23 rows x 44 f32x4 (176 cols; cols 174,175 spare)
  for (int idx = tid; idx < 23 * 44; idx += 256) {
    int row = idx / 44;
    int cv = idx - row * 44;
    int gr = qi * 42 + 43 + tau0 + row;      // 42..1721
    int gc = colL + 4 * cv;
    const float* p1 = Gz + (long)gr * 1764 + gc;
    f32x4 v = *(const f32x4u*)(p1 - 42 * 1765) + *(const f32x4u*)(p1)
            + *(const f32x4u*)(p1 + 42 * 1765);
    *reinterpret_cast<f32x4*>(&Hs[row][4 * cv]) = v;
  }
  if (tid < 21) IVs[tid] = IVz[qi * 40 + qj0 - 1 + tid];
  __syncthreads();

  // compute: 760 quad-jobs (19 q x 40 quads)
  for (int j = tid; j < 760; j += 256) {
    int jq = j / 40;
    int jp = j - jq * 40;
    int pblk = jp / 10;
    int pj0 = (jp - pblk * 10) * 4;
    int C0loc = pblk * 42 + pj0 + 4;
    int p0 = g * 160 + jp * 4;
    int qj = qj0 + jq;
    int q = qi * 40 + qj;
    f32x4 hs[5];
    #pragma unroll
    for (int s2 = 0; s2 < 5; ++s2) {
      int tr = jq + s2;
      int cc = C0loc + s2 - 2;
      f32x4 hv = {Hs[tr][cc], Hs[tr][cc + 1], Hs[tr][cc + 2], Hs[tr][cc + 3]};
      hs[s2] = hv;
    }
    f32x4 c12 = hs[1] + hs[2];
    f32x4 c23 = hs[2] + hs[3];
    f32x4 psm = hs[0] + c12;
    f32x4 ps0 = c12 + hs[3];
    f32x4 psp = c23 + hs[4];
    if (pj0 == 0) {             // crossing (t=0,d=-1)
      float pv = 0.f;
      if (p0 >= 1) {
        int C2 = pblk * 42 + 1;
        #pragma unroll
        for (int dj = -1; dj <= 1; ++dj) pv += Hs[jq + 1 + dj][C2 + dj];
      }
      psm[0] = pv;
    } else if (pj0 == 36) {     // crossing (t=3,d=+1)
      float pv = 0.f;
      if (p0 + 4 < 1600) {
        int C2 = pblk * 42 + 46;
        #pragma unroll
        for (int dj = -1; dj <= 1; ++dj) pv += Hs[jq + 3 + dj][C2 + dj];
      }
      psp[3] = pv;
    }
    float wm = IVs[jq], w0 = IVs[jq + 1], wp = IVs[jq + 2];
    f32x4 outv = psm * wm + ps0 * w0 + psp * wp;
    *reinterpret_cast<f32x4*>(S2 + ((long)z * 1600 + q) * 1600 + p0) = outv;
  }
}

// ---------------------------------------------------------------------------
// K4b v5 SLOW: rows qj in {0,39} — exact v2 slow-path body (global ps9).
// grid: dim3(125, 4); 32000 threads/z = 80 q-rows x 400 quads.
// ---------------------------------------------------------------------------
__global__ __launch_bounds__(256) void s1fuse1_slow(const float* __restrict__ Gp,
                                                    const float* __restrict__ INV,
                                                    float* __restrict__ S2) {
  int z = blockIdx.y;
  unsigned int gid = blockIdx.x * 256u + threadIdx.x;  // 0..31999
  int qidx = gid / 400u;          // 0..79
  int quad = gid - qidx * 400u;
  int qi = qidx >> 1;
  int qj = (qidx & 1) * 39;
  int q = qi * 40 + qj;
  int p0 = quad * 4;
  const float* Gz = Gp + (long)z * GPAD_Z;
  const float* IVz = INV + z * 1600;
  f32x4 outv;
  #pragma unroll
  for (int t = 0; t < 4; ++t) {
    int p = p0 + t;
    float s = 0.f;
    #pragma unroll
    for (int d = -1; d <= 1; ++d) {
      int q2 = q + d, p2 = p + d;
      bool ok = ((unsigned)q2 < 1600u) && ((unsigned)p2 < 1600u);
      if (ok) s += IVz[q2] * ps9(Gz, q2, p2);
    }
    outv[t] = s;
  }
  *reinterpret_cast<f32x4*>(S2 + ((long)z * 1600 + q) * 1600 + p0) = outv;
}

// ---------------------------------------------------------------------------
// K6 v2: fuse pass 2, quad-vectorized (unchanged).
// ---------------------------------------------------------------------------
__global__ __launch_bounds__(256) void fuse2_kernel(const float* __restrict__ S2,
                                                    float* __restrict__ S3) {
  int z = blockIdx.y;
  int bx = blockIdx.x;
  int xc = bx & 7, rest = bx >> 3;
  int lid = (xc < 4 ? xc * 313 : 1252 + (xc - 4) * 312) + rest;
  unsigned int gid = (unsigned int)lid * 256u + threadIdx.x;
  int q = gid / 400u;
  int quad = gid - q * 400u;
  int p0 = quad * 4;
  const float* S = S2 + (long)z * 2560000;
  int il = q / 40, jl = q - il * 40;
  int im = p0 / 40, jm = p0 - im * 40;
  int u = jl * 40 + il;
  f32x4 acc = {0.f, 0.f, 0.f, 0.f};
  #pragma unroll
  for (int d = -1; d <= 1; ++d) {
    int u2 = u + d;
    if ((unsigned)u2 >= 1600u) continue;
    int q2 = (u2 % 40) * 40 + u2 / 40;
    int imd = im + d;
    if ((unsigned)imd < 40u) {
      acc += *reinterpret_cast<const f32x4*>(S + (long)q2 * 1600 + imd * 40 + jm);
    } else {
      #pragma unroll
      for (int t = 0; t < 4; ++t) {
        int v2 = (jm + t) * 40 + im + d;
        if ((unsigned)v2 < 1600u) {
          int p2 = (v2 % 40) * 40 + v2 / 40;
          acc[t] += S[(long)q2 * 1600 + p2];
        }
      }
    }
  }
  *reinterpret_cast<f32x4*>(S3 + ((long)z * 1600 + q) * 1600 + p0) = acc;
}

// ---------------------------------------------------------------------------
// K7a: softmax partials over q-chunks of 200, per (z,p)
// ---------------------------------------------------------------------------
__global__ __launch_bounds__(256) void smax_part(const float* __restrict__ S3,
                                                 float* __restrict__ Pm,
                                                 float* __restrict__ Ps) {
  int z = blockIdx.z, qc = blockIdx.y;
  int pl = threadIdx.x & 63;
  int ql = threadIdx.x >> 6;
  int p = blockIdx.x * 64 + pl;
  const float* S = S3 + (long)z * 2560000;
  float m = -1e30f, s = 0.f;
  for (int i = 0; i < 50; ++i) {
    int q = qc * 200 + i * 4 + ql;
    float x = 10.f * S[(long)q * 1600 + p];
    if (x > m) { s *= __expf(m - x); m = x; }
    s += __expf(x - m);
  }
  __shared__ float lm[4][64], ls[4][64];
  lm[ql][pl] = m;
  ls[ql][pl] = s;
  __syncthreads();
  if (ql == 0) {
    float M = m, SS = s;
    #pragma unroll
    for (int j = 1; j < 4; ++j) {
      float mj = lm[j][pl], sj = ls[j][pl];
      if (mj > M) { SS = SS * __expf(M - mj) + sj; M = mj; }
      else SS += sj * __expf(mj - M);
    }
    Pm[((long)z * 8 + qc) * 1600 + p] = M;
    Ps[((long)z * 8 + qc) * 1600 + p] = SS;
  }
}

// ---------------------------------------------------------------------------
// K7b: combine partials (folded, per p) -> normalize S3 -> bf16 ->
// LDS-transpose -> AT[p][q]
// ---------------------------------------------------------------------------
__global__ __launch_bounds__(256) void smax_write(const float* __restrict__ S3,
                                                  const float* __restrict__ Pm,
                                                  const float* __restrict__ Ps,
                                                  bf16* __restrict__ AT) {
  int z = blockIdx.z;
  int p0 = blockIdx.x * 64, q0 = blockIdx.y * 64;
  int pl = threadIdx.x & 63, ql = threadIdx.x >> 6;
  __shared__ float lfm[64], lfs[64];
  if (ql == 0) {
    int p = p0 + pl;
    float M = -1e30f;
    #pragma unroll
    for (int c = 0; c < 8; ++c) M = fmaxf(M, Pm[((long)z * 8 + c) * 1600 + p]);
    float S = 0.f;
    #pragma unroll
    for (int c = 0; c < 8; ++c)
      S += Ps[((long)z * 8 + c) * 1600 + p] * __expf(Pm[((long)z * 8 + c) * 1600 + p] - M);
    lfm[pl] = M;
    lfs[pl] = 1.f / S;
  }
  __syncthreads();
  __shared__ ushort_t T[64][66];
  float fm = lfm[pl];
  float fs = lfs[pl];
  const float* S = S3 + (long)z * 2560000;
  #pragma unroll
  for (int i = 0; i < 16; ++i) {
    int qq = ql + i * 4;
    float x = 10.f * S[(long)(q0 + qq) * 1600 + p0 + pl];
    bf16 h = __float2bfloat16(__expf(x - fm) * fs);
    T[pl][qq] = *reinterpret_cast<ushort_t*>(&h);
  }
  __syncthreads();
  int rp = threadIdx.x >> 5;  // 0..7
  int j = threadIdx.x & 31;
  #pragma unroll
  for (int pass = 0; pass < 8; ++pass) {
    int row = pass * 8 + rp;
    unsigned int vv = (unsigned int)T[row][2 * j] | ((unsigned int)T[row][2 * j + 1] << 16);
    *reinterpret_cast<unsigned int*>(AT + ((long)z * 1664 + p0 + row) * 1600 + q0 + 2 * j) = vv;
  }
}

// ---------------------------------------------------------------------------
// K8: RAWPT[z][(c,i,j)][q] = bf16(raw[b][c][2qi+i-1][2qj+j-1])
// ---------------------------------------------------------------------------
__global__ __launch_bounds__(256) void rawpt_kernel(const float* __restrict__ rawL,
                                                    const float* __restrict__ rawR,
                                                    bf16* __restrict__ RAWPT) {
  int z = blockIdx.z;
  int r = blockIdx.y * 4 + (threadIdx.x >> 6);
  int q = blockIdx.x * 64 + (threadIdx.x & 63);
  const float* raw = ((z < 2) ? rawL : rawR) + (long)(z & 1) * 819200;
  int c = r >> 4, i = (r >> 2) & 3, j = r & 3;
  int qi = q / 40, qj = q - qi * 40;
  int y = 2 * qi + i - 1, x = 2 * qj + j - 1;
  float v = 0.f;
  if (y >= 0 && y < 80 && x >= 0 && x < 80) v = raw[((long)c * 80 + y) * 80 + x];
  RAWPT[((long)z * 2048 + r) * 1600 + q] = __float2bfloat16(v);
}

// ---------------------------------------------------------------------------
// K10 v2: overlap-add paste, 8 consecutive x per thread, vectorized.
// ---------------------------------------------------------------------------
__global__ __launch_bounds__(256) void paste_kernel(const float* __restrict__ Z,
                                                    float* __restrict__ out) {
  int t8 = blockIdx.x * 256 + threadIdx.x;  // 0..204799, exact
  int g = t8 % 10;
  int r = t8 / 10;                           // (b,c,y)
  int x0 = g * 8;
  int h = x0 >> 1;
  int y = r % 80;
  int cc = (r / 80) % 128;
  int b = r / (80 * 128);
  int imA = (y - 1) >> 1, ipA = y - 2 * imA + 1;  // a=0:(imA,ipA) a=1:(imA+1,ipA-2)
  const long zs = 2048L * 1600;
  const float* ZL = Z + (long)b * zs;
  const float* ZR = Z + (long)(2 + b) * zs;
  f32x4 EL = {0.f,0.f,0.f,0.f}, OL = {0.f,0.f,0.f,0.f};
  f32x4 ER = {0.f,0.f,0.f,0.f}, OR_ = {0.f,0.f,0.f,0.f};
  #pragma unroll
  for (int a = 0; a < 2; ++a) {
    int im = imA + a;
    if ((unsigned)im > 39u) continue;
    int ip = ipA - 2 * a;
    long rb = (long)(cc * 16 + ip * 4) * 1600 + im * 40;
    f32x4 l3 = *(const f32x4u*)(ZL + rb + 3 * 1600 + h - 1);
    f32x4 l1 = *(const f32x4u*)(ZL + rb + 1 * 1600 + h);
    f32x4 l2 = *(const f32x4u*)(ZL + rb + 2 * 1600 + h);
    f32x4 l0 = *(const f32x4u*)(ZL + rb + 0 * 1600 + h + 1);
    f32x4 r3 = *(const f32x4u*)(ZR + rb + 3 * 1600 + h - 1);
    f32x4 r1 = *(const f32x4u*)(ZR + rb + 1 * 1600 + h);
    f32x4 r2 = *(const f32x4u*)(ZR + rb + 2 * 1600 + h);
    f32x4 r0 = *(const f32x4u*)(ZR + rb + 0 * 1600 + h + 1);
    if (x0 == 0) { l3[0] = 0.f; r3[0] = 0.f; }    // jm=-1 invalid
    if (x0 == 72) { l0[3] = 0.f; r0[3] = 0.f; }   // jm=40 invalid
    EL += l3 + l1; OL += l2 + l0;
    ER += r3 + r1; OR_ += r2 + r0;
  }
  f32x4 o0, o1;
  #pragma unroll
  for (int k = 0; k < 4; ++k) {
    int xe = x0 + 2 * k, xo = xe + 1;
    float ce = cosf(PI_F * xe / 79.f);
    float co = cosf(PI_F * xo / 79.f);
    float ve = 0.25f * (0.5f * (1.f + ce) * EL[k] + 0.5f * (1.f - ce) * ER[k]);
    float vo = 0.25f * (0.5f * (1.f + co) * OL[k] + 0.5f * (1.f - co) * OR_[k]);
    if (k < 2) { o0[2 * k] = ve; o0[2 * k + 1] = vo; }
    else { o1[2 * (k - 2)] = ve; o1[2 * (k - 2) + 1] = vo; }
  }
  float* dst = out + (long)r * 80 + x0;
  *reinterpret_cast<f32x4*>(dst) = o0;
  *reinterpret_cast<f32x4*>(dst + 4) = o1;
}

// ---------------------------------------------------------------------------
extern "C" void kernel_launch(void* const* d_in, const int* in_sizes, int n_in,
                              void* d_out, int out_size, void* d_ws, size_t ws_size,
                              hipStream_t stream) {
  const float* left  = (const float*)d_in[0];
  const float* right = (const float*)d_in[1];
  const float* mid   = (const float*)d_in[2];
  const float* rawL  = (const float*)d_in[3];
  const float* rawR  = (const float*)d_in[4];
  float* out = (float*)d_out;
  char* ws = (char*)d_ws;

  bf16*  PTe   = (bf16*)(ws + 0);              // [4][1664][384] bf16 (hi|lo|hi)
  bf16*  MTe   = (bf16*)(ws + 5111808);        // [2][1664][384] bf16 (hi|hi|lo)
  float* SQ    = (float*)(ws + 7667712);       // [4][1600]
  float* INV   = (float*)(ws + 7693312);       // [4][1600]
  float* Pm    = (float*)(ws + 7718912);       // [4][8][1600]
  float* Ps    = (float*)(ws + 7923712);       // [4][8][1600]
  float* X     = (float*)(ws + 8179712);       // 52.4 MB pool: Gpad -> S3 -> Z
  float* Y     = (float*)(ws + 60608512);      // 41.0 MB pool: S2 -> RAWPT
  bf16*  AT    = (bf16*)(ws + 101568512);      // [4][1664][1600] bf16 (ends ~122.9MB)
  bf16*  RAWPT = (bf16*)Y;                     // overlay (26.2 MB <= 41.0 MB)

  prep_pt<<<dim3(1600, 6, 1), 128, 0, stream>>>(left, right, mid, PTe, MTe, SQ);
  invn_kernel<<<25, 256, 0, stream>>>(SQ, INV);
  padzero_kernel<<<dim3(1764, 4), 256, 0, stream>>>(X);
  // Gram via three-term double-bf16 MFMA (K=384), writing padded 4D layout:
  gemm_nt<<<dim3(13, 13, 4), 256, 0, stream>>>(PTe, MTe, X, 1600, 1600, 384,
                                               1664L * 384, 1664L * 384, GPAD_Z, 1, 1);
  s1fuse1_fast<<<3200, 256, 0, stream>>>(X, INV, Y);             // Gpad -> S2 (qj 1..38)
  s1fuse1_slow<<<dim3(125, 4), 256, 0, stream>>>(X, INV, Y);     // qj in {0,39}
  fuse2_kernel<<<dim3(2500, 4), 256, 0, stream>>>(Y, X);         // S2 -> S3
  smax_part<<<dim3(25, 8, 4), 256, 0, stream>>>(X, Pm, Ps);
  smax_write<<<dim3(25, 25, 4), 256, 0, stream>>>(X, Pm, Ps, AT);   // S3 -> AT
  rawpt_kernel<<<dim3(25, 512, 4), 256, 0, stream>>>(rawL, rawR, RAWPT);  // S2 dead
  // Deconv GEMM: 256x256 8-phase + XCD z-chunk remap
  gemm256_nt<<<dim3(8, 7, 4), 512, 0, stream>>>(RAWPT, AT, X, 2048, 1600, 1600,
                                                2048L * 1600, 1664L * 1600, 2048L * 1600, 1664);
  paste_kernel<<<800, 256, 0, stream>>>(X, out);
}

// Round 6
// 301.983 us; speedup vs baseline: 1.0998x; 1.0089x over previous
//
#include <hip/hip_runtime.h>
#include <hip/hip_bf16.h>

typedef __hip_bfloat16 bf16;
typedef __attribute__((ext_vector_type(8))) short short8;
typedef __attribute__((ext_vector_type(4))) float f32x4;
typedef float f32x4u __attribute__((ext_vector_type(4), aligned(4)));
typedef unsigned short ushort_t;

#define PI_F 3.14159265358979323846f
#define GPAD_Z 3111696L  // 1764*1764

#define GLOAD_LDS16(gp, lp)                                                    \
  __builtin_amdgcn_global_load_lds(                                            \
      (const __attribute__((address_space(1))) unsigned int*)(gp),             \
      (__attribute__((address_space(3))) unsigned int*)(lp), 16, 0, 0)

// ---------------------------------------------------------------------------
// K1: downsample (::2,::2) + transpose to [slice][q][384] bf16 with the
// three-term double-bf16 layout. Also per-pixel squared norms SQ (l/r).
// ---------------------------------------------------------------------------
__global__ __launch_bounds__(128) void prep_pt(const float* __restrict__ left,
                                               const float* __restrict__ right,
                                               const float* __restrict__ mid,
                                               bf16* __restrict__ PTe,
                                               bf16* __restrict__ MTe,
                                               float* __restrict__ SQ) {
  int q = blockIdx.x;          // 0..1599
  int y = blockIdx.y;          // 0..5
  int c = threadIdx.x;         // 0..127
  int qi = q / 40, qj = q - qi * 40;
  const float* src;
  bf16* dst;
  int b;
  bool aside = (y < 4);
  if (aside) {
    b = y & 1;
    src = (y < 2) ? left : right;
    dst = PTe + (long)y * 1664 * 384;
  } else {
    b = y - 4;
    src = mid;
    dst = MTe + (long)(y - 4) * 1664 * 384;
  }
  float v = src[(((long)b * 128 + c) * 80 + 2 * qi) * 80 + 2 * qj];
  bf16 hi = __float2bfloat16(v);
  bf16 lo = __float2bfloat16(v - __bfloat162float(hi));
  if (aside) {
    dst[(long)q * 384 + c] = hi;
    dst[(long)q * 384 + 128 + c] = lo;
    dst[(long)q * 384 + 256 + c] = hi;
  } else {
    dst[(long)q * 384 + c] = hi;
    dst[(long)q * 384 + 128 + c] = hi;
    dst[(long)q * 384 + 256 + c] = lo;
  }
  if (aside) {
    __shared__ float red[128];
    red[c] = v * v;
    __syncthreads();
    for (int s = 64; s > 0; s >>= 1) {
      if (c < s) red[c] += red[c + s];
      __syncthreads();
    }
    if (c == 0) SQ[y * 1600 + q] = red[0];
  }
}

// ---------------------------------------------------------------------------
// K2 merged: bx<1764 -> zero pad cells of Gpad row bx (z=by);
// bx>=1764 -> invN[z][q] = rsqrt( 3x3 box of SQ + 1152*EPS ), 7 blocks/z.
// ---------------------------------------------------------------------------
__global__ __launch_bounds__(256) void pad_invn_kernel(float* __restrict__ Gp,
                                                       const float* __restrict__ SQ,
                                                       float* __restrict__ INV) {
  int z = blockIdx.y;
  int bx = blockIdx.x;
  if (bx < 1764) {
    float* R = Gp + (long)z * GPAD_Z + (long)bx * 1764;
    int r42 = bx % 42;
    if (r42 == 0 || r42 == 41) {
      for (int c = threadIdx.x; c < 1764; c += 256) R[c] = 0.f;
    } else {
      for (int i = threadIdx.x; i < 84; i += 256) {
        int c = (i >> 1) * 42 + ((i & 1) ? 41 : 0);
        R[c] = 0.f;
      }
    }
  } else {
    int q = (bx - 1764) * 256 + threadIdx.x;
    if (q < 1600) {
      int qi = q / 40, qj = q - qi * 40;
      float s = 0.1152f;  // 128*3*3 * 1e-4
      #pragma unroll
      for (int di = -1; di <= 1; ++di)
        #pragma unroll
        for (int dj = -1; dj <= 1; ++dj) {
          int a = qi + di, b2 = qj + dj;
          if (a >= 0 && a < 40 && b2 >= 0 && b2 < 40) s += SQ[z * 1600 + a * 40 + b2];
        }
      INV[z * 1600 + q] = rsqrtf(s);
    }
  }
}

// ---------------------------------------------------------------------------
// K3: bf16 MFMA GEMM (m97 structure, BK=32) — Gram GEMM only (K=384, cpad).
// ---------------------------------------------------------------------------
__global__ __launch_bounds__(256) void gemm_nt(const bf16* __restrict__ A,
                                               const bf16* __restrict__ B,
                                               float* __restrict__ C,
                                               int M, int N, int K,
                                               long Az, long Bz, long Cz,
                                               int bmod, int cpad) {
  int z = blockIdx.z;
  A += (long)z * Az;
  B += (long)(bmod ? (z & 1) : z) * Bz;
  C += (long)z * Cz;
  __shared__ bf16 As[128 * 32];  // row-major [row][32], 64 B rows, 8 KB
  __shared__ bf16 Bs[128 * 32];
  int lane = threadIdx.x & 63;
  int w = threadIdx.x >> 6;
  int mb = blockIdx.x * 128;
  int nb = blockIdx.y * 128;
  int lr = lane >> 2;
  int gb = (lane & 3) ^ ((lane >> 3) & 3);  // XOR swizzle at stage time
  int lm = lane & 15;
  int swz = (lm >> 1) & 3;
  int kb = lane >> 4;                  // 0..3 (k block of 8)
  int pos = (kb ^ swz) * 8;            // mirrored swizzle at read time
  int warow = (w >> 1) * 64;
  int wbrow = (w & 1) * 64;
  f32x4 acc[4][4];
  #pragma unroll
  for (int i = 0; i < 4; ++i)
    #pragma unroll
    for (int j = 0; j < 4; ++j) {
      f32x4 zv = {0.f, 0.f, 0.f, 0.f};
      acc[i][j] = zv;
    }
  for (int k0 = 0; k0 < K; k0 += 32) {
    __syncthreads();
    #pragma unroll
    for (int t = 0; t < 2; ++t) {
      int r = (w * 2 + t) * 16 + lr;   // 0..127
      GLOAD_LDS16(A + (long)(mb + r) * K + k0 + gb * 8, As + (w * 2 + t) * 512);
      GLOAD_LDS16(B + (long)(nb + r) * K + k0 + gb * 8, Bs + (w * 2 + t) * 512);
    }
    __syncthreads();
    short8 af[4], bfr[4];
    #pragma unroll
    for (int i = 0; i < 4; ++i) {
      af[i]  = *reinterpret_cast<const short8*>(As + (warow + i * 16 + lm) * 32 + pos);
      bfr[i] = *reinterpret_cast<const short8*>(Bs + (wbrow + i * 16 + lm) * 32 + pos);
    }
    #pragma unroll
    for (int i = 0; i < 4; ++i)
      #pragma unroll
      for (int j = 0; j < 4; ++j)
        acc[i][j] = __builtin_amdgcn_mfma_f32_16x16x32_bf16(af[i], bfr[j], acc[i][j], 0, 0, 0);
  }
  int m0 = mb + warow;
  int n0 = nb + wbrow;
  int col = lane & 15;
  int r0 = (lane >> 4) * 4;
  #pragma unroll
  for (int i = 0; i < 4; ++i)
    #pragma unroll
    for (int j = 0; j < 4; ++j) {
      int n = n0 + j * 16 + col;
      if (n < N) {
        int nc = cpad ? ((n / 40) * 42 + (n - (n / 40) * 40) + 43) : n;
        #pragma unroll
        for (int r = 0; r < 4; ++r) {
          int m = m0 + i * 16 + r0 + r;
          if (m < M) {
            long mr = cpad ? ((long)((m / 40) * 42 + (m - (m / 40) * 40) + 43) * 1764)
                           : ((long)m * N);
            C[mr + nc] = acc[i][j][r];
          }
        }
      }
    }
}

// ---------------------------------------------------------------------------
// K9: 256x256 8-wave bf16 GEMM, round-6 change: 2 merged phases per K-tile
// with B register residency. Per K-tile: 32 ds_read_b128/thread (was 40),
// 5 barriers (was 9), MFMA runs of 32 (was 16). vmcnt invariant unchanged:
// B1(t+1) staged in phase A + 3 boundary half-tiles -> vmcnt(6) drains the
// oldest 2. XCD remap (round 4) kept: XCD x -> (z=x>>1, M-half=x&1), N-major.
// ---------------------------------------------------------------------------
#define BAR() __builtin_amdgcn_s_barrier()
#define LGKM0() asm volatile("s_waitcnt lgkmcnt(0)" ::: "memory")
#define STAGE_A(tt, h)                                                         \
  { long _k = (long)(tt) * 64;                                                 \
    char* _d = lds + (((tt) & 1) << 16) + (((h) * 8 + w) << 11);               \
    GLOAD_LDS16(a_row[h] + _k, _d);                                            \
    GLOAD_LDS16(a_row[h] + _k + 32, _d + 1024); }
#define STAGE_B(tt, h)                                                         \
  { long _k = (long)(tt) * 64;                                                 \
    char* _d = lds + (((tt) & 1) << 16) + 32768 + (((h) * 8 + w) << 11);       \
    GLOAD_LDS16(b_row[h] + _k, _d);                                            \
    GLOAD_LDS16(b_row[h] + _k + 32, _d + 1024); }
#define LD8(off) (*reinterpret_cast<const short8*>(lds + (off)))
#define LOAD_A(bufo, mh)                                                       \
  { _Pragma("unroll") for (int i = 0; i < 4; ++i)                              \
      { _Pragma("unroll") for (int kc = 0; kc < 2; ++kc)                       \
          a[i][kc] = LD8((bufo) + (((wm * 8 + (mh) * 4 + i) * 2 + kc) << 10) + rd_off); } }
#define LOAD_B(dst, bufo, nh)                                                  \
  { _Pragma("unroll") for (int j = 0; j < 2; ++j)                              \
      { _Pragma("unroll") for (int kc = 0; kc < 2; ++kc)                       \
          dst[j][kc] = LD8((bufo) + 32768 + (((wn * 4 + (nh) * 2 + j) * 2 + kc) << 10) + rd_off); } }
#define MFMA16(mh, nh, bset)                                                   \
  { _Pragma("unroll") for (int kc = 0; kc < 2; ++kc)                           \
      { _Pragma("unroll") for (int i = 0; i < 4; ++i)                          \
          { _Pragma("unroll") for (int j = 0; j < 2; ++j)                      \
              acc[(mh) * 4 + i][(nh) * 2 + j] = __builtin_amdgcn_mfma_f32_16x16x32_bf16( \
                  a[i][kc], bset[j][kc], acc[(mh) * 4 + i][(nh) * 2 + j], 0, 0, 0); } } }

__global__ __launch_bounds__(512, 2) void gemm256_nt(const bf16* __restrict__ A,
                                                     const bf16* __restrict__ B,
                                                     float* __restrict__ C,
                                                     int M, int N, int K,
                                                     long Az, long Bz, long Cz,
                                                     int nballoc) {
  __shared__ __align__(16) char lds[131072];  // [buf2][op2][32 subtiles x 1024B]
  // XCD remap: linear id l, XCD = l&7 -> z = x>>1, M-half = x&1; j = l>>3:
  // N-tile = j>>2 (slow), M-sub = j&3 (fast) -> 4 M-tiles share each B panel.
  int l = blockIdx.x + (blockIdx.y << 3) + blockIdx.z * 56;
  int x = l & 7;
  int j7 = l >> 3;             // 0..27
  int z = x >> 1;
  int mb = (((x & 1) << 2) + (j7 & 3)) * 256;
  int nb = (j7 >> 2) * 256;
  A += (long)z * Az;
  B += (long)z * Bz;
  C += (long)z * Cz;
  int tid = threadIdx.x;
  int lane = tid & 63;
  int w = tid >> 6;          // wave 0..7
  int wm = w >> 2;           // 0..1 (M half)
  int wn = w & 3;            // 0..3 (N quarter)
  int NT = K >> 6;

  // stage: LDS dest linear (base + lane*16); global source inverse-swizzled
  int srcb = (lane << 4) ^ (lane & 32);  // byte in 1024B subtile
  int r_src = srcb >> 6;                 // 0..15
  int c_src = (srcb & 63) >> 1;          // element 0..31 (x8 granules)
  const bf16* a_row[2];
  const bf16* b_row[2];
  #pragma unroll
  for (int h = 0; h < 2; ++h) {
    a_row[h] = A + (long)(mb + (h * 8 + w) * 16 + r_src) * K + c_src;
    int br = nb + (h * 8 + w) * 16 + r_src;
    if (br > nballoc - 1) br = nballoc - 1;  // N-tail: clamp inside allocation
    b_row[h] = B + (long)br * K + c_src;
  }
  // read: swizzled byte offset within subtile (4-way after st_16x32)
  int rd_off = (((lane & 15) << 6) | ((lane >> 4) << 4)) ^ ((lane & 8) << 2);

  short8 a[4][2], p0[2][2], p1[2][2];
  f32x4 acc[8][4];
  #pragma unroll
  for (int i = 0; i < 8; ++i)
    #pragma unroll
    for (int j = 0; j < 4; ++j) {
      f32x4 zv = {0.f, 0.f, 0.f, 0.f};
      acc[i][j] = zv;
    }

  // prologue: tile0 fully + tile1 {A0,A1,B0}; wait tile0 (3 half-tiles in flight)
  STAGE_A(0, 0); STAGE_A(0, 1); STAGE_B(0, 0); STAGE_B(0, 1);
  STAGE_A(1, 0); STAGE_A(1, 1); STAGE_B(1, 0);
  asm volatile("s_waitcnt vmcnt(6)" ::: "memory");
  BAR();

  for (int t = 0; t < NT; ++t) {
    int bufo = (t & 1) << 16;
    // phase A: M-half 0 x full N (24 ds_reads); stage B1 of t+1
    LOAD_A(bufo, 0);
    LOAD_B(p0, bufo, 0);
    LOAD_B(p1, bufo, 1);
    if (t + 1 < NT) STAGE_B(t + 1, 1);
    asm volatile("s_waitcnt lgkmcnt(8)" ::: "memory");  // pre-drain before barrier
    BAR(); LGKM0();
    __builtin_amdgcn_s_setprio(1);
    MFMA16(0, 0, p0); MFMA16(0, 1, p1);
    __builtin_amdgcn_s_setprio(0);
    BAR();
    // phase B: M-half 1 x full N; B reused in registers (8 ds_reads)
    LOAD_A(bufo, 1);
    BAR(); LGKM0();
    __builtin_amdgcn_s_setprio(1);
    MFMA16(1, 0, p0); MFMA16(1, 1, p1);
    __builtin_amdgcn_s_setprio(0);
    BAR();
    // boundary: stage t+2 {A0,A1,B0}, counted vmcnt(6)
    if (t + 2 < NT) {
      STAGE_A(t + 2, 0); STAGE_A(t + 2, 1); STAGE_B(t + 2, 0);
      asm volatile("s_waitcnt vmcnt(6)" ::: "memory");
      BAR();
    } else if (t + 1 < NT) {
      asm volatile("s_waitcnt vmcnt(0)" ::: "memory");  // one drain, last prefetch
      BAR();
    }
  }

  // epilogue: C/D frag = {col=lane&15, row=(lane>>4)*4+r}
  int col = lane & 15;
  int r0 = (lane >> 4) * 4;
  int m_base = mb + wm * 128;
  int n_base = nb + wn * 64;
  #pragma unroll
  for (int i = 0; i < 8; ++i)
    #pragma unroll
    for (int j = 0; j < 4; ++j) {
      int n = n_base + j * 16 + col;
      if (n < N) {
        #pragma unroll
        for (int r = 0; r < 4; ++r) {
          int m = m_base + i * 16 + r0 + r;
          C[(long)m * N + n] = acc[i][j][r];
        }
      }
    }
}

// ---------------------------------------------------------------------------
// helper: 9-tap diagonal patch sum at (q2,p2) in padded Gz (pads give zeros)
// ---------------------------------------------------------------------------
__device__ __forceinline__ float ps9(const float* __restrict__ Gz, int q2, int p2) {
  int qi2 = q2 / 40, qj2 = q2 - qi2 * 40;
  int pi2 = p2 / 40, pj2 = p2 - pi2 * 40;
  const float* base = Gz + (long)(qi2 * 42 + qj2 + 43) * 1764 + (pi2 * 42 + pj2 + 43);
  float t = 0.f;
  #pragma unroll
  for (int di = -1; di <= 1; ++di)
    #pragma unroll
    for (int dj = -1; dj <= 1; ++dj)
      t += base[(long)(di * 42 + dj) * 1765];
  return t;
}

// ---------------------------------------------------------------------------
// K4+K5 v5 FAST: LDS-tiled H42 sharing (verified round 5).
// ---------------------------------------------------------------------------
__global__ __launch_bounds__(256) void s1fuse1_fast(const float* __restrict__ Gp,
                                                    const float* __restrict__ INV,
                                                    float* __restrict__ S2) {
  __shared__ float Hs[23][176];
  __shared__ float IVs[21];
  int b = blockIdx.x;              // 0..3199
  int g = b % 10;                  // pi-group (pi0 = 4g)
  int half = (b / 10) & 1;
  int qi = (b / 20) % 40;
  int z = b / 800;
  int qj0 = half ? 20 : 1;
  int tau0 = qj0 - 2;              // -1 or 18
  int colL = 168 * g + 39;
  const float* Gz = Gp + (long)z * GPAD_Z;
  const float* IVz = INV + z * 1600;
  int tid = threadIdx.x;

  // stage H42 tile: 23 rows x 44 f32x4 (176 cols; cols 174,175 spare)
  for (int idx = tid; idx < 23 * 44; idx += 256) {
    int row = idx / 44;
    int cv = idx - row * 44;
    int gr = qi * 42 + 43 + tau0 + row;      // 42..1721
    int gc = colL + 4 * cv;
    const float* p1 = Gz + (long)gr * 1764 + gc;
    f32x4 v = *(const f32x4u*)(p1 - 42 * 1765) + *(const f32x4u*)(p1)
            + *(const f32x4u*)(p1 + 42 * 1765);
    *reinterpret_cast<f32x4*>(&Hs[row][4 * cv]) = v;
  }
  if (tid < 21) IVs[tid] = IVz[qi * 40 + qj0 - 1 + tid];
  __syncthreads();

  // compute: 760 quad-jobs (19 q x 40 quads)
  for (int j = tid; j < 760; j += 256) {
    int jq = j / 40;
    int jp = j - jq * 40;
    int pblk = jp / 10;
    int pj0 = (jp - pblk * 10) * 4;
    int C0loc = pblk * 42 + pj0 + 4;
    int p0 = g * 160 + jp * 4;
    int qj = qj0 + jq;
    int q = qi * 40 + qj;
    f32x4 hs[5];
    #pragma unroll
    for (int s2 = 0; s2 < 5; ++s2) {
      int tr = jq + s2;
      int cc = C0loc + s2 - 2;
      f32x4 hv = {Hs[tr][cc], Hs[tr][cc + 1], Hs[tr][cc + 2], Hs[tr][cc + 3]};
      hs[s2] = hv;
    }
    f32x4 c12 = hs[1] + hs[2];
    f32x4 c23 = hs[2] + hs[3];
    f32x4 psm = hs[0] + c12;
    f32x4 ps0 = c12 + hs[3];
    f32x4 psp = c23 + hs[4];
    if (pj0 == 0) {             // crossing (t=0,d=-1)
      float pv = 0.f;
      if (p0 >= 1) {
        int C2 = pblk * 42 + 1;
        #pragma unroll
        for (int dj = -1; dj <= 1; ++dj) pv += Hs[jq + 1 + dj][C2 + dj];
      }
      psm[0] = pv;
    } else if (pj0 == 36) {     // crossing (t=3,d=+1)
      float pv = 0.f;
      if (p0 + 4 < 1600) {
        int C2 = pblk * 42 + 46;
        #pragma unroll
        for (int dj = -1; dj <= 1; ++dj) pv += Hs[jq + 3 + dj][C2 + dj];
      }
      psp[3] = pv;
    }
    float wm = IVs[jq], w0 = IVs[jq + 1], wp = IVs[jq + 2];
    f32x4 outv = psm * wm + ps0 * w0 + psp * wp;
    *reinterpret_cast<f32x4*>(S2 + ((long)z * 1600 + q) * 1600 + p0) = outv;
  }
}

// ---------------------------------------------------------------------------
// K4b v5 SLOW: rows qj in {0,39} — exact v2 slow-path body (global ps9).
// ---------------------------------------------------------------------------
__global__ __launch_bounds__(256) void s1fuse1_slow(const float* __restrict__ Gp,
                                                    const float* __restrict__ INV,
                                                    float* __restrict__ S2) {
  int z = blockIdx.y;
  unsigned int gid = blockIdx.x * 256u + threadIdx.x;  // 0..31999
  int qidx = gid / 400u;          // 0..79
  int quad = gid - qidx * 400u;
  int qi = qidx >> 1;
  int qj = (qidx & 1) * 39;
  int q = qi * 40 + qj;
  int p0 = quad * 4;
  const float* Gz = Gp + (long)z * GPAD_Z;
  const float* IVz = INV + z * 1600;
  f32x4 outv;
  #pragma unroll
  for (int t = 0; t < 4; ++t) {
    int p = p0 + t;
    float s = 0.f;
    #pragma unroll
    for (int d = -1; d <= 1; ++d) {
      int q2 = q + d, p2 = p + d;
      bool ok = ((unsigned)q2 < 1600u) && ((unsigned)p2 < 1600u);
      if (ok) s += IVz[q2] * ps9(Gz, q2, p2);
    }
    outv[t] = s;
  }
  *reinterpret_cast<f32x4*>(S2 + ((long)z * 1600 + q) * 1600 + p0) = outv;
}

// ---------------------------------------------------------------------------
// K6 v2: fuse pass 2, quad-vectorized (unchanged).
// ---------------------------------------------------------------------------
__global__ __launch_bounds__(256) void fuse2_kernel(const float* __restrict__ S2,
                                                    float* __restrict__ S3) {
  int z = blockIdx.y;
  int bx = blockIdx.x;
  int xc = bx & 7, rest = bx >> 3;
  int lid = (xc < 4 ? xc * 313 : 1252 + (xc - 4) * 312) + rest;
  unsigned int gid = (unsigned int)lid * 256u + threadIdx.x;
  int q = gid / 400u;
  int quad = gid - q * 400u;
  int p0 = quad * 4;
  const float* S = S2 + (long)z * 2560000;
  int il = q / 40, jl = q - il * 40;
  int im = p0 / 40, jm = p0 - im * 40;
  int u = jl * 40 + il;
  f32x4 acc = {0.f, 0.f, 0.f, 0.f};
  #pragma unroll
  for (int d = -1; d <= 1; ++d) {
    int u2 = u + d;
    if ((unsigned)u2 >= 1600u) continue;
    int q2 = (u2 % 40) * 40 + u2 / 40;
    int imd = im + d;
    if ((unsigned)imd < 40u) {
      acc += *reinterpret_cast<const f32x4*>(S + (long)q2 * 1600 + imd * 40 + jm);
    } else {
      #pragma unroll
      for (int t = 0; t < 4; ++t) {
        int v2 = (jm + t) * 40 + im + d;
        if ((unsigned)v2 < 1600u) {
          int p2 = (v2 % 40) * 40 + v2 / 40;
          acc[t] += S[(long)q2 * 1600 + p2];
        }
      }
    }
  }
  *reinterpret_cast<f32x4*>(S3 + ((long)z * 1600 + q) * 1600 + p0) = acc;
}

// ---------------------------------------------------------------------------
// K7a: softmax partials over q-chunks of 200, per (z,p)
// ---------------------------------------------------------------------------
__global__ __launch_bounds__(256) void smax_part(const float* __restrict__ S3,
                                                 float* __restrict__ Pm,
                                                 float* __restrict__ Ps) {
  int z = blockIdx.z, qc = blockIdx.y;
  int pl = threadIdx.x & 63;
  int ql = threadIdx.x >> 6;
  int p = blockIdx.x * 64 + pl;
  const float* S = S3 + (long)z * 2560000;
  float m = -1e30f, s = 0.f;
  for (int i = 0; i < 50; ++i) {
    int q = qc * 200 + i * 4 + ql;
    float x = 10.f * S[(long)q * 1600 + p];
    if (x > m) { s *= __expf(m - x); m = x; }
    s += __expf(x - m);
  }
  __shared__ float lm[4][64], ls[4][64];
  lm[ql][pl] = m;
  ls[ql][pl] = s;
  __syncthreads();
  if (ql == 0) {
    float M = m, SS = s;
    #pragma unroll
    for (int j = 1; j < 4; ++j) {
      float mj = lm[j][pl], sj = ls[j][pl];
      if (mj > M) { SS = SS * __expf(M - mj) + sj; M = mj; }
      else SS += sj * __expf(mj - M);
    }
    Pm[((long)z * 8 + qc) * 1600 + p] = M;
    Ps[((long)z * 8 + qc) * 1600 + p] = SS;
  }
}

// ---------------------------------------------------------------------------
// K7b: combine partials (folded, per p) -> normalize S3 -> bf16 ->
// LDS-transpose -> AT[p][q]
// ---------------------------------------------------------------------------
__global__ __launch_bounds__(256) void smax_write(const float* __restrict__ S3,
                                                  const float* __restrict__ Pm,
                                                  const float* __restrict__ Ps,
                                                  bf16* __restrict__ AT) {
  int z = blockIdx.z;
  int p0 = blockIdx.x * 64, q0 = blockIdx.y * 64;
  int pl = threadIdx.x & 63, ql = threadIdx.x >> 6;
  __shared__ float lfm[64], lfs[64];
  if (ql == 0) {
    int p = p0 + pl;
    float M = -1e30f;
    #pragma unroll
    for (int c = 0; c < 8; ++c) M = fmaxf(M, Pm[((long)z * 8 + c) * 1600 + p]);
    float S = 0.f;
    #pragma unroll
    for (int c = 0; c < 8; ++c)
      S += Ps[((long)z * 8 + c) * 1600 + p] * __expf(Pm[((long)z * 8 + c) * 1600 + p] - M);
    lfm[pl] = M;
    lfs[pl] = 1.f / S;
  }
  __syncthreads();
  __shared__ ushort_t T[64][66];
  float fm = lfm[pl];
  float fs = lfs[pl];
  const float* S = S3 + (long)z * 2560000;
  #pragma unroll
  for (int i = 0; i < 16; ++i) {
    int qq = ql + i * 4;
    float x = 10.f * S[(long)(q0 + qq) * 1600 + p0 + pl];
    bf16 h = __float2bfloat16(__expf(x - fm) * fs);
    T[pl][qq] = *reinterpret_cast<ushort_t*>(&h);
  }
  __syncthreads();
  int rp = threadIdx.x >> 5;  // 0..7
  int j = threadIdx.x & 31;
  #pragma unroll
  for (int pass = 0; pass < 8; ++pass) {
    int row = pass * 8 + rp;
    unsigned int vv = (unsigned int)T[row][2 * j] | ((unsigned int)T[row][2 * j + 1] << 16);
    *reinterpret_cast<unsigned int*>(AT + ((long)z * 1664 + p0 + row) * 1600 + q0 + 2 * j) = vv;
  }
}

// ---------------------------------------------------------------------------
// K8: RAWPT[z][(c,i,j)][q] = bf16(raw[b][c][2qi+i-1][2qj+j-1])
// ---------------------------------------------------------------------------
__global__ __launch_bounds__(256) void rawpt_kernel(const float* __restrict__ rawL,
                                                    const float* __restrict__ rawR,
                                                    bf16* __restrict__ RAWPT) {
  int z = blockIdx.z;
  int r = blockIdx.y * 4 + (threadIdx.x >> 6);
  int q = blockIdx.x * 64 + (threadIdx.x & 63);
  const float* raw = ((z < 2) ? rawL : rawR) + (long)(z & 1) * 819200;
  int c = r >> 4, i = (r >> 2) & 3, j = r & 3;
  int qi = q / 40, qj = q - qi * 40;
  int y = 2 * qi + i - 1, x = 2 * qj + j - 1;
  float v = 0.f;
  if (y >= 0 && y < 80 && x >= 0 && x < 80) v = raw[((long)c * 80 + y) * 80 + x];
  RAWPT[((long)z * 2048 + r) * 1600 + q] = __float2bfloat16(v);
}

// ---------------------------------------------------------------------------
// K10 v2: overlap-add paste, 8 consecutive x per thread, vectorized.
// ---------------------------------------------------------------------------
__global__ __launch_bounds__(256) void paste_kernel(const float* __restrict__ Z,
                                                    float* __restrict__ out) {
  int t8 = blockIdx.x * 256 + threadIdx.x;  // 0..204799, exact
  int g = t8 % 10;
  int r = t8 / 10;                           // (b,c,y)
  int x0 = g * 8;
  int h = x0 >> 1;
  int y = r % 80;
  int cc = (r / 80) % 128;
  int b = r / (80 * 128);
  int imA = (y - 1) >> 1, ipA = y - 2 * imA + 1;  // a=0:(imA,ipA) a=1:(imA+1,ipA-2)
  const long zs = 2048L * 1600;
  const float* ZL = Z + (long)b * zs;
  const float* ZR = Z + (long)(2 + b) * zs;
  f32x4 EL = {0.f,0.f,0.f,0.f}, OL = {0.f,0.f,0.f,0.f};
  f32x4 ER = {0.f,0.f,0.f,0.f}, OR_ = {0.f,0.f,0.f,0.f};
  #pragma unroll
  for (int a = 0; a < 2; ++a) {
    int im = imA + a;
    if ((unsigned)im > 39u) continue;
    int ip = ipA - 2 * a;
    long rb = (long)(cc * 16 + ip * 4) * 1600 + im * 40;
    f32x4 l3 = *(const f32x4u*)(ZL + rb + 3 * 1600 + h - 1);
    f32x4 l1 = *(const f32x4u*)(ZL + rb + 1 * 1600 + h);
    f32x4 l2 = *(const f32x4u*)(ZL + rb + 2 * 1600 + h);
    f32x4 l0 = *(const f32x4u*)(ZL + rb + 0 * 1600 + h + 1);
    f32x4 r3 = *(const f32x4u*)(ZR + rb + 3 * 1600 + h - 1);
    f32x4 r1 = *(const f32x4u*)(ZR + rb + 1 * 1600 + h);
    f32x4 r2 = *(const f32x4u*)(ZR + rb + 2 * 1600 + h);
    f32x4 r0 = *(const f32x4u*)(ZR + rb + 0 * 1600 + h + 1);
    if (x0 == 0) { l3[0] = 0.f; r3[0] = 0.f; }    // jm=-1 invalid
    if (x0 == 72) { l0[3] = 0.f; r0[3] = 0.f; }   // jm=40 invalid
    EL += l3 + l1; OL += l2 + l0;
    ER += r3 + r1; OR_ += r2 + r0;
  }
  f32x4 o0, o1;
  #pragma unroll
  for (int k = 0; k < 4; ++k) {
    int xe = x0 + 2 * k, xo = xe + 1;
    float ce = cosf(PI_F * xe / 79.f);
    float co = cosf(PI_F * xo / 79.f);
    float ve = 0.25f * (0.5f * (1.f + ce) * EL[k] + 0.5f * (1.f - ce) * ER[k]);
    float vo = 0.25f * (0.5f * (1.f + co) * OL[k] + 0.5f * (1.f - co) * OR_[k]);
    if (k < 2) { o0[2 * k] = ve; o0[2 * k + 1] = vo; }
    else { o1[2 * (k - 2)] = ve; o1[2 * (k - 2) + 1] = vo; }
  }
  float* dst = out + (long)r * 80 + x0;
  *reinterpret_cast<f32x4*>(dst) = o0;
  *reinterpret_cast<f32x4*>(dst + 4) = o1;
}

// ---------------------------------------------------------------------------
extern "C" void kernel_launch(void* const* d_in, const int* in_sizes, int n_in,
                              void* d_out, int out_size, void* d_ws, size_t ws_size,
                              hipStream_t stream) {
  const float* left  = (const float*)d_in[0];
  const float* right = (const float*)d_in[1];
  const float* mid   = (const float*)d_in[2];
  const float* rawL  = (const float*)d_in[3];
  const float* rawR  = (const float*)d_in[4];
  float* out = (float*)d_out;
  char* ws = (char*)d_ws;

  bf16*  PTe   = (bf16*)(ws + 0);              // [4][1664][384] bf16 (hi|lo|hi)
  bf16*  MTe   = (bf16*)(ws + 5111808);        // [2][1664][384] bf16 (hi|hi|lo)
  float* SQ    = (float*)(ws + 7667712);       // [4][1600]
  float* INV   = (float*)(ws + 7693312);       // [4][1600]
  float* Pm    = (float*)(ws + 7718912);       // [4][8][1600]
  float* Ps    = (float*)(ws + 7923712);       // [4][8][1600]
  float* X     = (float*)(ws + 8179712);       // 52.4 MB pool: Gpad -> S3 -> Z
  float* Y     = (float*)(ws + 60608512);      // 41.0 MB pool: S2 -> RAWPT
  bf16*  AT    = (bf16*)(ws + 101568512);      // [4][1664][1600] bf16 (ends ~122.9MB)
  bf16*  RAWPT = (bf16*)Y;                     // overlay (26.2 MB <= 41.0 MB)

  prep_pt<<<dim3(1600, 6, 1), 128, 0, stream>>>(left, right, mid, PTe, MTe, SQ);
  pad_invn_kernel<<<dim3(1771, 4), 256, 0, stream>>>(X, SQ, INV);
  // Gram via three-term double-bf16 MFMA (K=384), writing padded 4D layout:
  gemm_nt<<<dim3(13, 13, 4), 256, 0, stream>>>(PTe, MTe, X, 1600, 1600, 384,
                                               1664L * 384, 1664L * 384, GPAD_Z, 1, 1);
  s1fuse1_fast<<<3200, 256, 0, stream>>>(X, INV, Y);             // Gpad -> S2 (qj 1..38)
  s1fuse1_slow<<<dim3(125, 4), 256, 0, stream>>>(X, INV, Y);     // qj in {0,39}
  fuse2_kernel<<<dim3(2500, 4), 256, 0, stream>>>(Y, X);         // S2 -> S3
  smax_part<<<dim3(25, 8, 4), 256, 0, stream>>>(X, Pm, Ps);
  smax_write<<<dim3(25, 25, 4), 256, 0, stream>>>(X, Pm, Ps, AT);   // S3 -> AT
  rawpt_kernel<<<dim3(25, 512, 4), 256, 0, stream>>>(rawL, rawR, RAWPT);  // S2 dead
  // Deconv GEMM: 256x256 2-merged-phase (B reg reuse) + XCD z-chunk remap
  gemm256_nt<<<dim3(8, 7, 4), 512, 0, stream>>>(RAWPT, AT, X, 2048, 1600, 1600,
                                                2048L * 1600, 1664L * 1600, 2048L * 1600, 1664);
  paste_kernel<<<800, 256, 0, stream>>>(X, out);
}

// Round 9
// 301.218 us; speedup vs baseline: 1.1026x; 1.0025x over previous
//
#include <hip/hip_runtime.h>
#include <hip/hip_bf16.h>

typedef __hip_bfloat16 bf16;
typedef __attribute__((ext_vector_type(8))) short short8;
typedef __attribute__((ext_vector_type(4))) float f32x4;
typedef float f32x4u __attribute__((ext_vector_type(4), aligned(4)));
typedef unsigned short ushort_t;

#define PI_F 3.14159265358979323846f
#define GPAD_Z 3111696L  // 1764*1764

#define GLOAD_LDS16(gp, lp)                                                    \
  __builtin_amdgcn_global_load_lds(                                            \
      (const __attribute__((address_space(1))) unsigned int*)(gp),             \
      (__attribute__((address_space(3))) unsigned int*)(lp), 16, 0, 0)

// ---------------------------------------------------------------------------
// K1: downsample (::2,::2) + transpose to [slice][q][384] bf16 with the
// three-term double-bf16 layout. Also per-pixel squared norms SQ (l/r).
// ---------------------------------------------------------------------------
__global__ __launch_bounds__(128) void prep_pt(const float* __restrict__ left,
                                               const float* __restrict__ right,
                                               const float* __restrict__ mid,
                                               bf16* __restrict__ PTe,
                                               bf16* __restrict__ MTe,
                                               float* __restrict__ SQ) {
  int q = blockIdx.x;          // 0..1599
  int y = blockIdx.y;          // 0..5
  int c = threadIdx.x;         // 0..127
  int qi = q / 40, qj = q - qi * 40;
  const float* src;
  bf16* dst;
  int b;
  bool aside = (y < 4);
  if (aside) {
    b = y & 1;
    src = (y < 2) ? left : right;
    dst = PTe + (long)y * 1664 * 384;
  } else {
    b = y - 4;
    src = mid;
    dst = MTe + (long)(y - 4) * 1664 * 384;
  }
  float v = src[(((long)b * 128 + c) * 80 + 2 * qi) * 80 + 2 * qj];
  bf16 hi = __float2bfloat16(v);
  bf16 lo = __float2bfloat16(v - __bfloat162float(hi));
  if (aside) {
    dst[(long)q * 384 + c] = hi;
    dst[(long)q * 384 + 128 + c] = lo;
    dst[(long)q * 384 + 256 + c] = hi;
  } else {
    dst[(long)q * 384 + c] = hi;
    dst[(long)q * 384 + 128 + c] = hi;
    dst[(long)q * 384 + 256 + c] = lo;
  }
  if (aside) {
    __shared__ float red[128];
    red[c] = v * v;
    __syncthreads();
    for (int s = 64; s > 0; s >>= 1) {
      if (c < s) red[c] += red[c + s];
      __syncthreads();
    }
    if (c == 0) SQ[y * 1600 + q] = red[0];
  }
}

// ---------------------------------------------------------------------------
// K2 merged: bx<1764 -> zero pad cells of Gpad row bx (z=by);
// bx>=1764 -> invN[z][q] = rsqrt( 3x3 box of SQ + 1152*EPS ), 7 blocks/z.
// ---------------------------------------------------------------------------
__global__ __launch_bounds__(256) void pad_invn_kernel(float* __restrict__ Gp,
                                                       const float* __restrict__ SQ,
                                                       float* __restrict__ INV) {
  int z = blockIdx.y;
  int bx = blockIdx.x;
  if (bx < 1764) {
    float* R = Gp + (long)z * GPAD_Z + (long)bx * 1764;
    int r42 = bx % 42;
    if (r42 == 0 || r42 == 41) {
      for (int c = threadIdx.x; c < 1764; c += 256) R[c] = 0.f;
    } else {
      for (int i = threadIdx.x; i < 84; i += 256) {
        int c = (i >> 1) * 42 + ((i & 1) ? 41 : 0);
        R[c] = 0.f;
      }
    }
  } else {
    int q = (bx - 1764) * 256 + threadIdx.x;
    if (q < 1600) {
      int qi = q / 40, qj = q - qi * 40;
      float s = 0.1152f;  // 128*3*3 * 1e-4
      #pragma unroll
      for (int di = -1; di <= 1; ++di)
        #pragma unroll
        for (int dj = -1; dj <= 1; ++dj) {
          int a = qi + di, b2 = qj + dj;
          if (a >= 0 && a < 40 && b2 >= 0 && b2 < 40) s += SQ[z * 1600 + a * 40 + b2];
        }
      INV[z * 1600 + q] = rsqrtf(s);
    }
  }
}

// ---------------------------------------------------------------------------
// K3: bf16 MFMA GEMM (m97 structure, BK=32) — Gram GEMM only (K=384, cpad).
// ---------------------------------------------------------------------------
__global__ __launch_bounds__(256) void gemm_nt(const bf16* __restrict__ A,
                                               const bf16* __restrict__ B,
                                               float* __restrict__ C,
                                               int M, int N, int K,
                                               long Az, long Bz, long Cz,
                                               int bmod, int cpad) {
  int z = blockIdx.z;
  A += (long)z * Az;
  B += (long)(bmod ? (z & 1) : z) * Bz;
  C += (long)z * Cz;
  __shared__ bf16 As[128 * 32];  // row-major [row][32], 64 B rows, 8 KB
  __shared__ bf16 Bs[128 * 32];
  int lane = threadIdx.x & 63;
  int w = threadIdx.x >> 6;
  int mb = blockIdx.x * 128;
  int nb = blockIdx.y * 128;
  int lr = lane >> 2;
  int gb = (lane & 3) ^ ((lane >> 3) & 3);  // XOR swizzle at stage time
  int lm = lane & 15;
  int swz = (lm >> 1) & 3;
  int kb = lane >> 4;                  // 0..3 (k block of 8)
  int pos = (kb ^ swz) * 8;            // mirrored swizzle at read time
  int warow = (w >> 1) * 64;
  int wbrow = (w & 1) * 64;
  f32x4 acc[4][4];
  #pragma unroll
  for (int i = 0; i < 4; ++i)
    #pragma unroll
    for (int j = 0; j < 4; ++j) {
      f32x4 zv = {0.f, 0.f, 0.f, 0.f};
      acc[i][j] = zv;
    }
  for (int k0 = 0; k0 < K; k0 += 32) {
    __syncthreads();
    #pragma unroll
    for (int t = 0; t < 2; ++t) {
      int r = (w * 2 + t) * 16 + lr;   // 0..127
      GLOAD_LDS16(A + (long)(mb + r) * K + k0 + gb * 8, As + (w * 2 + t) * 512);
      GLOAD_LDS16(B + (long)(nb + r) * K + k0 + gb * 8, Bs + (w * 2 + t) * 512);
    }
    __syncthreads();
    short8 af[4], bfr[4];
    #pragma unroll
    for (int i = 0; i < 4; ++i) {
      af[i]  = *reinterpret_cast<const short8*>(As + (warow + i * 16 + lm) * 32 + pos);
      bfr[i] = *reinterpret_cast<const short8*>(Bs + (wbrow + i * 16 + lm) * 32 + pos);
    }
    #pragma unroll
    for (int i = 0; i < 4; ++i)
      #pragma unroll
      for (int j = 0; j < 4; ++j)
        acc[i][j] = __builtin_amdgcn_mfma_f32_16x16x32_bf16(af[i], bfr[j], acc[i][j], 0, 0, 0);
  }
  int m0 = mb + warow;
  int n0 = nb + wbrow;
  int col = lane & 15;
  int r0 = (lane >> 4) * 4;
  #pragma unroll
  for (int i = 0; i < 4; ++i)
    #pragma unroll
    for (int j = 0; j < 4; ++j) {
      int n = n0 + j * 16 + col;
      if (n < N) {
        int nc = cpad ? ((n / 40) * 42 + (n - (n / 40) * 40) + 43) : n;
        #pragma unroll
        for (int r = 0; r < 4; ++r) {
          int m = m0 + i * 16 + r0 + r;
          if (m < M) {
            long mr = cpad ? ((long)((m / 40) * 42 + (m - (m / 40) * 40) + 43) * 1764)
                           : ((long)m * N);
            C[mr + nc] = acc[i][j][r];
          }
        }
      }
    }
}

// ---------------------------------------------------------------------------
// K9: 256x256 8-phase bf16 GEMM — REVERTED to the exact round-4/5 verified
// schedule (60.4 µs, passed): 4 quadrant phases + boundary mini-phase; all
// t+2 stages issued at the boundary (after ph3's barrier closes every read
// of the current buffer), vmcnt(6)+BAR. Spread-staging (rounds 6-8) is a
// dead end: 2-merged-phase regressed (+12 µs, m196's penalty), and both
// mid-tile same-buffer stage placements failed correctness (absmax ~4.6)
// despite clean ledgers — unmodeled LDS-DMA write/ds_read hazard that this
// boundary structure avoids by construction. XCD remap (round 4) kept:
// XCD x -> (z=x>>1, M-half=x&1), N-major; FETCH 96->33.7 MB verified.
// ---------------------------------------------------------------------------
#define BAR() __builtin_amdgcn_s_barrier()
#define LGKM0() asm volatile("s_waitcnt lgkmcnt(0)" ::: "memory")
#define STAGE_A(tt, h)                                                         \
  { long _k = (long)(tt) * 64;                                                 \
    char* _d = lds + (((tt) & 1) << 16) + (((h) * 8 + w) << 11);               \
    GLOAD_LDS16(a_row[h] + _k, _d);                                            \
    GLOAD_LDS16(a_row[h] + _k + 32, _d + 1024); }
#define STAGE_B(tt, h)                                                         \
  { long _k = (long)(tt) * 64;                                                 \
    char* _d = lds + (((tt) & 1) << 16) + 32768 + (((h) * 8 + w) << 11);       \
    GLOAD_LDS16(b_row[h] + _k, _d);                                            \
    GLOAD_LDS16(b_row[h] + _k + 32, _d + 1024); }
#define LD8(off) (*reinterpret_cast<const short8*>(lds + (off)))
#define LOAD_A(bufo, mh)                                                       \
  { _Pragma("unroll") for (int i = 0; i < 4; ++i)                              \
      { _Pragma("unroll") for (int kc = 0; kc < 2; ++kc)                       \
          a[i][kc] = LD8((bufo) + (((wm * 8 + (mh) * 4 + i) * 2 + kc) << 10) + rd_off); } }
#define LOAD_B(dst, bufo, nh)                                                  \
  { _Pragma("unroll") for (int j = 0; j < 2; ++j)                              \
      { _Pragma("unroll") for (int kc = 0; kc < 2; ++kc)                       \
          dst[j][kc] = LD8((bufo) + 32768 + (((wn * 4 + (nh) * 2 + j) * 2 + kc) << 10) + rd_off); } }
#define MFMA16(mh, nh, bset)                                                   \
  { _Pragma("unroll") for (int kc = 0; kc < 2; ++kc)                           \
      { _Pragma("unroll") for (int i = 0; i < 4; ++i)                          \
          { _Pragma("unroll") for (int j = 0; j < 2; ++j)                      \
              acc[(mh) * 4 + i][(nh) * 2 + j] = __builtin_amdgcn_mfma_f32_16x16x32_bf16( \
                  a[i][kc], bset[j][kc], acc[(mh) * 4 + i][(nh) * 2 + j], 0, 0, 0); } } }

__global__ __launch_bounds__(512, 2) void gemm256_nt(const bf16* __restrict__ A,
                                                     const bf16* __restrict__ B,
                                                     float* __restrict__ C,
                                                     int M, int N, int K,
                                                     long Az, long Bz, long Cz,
                                                     int nballoc) {
  __shared__ __align__(16) char lds[131072];  // [buf2][op2][32 subtiles x 1024B]
  // XCD remap: linear id l, XCD = l&7 -> z = x>>1, M-half = x&1; j = l>>3:
  // N-tile = j>>2 (slow), M-sub = j&3 (fast) -> 4 M-tiles share each B panel.
  int l = blockIdx.x + (blockIdx.y << 3) + blockIdx.z * 56;
  int x = l & 7;
  int j7 = l >> 3;             // 0..27
  int z = x >> 1;
  int mb = (((x & 1) << 2) + (j7 & 3)) * 256;
  int nb = (j7 >> 2) * 256;
  A += (long)z * Az;
  B += (long)z * Bz;
  C += (long)z * Cz;
  int tid = threadIdx.x;
  int lane = tid & 63;
  int w = tid >> 6;          // wave 0..7
  int wm = w >> 2;           // 0..1 (M half)
  int wn = w & 3;            // 0..3 (N quarter)
  int NT = K >> 6;

  // stage: LDS dest linear (base + lane*16); global source inverse-swizzled
  int srcb = (lane << 4) ^ (lane & 32);  // byte in 1024B subtile
  int r_src = srcb >> 6;                 // 0..15
  int c_src = (srcb & 63) >> 1;          // element 0..31 (x8 granules)
  const bf16* a_row[2];
  const bf16* b_row[2];
  #pragma unroll
  for (int h = 0; h < 2; ++h) {
    a_row[h] = A + (long)(mb + (h * 8 + w) * 16 + r_src) * K + c_src;
    int br = nb + (h * 8 + w) * 16 + r_src;
    if (br > nballoc - 1) br = nballoc - 1;  // N-tail: clamp inside allocation
    b_row[h] = B + (long)br * K + c_src;
  }
  // read: swizzled byte offset within subtile (4-way after st_16x32)
  int rd_off = (((lane & 15) << 6) | ((lane >> 4) << 4)) ^ ((lane & 8) << 2);

  short8 a[4][2], p0[2][2], p1[2][2];
  f32x4 acc[8][4];
  #pragma unroll
  for (int i = 0; i < 8; ++i)
    #pragma unroll
    for (int j = 0; j < 4; ++j) {
      f32x4 zv = {0.f, 0.f, 0.f, 0.f};
      acc[i][j] = zv;
    }

  // prologue: tile0 fully + tile1 {A0,A1,B0}; wait tile0 (3 half-tiles in flight)
  STAGE_A(0, 0); STAGE_A(0, 1); STAGE_B(0, 0); STAGE_B(0, 1);
  STAGE_A(1, 0); STAGE_A(1, 1); STAGE_B(1, 0);
  asm volatile("s_waitcnt vmcnt(6)" ::: "memory");
  BAR();

  for (int t = 0; t < NT; ++t) {
    int bufo = (t & 1) << 16;
    // phase 0: quadrant (m0,n0); stage B1 of t+1
    LOAD_A(bufo, 0);
    LOAD_B(p0, bufo, 0);
    if (t + 1 < NT) STAGE_B(t + 1, 1);
    BAR(); LGKM0();
    __builtin_amdgcn_s_setprio(1); MFMA16(0, 0, p0); __builtin_amdgcn_s_setprio(0);
    BAR();
    // phase 1: quadrant (m0,n1); A reused
    LOAD_B(p1, bufo, 1);
    BAR(); LGKM0();
    __builtin_amdgcn_s_setprio(1); MFMA16(0, 1, p1); __builtin_amdgcn_s_setprio(0);
    BAR();
    // phase 2: quadrant (m1,n1); B reused
    LOAD_A(bufo, 1);
    BAR(); LGKM0();
    __builtin_amdgcn_s_setprio(1); MFMA16(1, 1, p1); __builtin_amdgcn_s_setprio(0);
    BAR();
    // phase 3: quadrant (m1,n0)
    LOAD_B(p0, bufo, 0);
    BAR(); LGKM0();
    __builtin_amdgcn_s_setprio(1); MFMA16(1, 0, p0); __builtin_amdgcn_s_setprio(0);
    BAR();
    // boundary: stage t+2 {A0,A1,B0}, counted vmcnt(6)
    if (t + 2 < NT) {
      STAGE_A(t + 2, 0); STAGE_A(t + 2, 1); STAGE_B(t + 2, 0);
      asm volatile("s_waitcnt vmcnt(6)" ::: "memory");
      BAR();
    } else if (t + 1 < NT) {
      asm volatile("s_waitcnt vmcnt(0)" ::: "memory");  // one drain, last prefetch
      BAR();
    }
  }

  // epilogue: C/D frag = {col=lane&15, row=(lane>>4)*4+r}
  int col = lane & 15;
  int r0 = (lane >> 4) * 4;
  int m_base = mb + wm * 128;
  int n_base = nb + wn * 64;
  #pragma unroll
  for (int i = 0; i < 8; ++i)
    #pragma unroll
    for (int j = 0; j < 4; ++j) {
      int n = n_base + j * 16 + col;
      if (n < N) {
        #pragma unroll
        for (int r = 0; r < 4; ++r) {
          int m = m_base + i * 16 + r0 + r;
          C[(long)m * N + n] = acc[i][j][r];
        }
      }
    }
}

// ---------------------------------------------------------------------------
// helper: 9-tap diagonal patch sum at (q2,p2) in padded Gz (pads give zeros)
// ---------------------------------------------------------------------------
__device__ __forceinline__ float ps9(const float* __restrict__ Gz, int q2, int p2) {
  int qi2 = q2 / 40, qj2 = q2 - qi2 * 40;
  int pi2 = p2 / 40, pj2 = p2 - pi2 * 40;
  const float* base = Gz + (long)(qi2 * 42 + qj2 + 43) * 1764 + (pi2 * 42 + pj2 + 43);
  float t = 0.f;
  #pragma unroll
  for (int di = -1; di <= 1; ++di)
    #pragma unroll
    for (int dj = -1; dj <= 1; ++dj)
      t += base[(long)(di * 42 + dj) * 1765];
  return t;
}

// ---------------------------------------------------------------------------
// K4+K5 v5 FAST: LDS-tiled H42 sharing (verified round 5).
// ---------------------------------------------------------------------------
__global__ __launch_bounds__(256) void s1fuse1_fast(const float* __restrict__ Gp,
                                                    const float* __restrict__ INV,
                                                    float* __restrict__ S2) {
  __shared__ float Hs[23][176];
  __shared__ float IVs[21];
  int b = blockIdx.x;              // 0..3199
  int g = b % 10;                  // pi-group (pi0 = 4g)
  int half = (b / 10) & 1;
  int qi = (b / 20) % 40;
  int z = b / 800;
  int qj0 = half ? 20 : 1;
  int tau0 = qj0 - 2;              // -1 or 18
  int colL = 168 * g + 39;
  const float* Gz = Gp + (long)z * GPAD_Z;
  const float* IVz = INV + z * 1600;
  int tid = threadIdx.x;

  // stage H42 tile: 23 rows x 44 f32x4 (176 cols; cols 174,175 spare)
  for (int idx = tid; idx < 23 * 44; idx += 256) {
    int row = idx / 44;
    int cv = idx - row * 44;
    int gr = qi * 42 + 43 + tau0 + row;      // 42..1721
    int gc = colL + 4 * cv;
    const float* p1 = Gz + (long)gr * 1764 + gc;
    f32x4 v = *(const f32x4u*)(p1 - 42 * 1765) + *(const f32x4u*)(p1)
            + *(const f32x4u*)(p1 + 42 * 1765);
    *reinterpret_cast<f32x4*>(&Hs[row][4 * cv]) = v;
  }
  if (tid < 21) IVs[tid] = IVz[qi * 40 + qj0 - 1 + tid];
  __syncthreads();

  // compute: 760 quad-jobs (19 q x 40 quads)
  for (int j = tid; j < 760; j += 256) {
    int jq = j / 40;
    int jp = j - jq * 40;
    int pblk = jp / 10;
    int pj0 = (jp - pblk * 10) * 4;
    int C0loc = pblk * 42 + pj0 + 4;
    int p0 = g * 160 + jp * 4;
    int qj = qj0 + jq;
    int q = qi * 40 + qj;
    f32x4 hs[5];
    #pragma unroll
    for (int s2 = 0; s2 < 5; ++s2) {
      int tr = jq + s2;
      int cc = C0loc + s2 - 2;
      f32x4 hv = {Hs[tr][cc], Hs[tr][cc + 1], Hs[tr][cc + 2], Hs[tr][cc + 3]};
      hs[s2] = hv;
    }
    f32x4 c12 = hs[1] + hs[2];
    f32x4 c23 = hs[2] + hs[3];
    f32x4 psm = hs[0] + c12;
    f32x4 ps0 = c12 + hs[3];
    f32x4 psp = c23 + hs[4];
    if (pj0 == 0) {             // crossing (t=0,d=-1)
      float pv = 0.f;
      if (p0 >= 1) {
        int C2 = pblk * 42 + 1;
        #pragma unroll
        for (int dj = -1; dj <= 1; ++dj) pv += Hs[jq + 1 + dj][C2 + dj];
      }
      psm[0] = pv;
    } else if (pj0 == 36) {     // crossing (t=3,d=+1)
      float pv = 0.f;
      if (p0 + 4 < 1600) {
        int C2 = pblk * 42 + 46;
        #pragma unroll
        for (int dj = -1; dj <= 1; ++dj) pv += Hs[jq + 3 + dj][C2 + dj];
      }
      psp[3] = pv;
    }
    float wm = IVs[jq], w0 = IVs[jq + 1], wp = IVs[jq + 2];
    f32x4 outv = psm * wm + ps0 * w0 + psp * wp;
    *reinterpret_cast<f32x4*>(S2 + ((long)z * 1600 + q) * 1600 + p0) = outv;
  }
}

// ---------------------------------------------------------------------------
// K4b v5 SLOW: rows qj in {0,39} — exact v2 slow-path body (global ps9).
// ---------------------------------------------------------------------------
__global__ __launch_bounds__(256) void s1fuse1_slow(const float* __restrict__ Gp,
                                                    const float* __restrict__ INV,
                                                    float* __restrict__ S2) {
  int z = blockIdx.y;
  unsigned int gid = blockIdx.x * 256u + threadIdx.x;  // 0..31999
  int qidx = gid / 400u;          // 0..79
  int quad = gid - qidx * 400u;
  int qi = qidx >> 1;
  int qj = (qidx & 1) * 39;
  int q = qi * 40 + qj;
  int p0 = quad * 4;
  const float* Gz = Gp + (long)z * GPAD_Z;
  const float* IVz = INV + z * 1600;
  f32x4 outv;
  #pragma unroll
  for (int t = 0; t < 4; ++t) {
    int p = p0 + t;
    float s = 0.f;
    #pragma unroll
    for (int d = -1; d <= 1; ++d) {
      int q2 = q + d, p2 = p + d;
      bool ok = ((unsigned)q2 < 1600u) && ((unsigned)p2 < 1600u);
      if (ok) s += IVz[q2] * ps9(Gz, q2, p2);
    }
    outv[t] = s;
  }
  *reinterpret_cast<f32x4*>(S2 + ((long)z * 1600 + q) * 1600 + p0) = outv;
}

// ---------------------------------------------------------------------------
// K6 v2: fuse pass 2, quad-vectorized (unchanged).
// ---------------------------------------------------------------------------
__global__ __launch_bounds__(256) void fuse2_kernel(const float* __restrict__ S2,
                                                    float* __restrict__ S3) {
  int z = blockIdx.y;
  int bx = blockIdx.x;
  int xc = bx & 7, rest = bx >> 3;
  int lid = (xc < 4 ? xc * 313 : 1252 + (xc - 4) * 312) + rest;
  unsigned int gid = (unsigned int)lid * 256u + threadIdx.x;
  int q = gid / 400u;
  int quad = gid - q * 400u;
  int p0 = quad * 4;
  const float* S = S2 + (long)z * 2560000;
  int il = q / 40, jl = q - il * 40;
  int im = p0 / 40, jm = p0 - im * 40;
  int u = jl * 40 + il;
  f32x4 acc = {0.f, 0.f, 0.f, 0.f};
  #pragma unroll
  for (int d = -1; d <= 1; ++d) {
    int u2 = u + d;
    if ((unsigned)u2 >= 1600u) continue;
    int q2 = (u2 % 40) * 40 + u2 / 40;
    int imd = im + d;
    if ((unsigned)imd < 40u) {
      acc += *reinterpret_cast<const f32x4*>(S + (long)q2 * 1600 + imd * 40 + jm);
    } else {
      #pragma unroll
      for (int t = 0; t < 4; ++t) {
        int v2 = (jm + t) * 40 + im + d;
        if ((unsigned)v2 < 1600u) {
          int p2 = (v2 % 40) * 40 + v2 / 40;
          acc[t] += S[(long)q2 * 1600 + p2];
        }
      }
    }
  }
  *reinterpret_cast<f32x4*>(S3 + ((long)z * 1600 + q) * 1600 + p0) = acc;
}

// ---------------------------------------------------------------------------
// K7a: softmax partials over q-chunks of 200, per (z,p)
// ---------------------------------------------------------------------------
__global__ __launch_bounds__(256) void smax_part(const float* __restrict__ S3,
                                                 float* __restrict__ Pm,
                                                 float* __restrict__ Ps) {
  int z = blockIdx.z, qc = blockIdx.y;
  int pl = threadIdx.x & 63;
  int ql = threadIdx.x >> 6;
  int p = blockIdx.x * 64 + pl;
  const float* S = S3 + (long)z * 2560000;
  float m = -1e30f, s = 0.f;
  for (int i = 0; i < 50; ++i) {
    int q = qc * 200 + i * 4 + ql;
    float x = 10.f * S[(long)q * 1600 + p];
    if (x > m) { s *= __expf(m - x); m = x; }
    s += __expf(x - m);
  }
  __shared__ float lm[4][64], ls[4][64];
  lm[ql][pl] = m;
  ls[ql][pl] = s;
  __syncthreads();
  if (ql == 0) {
    float M = m, SS = s;
    #pragma unroll
    for (int j = 1; j < 4; ++j) {
      float mj = lm[j][pl], sj = ls[j][pl];
      if (mj > M) { SS = SS * __expf(M - mj) + sj; M = mj; }
      else SS += sj * __expf(mj - M);
    }
    Pm[((long)z * 8 + qc) * 1600 + p] = M;
    Ps[((long)z * 8 + qc) * 1600 + p] = SS;
  }
}

// ---------------------------------------------------------------------------
// K7b: combine partials (folded, per p) -> normalize S3 -> bf16 ->
// LDS-transpose -> AT[p][q]
// ---------------------------------------------------------------------------
__global__ __launch_bounds__(256) void smax_write(const float* __restrict__ S3,
                                                  const float* __restrict__ Pm,
                                                  const float* __restrict__ Ps,
                                                  bf16* __restrict__ AT) {
  int z = blockIdx.z;
  int p0 = blockIdx.x * 64, q0 = blockIdx.y * 64;
  int pl = threadIdx.x & 63, ql = threadIdx.x >> 6;
  __shared__ float lfm[64], lfs[64];
  if (ql == 0) {
    int p = p0 + pl;
    float M = -1e30f;
    #pragma unroll
    for (int c = 0; c < 8; ++c) M = fmaxf(M, Pm[((long)z * 8 + c) * 1600 + p]);
    float S = 0.f;
    #pragma unroll
    for (int c = 0; c < 8; ++c)
      S += Ps[((long)z * 8 + c) * 1600 + p] * __expf(Pm[((long)z * 8 + c) * 1600 + p] - M);
    lfm[pl] = M;
    lfs[pl] = 1.f / S;
  }
  __syncthreads();
  __shared__ ushort_t T[64][66];
  float fm = lfm[pl];
  float fs = lfs[pl];
  const float* S = S3 + (long)z * 2560000;
  #pragma unroll
  for (int i = 0; i < 16; ++i) {
    int qq = ql + i * 4;
    float x = 10.f * S[(long)(q0 + qq) * 1600 + p0 + pl];
    bf16 h = __float2bfloat16(__expf(x - fm) * fs);
    T[pl][qq] = *reinterpret_cast<ushort_t*>(&h);
  }
  __syncthreads();
  int rp = threadIdx.x >> 5;  // 0..7
  int j = threadIdx.x & 31;
  #pragma unroll
  for (int pass = 0; pass < 8; ++pass) {
    int row = pass * 8 + rp;
    unsigned int vv = (unsigned int)T[row][2 * j] | ((unsigned int)T[row][2 * j + 1] << 16);
    *reinterpret_cast<unsigned int*>(AT + ((long)z * 1664 + p0 + row) * 1600 + q0 + 2 * j) = vv;
  }
}

// ---------------------------------------------------------------------------
// K8: RAWPT[z][(c,i,j)][q] = bf16(raw[b][c][2qi+i-1][2qj+j-1])
// ---------------------------------------------------------------------------
__global__ __launch_bounds__(256) void rawpt_kernel(const float* __restrict__ rawL,
                                                    const float* __restrict__ rawR,
                                                    bf16* __restrict__ RAWPT) {
  int z = blockIdx.z;
  int r = blockIdx.y * 4 + (threadIdx.x >> 6);
  int q = blockIdx.x * 64 + (threadIdx.x & 63);
  const float* raw = ((z < 2) ? rawL : rawR) + (long)(z & 1) * 819200;
  int c = r >> 4, i = (r >> 2) & 3, j = r & 3;
  int qi = q / 40, qj = q - qi * 40;
  int y = 2 * qi + i - 1, x = 2 * qj + j - 1;
  float v = 0.f;
  if (y >= 0 && y < 80 && x >= 0 && x < 80) v = raw[((long)c * 80 + y) * 80 + x];
  RAWPT[((long)z * 2048 + r) * 1600 + q] = __float2bfloat16(v);
}

// ---------------------------------------------------------------------------
// K10 v2: overlap-add paste, 8 consecutive x per thread, vectorized.
// ---------------------------------------------------------------------------
__global__ __launch_bounds__(256) void paste_kernel(const float* __restrict__ Z,
                                                    float* __restrict__ out) {
  int t8 = blockIdx.x * 256 + threadIdx.x;  // 0..204799, exact
  int g = t8 % 10;
  int r = t8 / 10;                           // (b,c,y)
  int x0 = g * 8;
  int h = x0 >> 1;
  int y = r % 80;
  int cc = (r / 80) % 128;
  int b = r / (80 * 128);
  int imA = (y - 1) >> 1, ipA = y - 2 * imA + 1;  // a=0:(imA,ipA) a=1:(imA+1,ipA-2)
  const long zs = 2048L * 1600;
  const float* ZL = Z + (long)b * zs;
  const float* ZR = Z + (long)(2 + b) * zs;
  f32x4 EL = {0.f,0.f,0.f,0.f}, OL = {0.f,0.f,0.f,0.f};
  f32x4 ER = {0.f,0.f,0.f,0.f}, OR_ = {0.f,0.f,0.f,0.f};
  #pragma unroll
  for (int a = 0; a < 2; ++a) {
    int im = imA + a;
    if ((unsigned)im > 39u) continue;
    int ip = ipA - 2 * a;
    long rb = (long)(cc * 16 + ip * 4) * 1600 + im * 40;
    f32x4 l3 = *(const f32x4u*)(ZL + rb + 3 * 1600 + h - 1);
    f32x4 l1 = *(const f32x4u*)(ZL + rb + 1 * 1600 + h);
    f32x4 l2 = *(const f32x4u*)(ZL + rb + 2 * 1600 + h);
    f32x4 l0 = *(const f32x4u*)(ZL + rb + 0 * 1600 + h + 1);
    f32x4 r3 = *(const f32x4u*)(ZR + rb + 3 * 1600 + h - 1);
    f32x4 r1 = *(const f32x4u*)(ZR + rb + 1 * 1600 + h);
    f32x4 r2 = *(const f32x4u*)(ZR + rb + 2 * 1600 + h);
    f32x4 r0 = *(const f32x4u*)(ZR + rb + 0 * 1600 + h + 1);
    if (x0 == 0) { l3[0] = 0.f; r3[0] = 0.f; }    // jm=-1 invalid
    if (x0 == 72) { l0[3] = 0.f; r0[3] = 0.f; }   // jm=40 invalid
    EL += l3 + l1; OL += l2 + l0;
    ER += r3 + r1; OR_ += r2 + r0;
  }
  f32x4 o0, o1;
  #pragma unroll
  for (int k = 0; k < 4; ++k) {
    int xe = x0 + 2 * k, xo = xe + 1;
    float ce = cosf(PI_F * xe / 79.f);
    float co = cosf(PI_F * xo / 79.f);
    float ve = 0.25f * (0.5f * (1.f + ce) * EL[k] + 0.5f * (1.f - ce) * ER[k]);
    float vo = 0.25f * (0.5f * (1.f + co) * OL[k] + 0.5f * (1.f - co) * OR_[k]);
    if (k < 2) { o0[2 * k] = ve; o0[2 * k + 1] = vo; }
    else { o1[2 * (k - 2)] = ve; o1[2 * (k - 2) + 1] = vo; }
  }
  float* dst = out + (long)r * 80 + x0;
  *reinterpret_cast<f32x4*>(dst) = o0;
  *reinterpret_cast<f32x4*>(dst + 4) = o1;
}

// ---------------------------------------------------------------------------
extern "C" void kernel_launch(void* const* d_in, const int* in_sizes, int n_in,
                              void* d_out, int out_size, void* d_ws, size_t ws_size,
                              hipStream_t stream) {
  const float* left  = (const float*)d_in[0];
  const float* right = (const float*)d_in[1];
  const float* mid   = (const float*)d_in[2];
  const float* rawL  = (const float*)d_in[3];
  const float* rawR  = (const float*)d_in[4];
  float* out = (float*)d_out;
  char* ws = (char*)d_ws;

  bf16*  PTe   = (bf16*)(ws + 0);              // [4][1664][384] bf16 (hi|lo|hi)
  bf16*  MTe   = (bf16*)(ws + 5111808);        // [2][1664][384] bf16 (hi|hi|lo)
  float* SQ    = (float*)(ws + 7667712);       // [4][1600]
  float* INV   = (float*)(ws + 7693312);       // [4][1600]
  float* Pm    = (float*)(ws + 7718912);       // [4][8][1600]
  float* Ps    = (float*)(ws + 7923712);       // [4][8][1600]
  float* X     = (float*)(ws + 8179712);       // 52.4 MB pool: Gpad -> S3 -> Z
  float* Y     = (float*)(ws + 60608512);      // 41.0 MB pool: S2 -> RAWPT
  bf16*  AT    = (bf16*)(ws + 101568512);      // [4][1664][1600] bf16 (ends ~122.9MB)
  bf16*  RAWPT = (bf16*)Y;                     // overlay (26.2 MB <= 41.0 MB)

  prep_pt<<<dim3(1600, 6, 1), 128, 0, stream>>>(left, right, mid, PTe, MTe, SQ);
  pad_invn_kernel<<<dim3(1771, 4), 256, 0, stream>>>(X, SQ, INV);
  // Gram via three-term double-bf16 MFMA (K=384), writing padded 4D layout:
  gemm_nt<<<dim3(13, 13, 4), 256, 0, stream>>>(PTe, MTe, X, 1600, 1600, 384,
                                               1664L * 384, 1664L * 384, GPAD_Z, 1, 1);
  s1fuse1_fast<<<3200, 256, 0, stream>>>(X, INV, Y);             // Gpad -> S2 (qj 1..38)
  s1fuse1_slow<<<dim3(125, 4), 256, 0, stream>>>(X, INV, Y);     // qj in {0,39}
  fuse2_kernel<<<dim3(2500, 4), 256, 0, stream>>>(Y, X);         // S2 -> S3
  smax_part<<<dim3(25, 8, 4), 256, 0, stream>>>(X, Pm, Ps);
  smax_write<<<dim3(25, 25, 4), 256, 0, stream>>>(X, Pm, Ps, AT);   // S3 -> AT
  rawpt_kernel<<<dim3(25, 512, 4), 256, 0, stream>>>(rawL, rawR, RAWPT);  // S2 dead
  // Deconv GEMM: 256x256 round-4 verified schedule + XCD z-chunk remap
  gemm256_nt<<<dim3(8, 7, 4), 512, 0, stream>>>(RAWPT, AT, X, 2048, 1600, 1600,
                                                2048L * 1600, 1664L * 1600, 2048L * 1600, 1664);
  paste_kernel<<<800, 256, 0, stream>>>(X, out);
}

// Round 11
// 299.922 us; speedup vs baseline: 1.1074x; 1.0043x over previous
//
#include <hip/hip_runtime.h>
#include <hip/hip_bf16.h>

typedef __hip_bfloat16 bf16;
typedef __attribute__((ext_vector_type(8))) short short8;
typedef __attribute__((ext_vector_type(4))) float f32x4;
typedef float f32x4u __attribute__((ext_vector_type(4), aligned(4)));
typedef unsigned short ushort_t;

#define PI_F 3.14159265358979323846f
#define GPAD_Z 3111696L  // 1764*1764

#define GLOAD_LDS16(gp, lp)                                                    \
  __builtin_amdgcn_global_load_lds(                                            \
      (const __attribute__((address_space(1))) unsigned int*)(gp),             \
      (__attribute__((address_space(3))) unsigned int*)(lp), 16, 0, 0)

// ---------------------------------------------------------------------------
// K1: downsample (::2,::2) + transpose to [slice][q][384] bf16 with the
// three-term double-bf16 layout. Also per-pixel squared norms SQ (l/r).
// ---------------------------------------------------------------------------
__global__ __launch_bounds__(128) void prep_pt(const float* __restrict__ left,
                                               const float* __restrict__ right,
                                               const float* __restrict__ mid,
                                               bf16* __restrict__ PTe,
                                               bf16* __restrict__ MTe,
                                               float* __restrict__ SQ) {
  int q = blockIdx.x;          // 0..1599
  int y = blockIdx.y;          // 0..5
  int c = threadIdx.x;         // 0..127
  int qi = q / 40, qj = q - qi * 40;
  const float* src;
  bf16* dst;
  int b;
  bool aside = (y < 4);
  if (aside) {
    b = y & 1;
    src = (y < 2) ? left : right;
    dst = PTe + (long)y * 1664 * 384;
  } else {
    b = y - 4;
    src = mid;
    dst = MTe + (long)(y - 4) * 1664 * 384;
  }
  float v = src[(((long)b * 128 + c) * 80 + 2 * qi) * 80 + 2 * qj];
  bf16 hi = __float2bfloat16(v);
  bf16 lo = __float2bfloat16(v - __bfloat162float(hi));
  if (aside) {
    dst[(long)q * 384 + c] = hi;
    dst[(long)q * 384 + 128 + c] = lo;
    dst[(long)q * 384 + 256 + c] = hi;
  } else {
    dst[(long)q * 384 + c] = hi;
    dst[(long)q * 384 + 128 + c] = hi;
    dst[(long)q * 384 + 256 + c] = lo;
  }
  if (aside) {
    __shared__ float red[128];
    red[c] = v * v;
    __syncthreads();
    for (int s = 64; s > 0; s >>= 1) {
      if (c < s) red[c] += red[c + s];
      __syncthreads();
    }
    if (c == 0) SQ[y * 1600 + q] = red[0];
  }
}

// ---------------------------------------------------------------------------
// K2 merged: bx<1764 -> zero pad cells of Gpad row bx (z=by);
// bx>=1764 -> invN[z][q] = rsqrt( 3x3 box of SQ + 1152*EPS ), 7 blocks/z.
// ---------------------------------------------------------------------------
__global__ __launch_bounds__(256) void pad_invn_kernel(float* __restrict__ Gp,
                                                       const float* __restrict__ SQ,
                                                       float* __restrict__ INV) {
  int z = blockIdx.y;
  int bx = blockIdx.x;
  if (bx < 1764) {
    float* R = Gp + (long)z * GPAD_Z + (long)bx * 1764;
    int r42 = bx % 42;
    if (r42 == 0 || r42 == 41) {
      for (int c = threadIdx.x; c < 1764; c += 256) R[c] = 0.f;
    } else {
      for (int i = threadIdx.x; i < 84; i += 256) {
        int c = (i >> 1) * 42 + ((i & 1) ? 41 : 0);
        R[c] = 0.f;
      }
    }
  } else {
    int q = (bx - 1764) * 256 + threadIdx.x;
    if (q < 1600) {
      int qi = q / 40, qj = q - qi * 40;
      float s = 0.1152f;  // 128*3*3 * 1e-4
      #pragma unroll
      for (int di = -1; di <= 1; ++di)
        #pragma unroll
        for (int dj = -1; dj <= 1; ++dj) {
          int a = qi + di, b2 = qj + dj;
          if (a >= 0 && a < 40 && b2 >= 0 && b2 < 40) s += SQ[z * 1600 + a * 40 + b2];
        }
      INV[z * 1600 + q] = rsqrtf(s);
    }
  }
}

// ---------------------------------------------------------------------------
// K3: bf16 MFMA GEMM (m97 structure, BK=32) — Gram GEMM only (K=384, cpad).
// ---------------------------------------------------------------------------
__global__ __launch_bounds__(256) void gemm_nt(const bf16* __restrict__ A,
                                               const bf16* __restrict__ B,
                                               float* __restrict__ C,
                                               int M, int N, int K,
                                               long Az, long Bz, long Cz,
                                               int bmod, int cpad) {
  int z = blockIdx.z;
  A += (long)z * Az;
  B += (long)(bmod ? (z & 1) : z) * Bz;
  C += (long)z * Cz;
  __shared__ bf16 As[128 * 32];  // row-major [row][32], 64 B rows, 8 KB
  __shared__ bf16 Bs[128 * 32];
  int lane = threadIdx.x & 63;
  int w = threadIdx.x >> 6;
  int mb = blockIdx.x * 128;
  int nb = blockIdx.y * 128;
  int lr = lane >> 2;
  int gb = (lane & 3) ^ ((lane >> 3) & 3);  // XOR swizzle at stage time
  int lm = lane & 15;
  int swz = (lm >> 1) & 3;
  int kb = lane >> 4;                  // 0..3 (k block of 8)
  int pos = (kb ^ swz) * 8;            // mirrored swizzle at read time
  int warow = (w >> 1) * 64;
  int wbrow = (w & 1) * 64;
  f32x4 acc[4][4];
  #pragma unroll
  for (int i = 0; i < 4; ++i)
    #pragma unroll
    for (int j = 0; j < 4; ++j) {
      f32x4 zv = {0.f, 0.f, 0.f, 0.f};
      acc[i][j] = zv;
    }
  for (int k0 = 0; k0 < K; k0 += 32) {
    __syncthreads();
    #pragma unroll
    for (int t = 0; t < 2; ++t) {
      int r = (w * 2 + t) * 16 + lr;   // 0..127
      GLOAD_LDS16(A + (long)(mb + r) * K + k0 + gb * 8, As + (w * 2 + t) * 512);
      GLOAD_LDS16(B + (long)(nb + r) * K + k0 + gb * 8, Bs + (w * 2 + t) * 512);
    }
    __syncthreads();
    short8 af[4], bfr[4];
    #pragma unroll
    for (int i = 0; i < 4; ++i) {
      af[i]  = *reinterpret_cast<const short8*>(As + (warow + i * 16 + lm) * 32 + pos);
      bfr[i] = *reinterpret_cast<const short8*>(Bs + (wbrow + i * 16 + lm) * 32 + pos);
    }
    #pragma unroll
    for (int i = 0; i < 4; ++i)
      #pragma unroll
      for (int j = 0; j < 4; ++j)
        acc[i][j] = __builtin_amdgcn_mfma_f32_16x16x32_bf16(af[i], bfr[j], acc[i][j], 0, 0, 0);
  }
  int m0 = mb + warow;
  int n0 = nb + wbrow;
  int col = lane & 15;
  int r0 = (lane >> 4) * 4;
  #pragma unroll
  for (int i = 0; i < 4; ++i)
    #pragma unroll
    for (int j = 0; j < 4; ++j) {
      int n = n0 + j * 16 + col;
      if (n < N) {
        int nc = cpad ? ((n / 40) * 42 + (n - (n / 40) * 40) + 43) : n;
        #pragma unroll
        for (int r = 0; r < 4; ++r) {
          int m = m0 + i * 16 + r0 + r;
          if (m < M) {
            long mr = cpad ? ((long)((m / 40) * 42 + (m - (m / 40) * 40) + 43) * 1764)
                           : ((long)m * N);
            C[mr + nc] = acc[i][j][r];
          }
        }
      }
    }
}

// ---------------------------------------------------------------------------
// K9: 256x256 8-wave bf16 GEMM, round-11 (= round-10 resubmit after infra
// failure): verified boundary-staging schedule (rounds 4/5/9, passed 3x)
// + READ-ONLY ds prefetching. During tile t's phases buf[t&1] receives NO
// writes (all stages target the other buffer / the boundary), so ds_reads
// may be freely reordered within the tile:
//   ph0: read A0,B0,B1 (16 ds_reads) + stage B1(t+1); BAR; lgkm0; MFMA(0,0,p0)
//   ph1: prefetch A1->a2 (8 ds_reads) under MFMA(0,1,p1) (p1 ready since ph0)
//   ph2: lgkm0(a2); MFMA(1,1,p1)   [pure MFMA, no loads]
//   ph3: MFMA(1,0,p0)              [p0 register-resident, no reload]
//   boundary: STAGE{A0,A1,B0}(t+2); vmcnt(6); BAR  [UNCHANGED]
// MFMA quadrant/K order identical -> bit-identical accumulation. Staging
// placement and vmcnt ledger untouched (mid-tile same-buffer staging is an
// unmodeled hazard — rounds 7/8 failed even with clean ledgers; frozen).
// ---------------------------------------------------------------------------
#define BAR() __builtin_amdgcn_s_barrier()
#define LGKM0() asm volatile("s_waitcnt lgkmcnt(0)" ::: "memory")
#define STAGE_A(tt, h)                                                         \
  { long _k = (long)(tt) * 64;                                                 \
    char* _d = lds + (((tt) & 1) << 16) + (((h) * 8 + w) << 11);               \
    GLOAD_LDS16(a_row[h] + _k, _d);                                            \
    GLOAD_LDS16(a_row[h] + _k + 32, _d + 1024); }
#define STAGE_B(tt, h)                                                         \
  { long _k = (long)(tt) * 64;                                                 \
    char* _d = lds + (((tt) & 1) << 16) + 32768 + (((h) * 8 + w) << 11);       \
    GLOAD_LDS16(b_row[h] + _k, _d);                                            \
    GLOAD_LDS16(b_row[h] + _k + 32, _d + 1024); }
#define LD8(off) (*reinterpret_cast<const short8*>(lds + (off)))
#define LOAD_A(dst, bufo, mh)                                                  \
  { _Pragma("unroll") for (int i = 0; i < 4; ++i)                              \
      { _Pragma("unroll") for (int kc = 0; kc < 2; ++kc)                       \
          dst[i][kc] = LD8((bufo) + (((wm * 8 + (mh) * 4 + i) * 2 + kc) << 10) + rd_off); } }
#define LOAD_B(dst, bufo, nh)                                                  \
  { _Pragma("unroll") for (int j = 0; j < 2; ++j)                              \
      { _Pragma("unroll") for (int kc = 0; kc < 2; ++kc)                       \
          dst[j][kc] = LD8((bufo) + 32768 + (((wn * 4 + (nh) * 2 + j) * 2 + kc) << 10) + rd_off); } }
#define MFMA16(arr, mh, nh, bset)                                              \
  { _Pragma("unroll") for (int kc = 0; kc < 2; ++kc)                           \
      { _Pragma("unroll") for (int i = 0; i < 4; ++i)                          \
          { _Pragma("unroll") for (int j = 0; j < 2; ++j)                      \
              acc[(mh) * 4 + i][(nh) * 2 + j] = __builtin_amdgcn_mfma_f32_16x16x32_bf16( \
                  arr[i][kc], bset[j][kc], acc[(mh) * 4 + i][(nh) * 2 + j], 0, 0, 0); } } }

__global__ __launch_bounds__(512, 2) void gemm256_nt(const bf16* __restrict__ A,
                                                     const bf16* __restrict__ B,
                                                     float* __restrict__ C,
                                                     int M, int N, int K,
                                                     long Az, long Bz, long Cz,
                                                     int nballoc) {
  __shared__ __align__(16) char lds[131072];  // [buf2][op2][32 subtiles x 1024B]
  // XCD remap: linear id l, XCD = l&7 -> z = x>>1, M-half = x&1; j = l>>3:
  // N-tile = j>>2 (slow), M-sub = j&3 (fast) -> 4 M-tiles share each B panel.
  int l = blockIdx.x + (blockIdx.y << 3) + blockIdx.z * 56;
  int x = l & 7;
  int j7 = l >> 3;             // 0..27
  int z = x >> 1;
  int mb = (((x & 1) << 2) + (j7 & 3)) * 256;
  int nb = (j7 >> 2) * 256;
  A += (long)z * Az;
  B += (long)z * Bz;
  C += (long)z * Cz;
  int tid = threadIdx.x;
  int lane = tid & 63;
  int w = tid >> 6;          // wave 0..7
  int wm = w >> 2;           // 0..1 (M half)
  int wn = w & 3;            // 0..3 (N quarter)
  int NT = K >> 6;

  // stage: LDS dest linear (base + lane*16); global source inverse-swizzled
  int srcb = (lane << 4) ^ (lane & 32);  // byte in 1024B subtile
  int r_src = srcb >> 6;                 // 0..15
  int c_src = (srcb & 63) >> 1;          // element 0..31 (x8 granules)
  const bf16* a_row[2];
  const bf16* b_row[2];
  #pragma unroll
  for (int h = 0; h < 2; ++h) {
    a_row[h] = A + (long)(mb + (h * 8 + w) * 16 + r_src) * K + c_src;
    int br = nb + (h * 8 + w) * 16 + r_src;
    if (br > nballoc - 1) br = nballoc - 1;  // N-tail: clamp inside allocation
    b_row[h] = B + (long)br * K + c_src;
  }
  // read: swizzled byte offset within subtile (4-way after st_16x32)
  int rd_off = (((lane & 15) << 6) | ((lane >> 4) << 4)) ^ ((lane & 8) << 2);

  short8 a[4][2], a2[4][2], p0[2][2], p1[2][2];
  f32x4 acc[8][4];
  #pragma unroll
  for (int i = 0; i < 8; ++i)
    #pragma unroll
    for (int j = 0; j < 4; ++j) {
      f32x4 zv = {0.f, 0.f, 0.f, 0.f};
      acc[i][j] = zv;
    }

  // prologue: tile0 fully + tile1 {A0,A1,B0}; wait tile0 (3 half-tiles in flight)
  STAGE_A(0, 0); STAGE_A(0, 1); STAGE_B(0, 0); STAGE_B(0, 1);
  STAGE_A(1, 0); STAGE_A(1, 1); STAGE_B(1, 0);
  asm volatile("s_waitcnt vmcnt(6)" ::: "memory");
  BAR();

  for (int t = 0; t < NT; ++t) {
    int bufo = (t & 1) << 16;
    // phase 0: read A0,B0,B1 (16 ds_reads); stage B1 of t+1 (other buffer)
    LOAD_A(a, bufo, 0);
    LOAD_B(p0, bufo, 0);
    LOAD_B(p1, bufo, 1);
    if (t + 1 < NT) STAGE_B(t + 1, 1);
    BAR(); LGKM0();
    __builtin_amdgcn_s_setprio(1); MFMA16(a, 0, 0, p0); __builtin_amdgcn_s_setprio(0);
    BAR();
    // phase 1: prefetch A1 -> a2 under MFMA(0,1,p1); p1 ready since ph0
    LOAD_A(a2, bufo, 1);
    BAR();
    __builtin_amdgcn_s_setprio(1); MFMA16(a, 0, 1, p1); __builtin_amdgcn_s_setprio(0);
    BAR();
    // phase 2: pure MFMA (1,1,p1) using a2 (reads hidden under ph1)
    LGKM0();
    __builtin_amdgcn_s_setprio(1); MFMA16(a2, 1, 1, p1); __builtin_amdgcn_s_setprio(0);
    BAR();
    // phase 3: pure MFMA (1,0,p0); p0 register-resident
    __builtin_amdgcn_s_setprio(1); MFMA16(a2, 1, 0, p0); __builtin_amdgcn_s_setprio(0);
    BAR();
    // boundary: stage t+2 {A0,A1,B0}, counted vmcnt(6) — UNCHANGED
    if (t + 2 < NT) {
      STAGE_A(t + 2, 0); STAGE_A(t + 2, 1); STAGE_B(t + 2, 0);
      asm volatile("s_waitcnt vmcnt(6)" ::: "memory");
      BAR();
    } else if (t + 1 < NT) {
      asm volatile("s_waitcnt vmcnt(0)" ::: "memory");  // one drain, last prefetch
      BAR();
    }
  }

  // epilogue: C/D frag = {col=lane&15, row=(lane>>4)*4+r}
  int col = lane & 15;
  int r0 = (lane >> 4) * 4;
  int m_base = mb + wm * 128;
  int n_base = nb + wn * 64;
  #pragma unroll
  for (int i = 0; i < 8; ++i)
    #pragma unroll
    for (int j = 0; j < 4; ++j) {
      int n = n_base + j * 16 + col;
      if (n < N) {
        #pragma unroll
        for (int r = 0; r < 4; ++r) {
          int m = m_base + i * 16 + r0 + r;
          C[(long)m * N + n] = acc[i][j][r];
        }
      }
    }
}

// ---------------------------------------------------------------------------
// helper: 9-tap diagonal patch sum at (q2,p2) in padded Gz (pads give zeros)
// ---------------------------------------------------------------------------
__device__ __forceinline__ float ps9(const float* __restrict__ Gz, int q2, int p2) {
  int qi2 = q2 / 40, qj2 = q2 - qi2 * 40;
  int pi2 = p2 / 40, pj2 = p2 - pi2 * 40;
  const float* base = Gz + (long)(qi2 * 42 + qj2 + 43) * 1764 + (pi2 * 42 + pj2 + 43);
  float t = 0.f;
  #pragma unroll
  for (int di = -1; di <= 1; ++di)
    #pragma unroll
    for (int dj = -1; dj <= 1; ++dj)
      t += base[(long)(di * 42 + dj) * 1765];
  return t;
}

// ---------------------------------------------------------------------------
// K4+K5 v5 FAST: LDS-tiled H42 sharing (verified round 5).
// ---------------------------------------------------------------------------
__global__ __launch_bounds__(256) void s1fuse1_fast(const float* __restrict__ Gp,
                                                    const float* __restrict__ INV,
                                                    float* __restrict__ S2) {
  __shared__ float Hs[23][176];
  __shared__ float IVs[21];
  int b = blockIdx.x;              // 0..3199
  int g = b % 10;                  // pi-group (pi0 = 4g)
  int half = (b / 10) & 1;
  int qi = (b / 20) % 40;
  int z = b / 800;
  int qj0 = half ? 20 : 1;
  int tau0 = qj0 - 2;              // -1 or 18
  int colL = 168 * g + 39;
  const float* Gz = Gp + (long)z * GPAD_Z;
  const float* IVz = INV + z * 1600;
  int tid = threadIdx.x;

  // stage H42 tile: 23 rows x 44 f32x4 (176 cols; cols 174,175 spare)
  for (int idx = tid; idx < 23 * 44; idx += 256) {
    int row = idx / 44;
    int cv = idx - row * 44;
    int gr = qi * 42 + 43 + tau0 + row;      // 42..1721
    int gc = colL + 4 * cv;
    const float* p1 = Gz + (long)gr * 1764 + gc;
    f32x4 v = *(const f32x4u*)(p1 - 42 * 1765) + *(const f32x4u*)(p1)
            + *(const f32x4u*)(p1 + 42 * 1765);
    *reinterpret_cast<f32x4*>(&Hs[row][4 * cv]) = v;
  }
  if (tid < 21) IVs[tid] = IVz[qi * 40 + qj0 - 1 + tid];
  __syncthreads();

  // compute: 760 quad-jobs (19 q x 40 quads)
  for (int j = tid; j < 760; j += 256) {
    int jq = j / 40;
    int jp = j - jq * 40;
    int pblk = jp / 10;
    int pj0 = (jp - pblk * 10) * 4;
    int C0loc = pblk * 42 + pj0 + 4;
    int p0 = g * 160 + jp * 4;
    int qj = qj0 + jq;
    int q = qi * 40 + qj;
    f32x4 hs[5];
    #pragma unroll
    for (int s2 = 0; s2 < 5; ++s2) {
      int tr = jq + s2;
      int cc = C0loc + s2 - 2;
      f32x4 hv = {Hs[tr][cc], Hs[tr][cc + 1], Hs[tr][cc + 2], Hs[tr][cc + 3]};
      hs[s2] = hv;
    }
    f32x4 c12 = hs[1] + hs[2];
    f32x4 c23 = hs[2] + hs[3];
    f32x4 psm = hs[0] + c12;
    f32x4 ps0 = c12 + hs[3];
    f32x4 psp = c23 + hs[4];
    if (pj0 == 0) {             // crossing (t=0,d=-1)
      float pv = 0.f;
      if (p0 >= 1) {
        int C2 = pblk * 42 + 1;
        #pragma unroll
        for (int dj = -1; dj <= 1; ++dj) pv += Hs[jq + 1 + dj][C2 + dj];
      }
      psm[0] = pv;
    } else if (pj0 == 36) {     // crossing (t=3,d=+1)
      float pv = 0.f;
      if (p0 + 4 < 1600) {
        int C2 = pblk * 42 + 46;
        #pragma unroll
        for (int dj = -1; dj <= 1; ++dj) pv += Hs[jq + 3 + dj][C2 + dj];
      }
      psp[3] = pv;
    }
    float wm = IVs[jq], w0 = IVs[jq + 1], wp = IVs[jq + 2];
    f32x4 outv = psm * wm + ps0 * w0 + psp * wp;
    *reinterpret_cast<f32x4*>(S2 + ((long)z * 1600 + q) * 1600 + p0) = outv;
  }
}

// ---------------------------------------------------------------------------
// K4b v5 SLOW: rows qj in {0,39} — exact v2 slow-path body (global ps9).
// ---------------------------------------------------------------------------
__global__ __launch_bounds__(256) void s1fuse1_slow(const float* __restrict__ Gp,
                                                    const float* __restrict__ INV,
                                                    float* __restrict__ S2) {
  int z = blockIdx.y;
  unsigned int gid = blockIdx.x * 256u + threadIdx.x;  // 0..31999
  int qidx = gid / 400u;          // 0..79
  int quad = gid - qidx * 400u;
  int qi = qidx >> 1;
  int qj = (qidx & 1) * 39;
  int q = qi * 40 + qj;
  int p0 = quad * 4;
  const float* Gz = Gp + (long)z * GPAD_Z;
  const float* IVz = INV + z * 1600;
  f32x4 outv;
  #pragma unroll
  for (int t = 0; t < 4; ++t) {
    int p = p0 + t;
    float s = 0.f;
    #pragma unroll
    for (int d = -1; d <= 1; ++d) {
      int q2 = q + d, p2 = p + d;
      bool ok = ((unsigned)q2 < 1600u) && ((unsigned)p2 < 1600u);
      if (ok) s += IVz[q2] * ps9(Gz, q2, p2);
    }
    outv[t] = s;
  }
  *reinterpret_cast<f32x4*>(S2 + ((long)z * 1600 + q) * 1600 + p0) = outv;
}

// ---------------------------------------------------------------------------
// K6 v2: fuse pass 2, quad-vectorized (unchanged).
// ---------------------------------------------------------------------------
__global__ __launch_bounds__(256) void fuse2_kernel(const float* __restrict__ S2,
                                                    float* __restrict__ S3) {
  int z = blockIdx.y;
  int bx = blockIdx.x;
  int xc = bx & 7, rest = bx >> 3;
  int lid = (xc < 4 ? xc * 313 : 1252 + (xc - 4) * 312) + rest;
  unsigned int gid = (unsigned int)lid * 256u + threadIdx.x;
  int q = gid / 400u;
  int quad = gid - q * 400u;
  int p0 = quad * 4;
  const float* S = S2 + (long)z * 2560000;
  int il = q / 40, jl = q - il * 40;
  int im = p0 / 40, jm = p0 - im * 40;
  int u = jl * 40 + il;
  f32x4 acc = {0.f, 0.f, 0.f, 0.f};
  #pragma unroll
  for (int d = -1; d <= 1; ++d) {
    int u2 = u + d;
    if ((unsigned)u2 >= 1600u) continue;
    int q2 = (u2 % 40) * 40 + u2 / 40;
    int imd = im + d;
    if ((unsigned)imd < 40u) {
      acc += *reinterpret_cast<const f32x4*>(S + (long)q2 * 1600 + imd * 40 + jm);
    } else {
      #pragma unroll
      for (int t = 0; t < 4; ++t) {
        int v2 = (jm + t) * 40 + im + d;
        if ((unsigned)v2 < 1600u) {
          int p2 = (v2 % 40) * 40 + v2 / 40;
          acc[t] += S[(long)q2 * 1600 + p2];
        }
      }
    }
  }
  *reinterpret_cast<f32x4*>(S3 + ((long)z * 1600 + q) * 1600 + p0) = acc;
}

// ---------------------------------------------------------------------------
// K7a: softmax partials over q-chunks of 200, per (z,p)
// ---------------------------------------------------------------------------
__global__ __launch_bounds__(256) void smax_part(const float* __restrict__ S3,
                                                 float* __restrict__ Pm,
                                                 float* __restrict__ Ps) {
  int z = blockIdx.z, qc = blockIdx.y;
  int pl = threadIdx.x & 63;
  int ql = threadIdx.x >> 6;
  int p = blockIdx.x * 64 + pl;
  const float* S = S3 + (long)z * 2560000;
  float m = -1e30f, s = 0.f;
  for (int i = 0; i < 50; ++i) {
    int q = qc * 200 + i * 4 + ql;
    float x = 10.f * S[(long)q * 1600 + p];
    if (x > m) { s *= __expf(m - x); m = x; }
    s += __expf(x - m);
  }
  __shared__ float lm[4][64], ls[4][64];
  lm[ql][pl] = m;
  ls[ql][pl] = s;
  __syncthreads();
  if (ql == 0) {
    float M = m, SS = s;
    #pragma unroll
    for (int j = 1; j < 4; ++j) {
      float mj = lm[j][pl], sj = ls[j][pl];
      if (mj > M) { SS = SS * __expf(M - mj) + sj; M = mj; }
      else SS += sj * __expf(mj - M);
    }
    Pm[((long)z * 8 + qc) * 1600 + p] = M;
    Ps[((long)z * 8 + qc) * 1600 + p] = SS;
  }
}

// ---------------------------------------------------------------------------
// K7b: combine partials (folded, per p) -> normalize S3 -> bf16 ->
// LDS-transpose -> AT[p][q]
// ---------------------------------------------------------------------------
__global__ __launch_bounds__(256) void smax_write(const float* __restrict__ S3,
                                                  const float* __restrict__ Pm,
                                                  const float* __restrict__ Ps,
                                                  bf16* __restrict__ AT) {
  int z = blockIdx.z;
  int p0 = blockIdx.x * 64, q0 = blockIdx.y * 64;
  int pl = threadIdx.x & 63, ql = threadIdx.x >> 6;
  __shared__ float lfm[64], lfs[64];
  if (ql == 0) {
    int p = p0 + pl;
    float M = -1e30f;
    #pragma unroll
    for (int c = 0; c < 8; ++c) M = fmaxf(M, Pm[((long)z * 8 + c) * 1600 + p]);
    float S = 0.f;
    #pragma unroll
    for (int c = 0; c < 8; ++c)
      S += Ps[((long)z * 8 + c) * 1600 + p] * __expf(Pm[((long)z * 8 + c) * 1600 + p] - M);
    lfm[pl] = M;
    lfs[pl] = 1.f / S;
  }
  __syncthreads();
  __shared__ ushort_t T[64][66];
  float fm = lfm[pl];
  float fs = lfs[pl];
  const float* S = S3 + (long)z * 2560000;
  #pragma unroll
  for (int i = 0; i < 16; ++i) {
    int qq = ql + i * 4;
    float x = 10.f * S[(long)(q0 + qq) * 1600 + p0 + pl];
    bf16 h = __float2bfloat16(__expf(x - fm) * fs);
    T[pl][qq] = *reinterpret_cast<ushort_t*>(&h);
  }
  __syncthreads();
  int rp = threadIdx.x >> 5;  // 0..7
  int j = threadIdx.x & 31;
  #pragma unroll
  for (int pass = 0; pass < 8; ++pass) {
    int row = pass * 8 + rp;
    unsigned int vv = (unsigned int)T[row][2 * j] | ((unsigned int)T[row][2 * j + 1] << 16);
    *reinterpret_cast<unsigned int*>(AT + ((long)z * 1664 + p0 + row) * 1600 + q0 + 2 * j) = vv;
  }
}

// ---------------------------------------------------------------------------
// K8: RAWPT[z][(c,i,j)][q] = bf16(raw[b][c][2qi+i-1][2qj+j-1])
// ---------------------------------------------------------------------------
__global__ __launch_bounds__(256) void rawpt_kernel(const float* __restrict__ rawL,
                                                    const float* __restrict__ rawR,
                                                    bf16* __restrict__ RAWPT) {
  int z = blockIdx.z;
  int r = blockIdx.y * 4 + (threadIdx.x >> 6);
  int q = blockIdx.x * 64 + (threadIdx.x & 63);
  const float* raw = ((z < 2) ? rawL : rawR) + (long)(z & 1) * 819200;
  int c = r >> 4, i = (r >> 2) & 3, j = r & 3;
  int qi = q / 40, qj = q - qi * 40;
  int y = 2 * qi + i - 1, x = 2 * qj + j - 1;
  float v = 0.f;
  if (y >= 0 && y < 80 && x >= 0 && x < 80) v = raw[((long)c * 80 + y) * 80 + x];
  RAWPT[((long)z * 2048 + r) * 1600 + q] = __float2bfloat16(v);
}

// ---------------------------------------------------------------------------
// K10 v2: overlap-add paste, 8 consecutive x per thread, vectorized.
// ---------------------------------------------------------------------------
__global__ __launch_bounds__(256) void paste_kernel(const float* __restrict__ Z,
                                                    float* __restrict__ out) {
  int t8 = blockIdx.x * 256 + threadIdx.x;  // 0..204799, exact
  int g = t8 % 10;
  int r = t8 / 10;                           // (b,c,y)
  int x0 = g * 8;
  int h = x0 >> 1;
  int y = r % 80;
  int cc = (r / 80) % 128;
  int b = r / (80 * 128);
  int imA = (y - 1) >> 1, ipA = y - 2 * imA + 1;  // a=0:(imA,ipA) a=1:(imA+1,ipA-2)
  const long zs = 2048L * 1600;
  const float* ZL = Z + (long)b * zs;
  const float* ZR = Z + (long)(2 + b) * zs;
  f32x4 EL = {0.f,0.f,0.f,0.f}, OL = {0.f,0.f,0.f,0.f};
  f32x4 ER = {0.f,0.f,0.f,0.f}, OR_ = {0.f,0.f,0.f,0.f};
  #pragma unroll
  for (int a = 0; a < 2; ++a) {
    int im = imA + a;
    if ((unsigned)im > 39u) continue;
    int ip = ipA - 2 * a;
    long rb = (long)(cc * 16 + ip * 4) * 1600 + im * 40;
    f32x4 l3 = *(const f32x4u*)(ZL + rb + 3 * 1600 + h - 1);
    f32x4 l1 = *(const f32x4u*)(ZL + rb + 1 * 1600 + h);
    f32x4 l2 = *(const f32x4u*)(ZL + rb + 2 * 1600 + h);
    f32x4 l0 = *(const f32x4u*)(ZL + rb + 0 * 1600 + h + 1);
    f32x4 r3 = *(const f32x4u*)(ZR + rb + 3 * 1600 + h - 1);
    f32x4 r1 = *(const f32x4u*)(ZR + rb + 1 * 1600 + h);
    f32x4 r2 = *(const f32x4u*)(ZR + rb + 2 * 1600 + h);
    f32x4 r0 = *(const f32x4u*)(ZR + rb + 0 * 1600 + h + 1);
    if (x0 == 0) { l3[0] = 0.f; r3[0] = 0.f; }    // jm=-1 invalid
    if (x0 == 72) { l0[3] = 0.f; r0[3] = 0.f; }   // jm=40 invalid
    EL += l3 + l1; OL += l2 + l0;
    ER += r3 + r1; OR_ += r2 + r0;
  }
  f32x4 o0, o1;
  #pragma unroll
  for (int k = 0; k < 4; ++k) {
    int xe = x0 + 2 * k, xo = xe + 1;
    float ce = cosf(PI_F * xe / 79.f);
    float co = cosf(PI_F * xo / 79.f);
    float ve = 0.25f * (0.5f * (1.f + ce) * EL[k] + 0.5f * (1.f - ce) * ER[k]);
    float vo = 0.25f * (0.5f * (1.f + co) * OL[k] + 0.5f * (1.f - co) * OR_[k]);
    if (k < 2) { o0[2 * k] = ve; o0[2 * k + 1] = vo; }
    else { o1[2 * (k - 2)] = ve; o1[2 * (k - 2) + 1] = vo; }
  }
  float* dst = out + (long)r * 80 + x0;
  *reinterpret_cast<f32x4*>(dst) = o0;
  *reinterpret_cast<f32x4*>(dst + 4) = o1;
}

// ---------------------------------------------------------------------------
extern "C" void kernel_launch(void* const* d_in, const int* in_sizes, int n_in,
                              void* d_out, int out_size, void* d_ws, size_t ws_size,
                              hipStream_t stream) {
  const float* left  = (const float*)d_in[0];
  const float* right = (const float*)d_in[1];
  const float* mid   = (const float*)d_in[2];
  const float* rawL  = (const float*)d_in[3];
  const float* rawR  = (const float*)d_in[4];
  float* out = (float*)d_out;
  char* ws = (char*)d_ws;

  bf16*  PTe   = (bf16*)(ws + 0);              // [4][1664][384] bf16 (hi|lo|hi)
  bf16*  MTe   = (bf16*)(ws + 5111808);        // [2][1664][384] bf16 (hi|hi|lo)
  float* SQ    = (float*)(ws + 7667712);       // [4][1600]
  float* INV   = (float*)(ws + 7693312);       // [4][1600]
  float* Pm    = (float*)(ws + 7718912);       // [4][8][1600]
  float* Ps    = (float*)(ws + 7923712);       // [4][8][1600]
  float* X     = (float*)(ws + 8179712);       // 52.4 MB pool: Gpad -> S3 -> Z
  float* Y     = (float*)(ws + 60608512);      // 41.0 MB pool: S2 -> RAWPT
  bf16*  AT    = (bf16*)(ws + 101568512);      // [4][1664][1600] bf16 (ends ~122.9MB)
  bf16*  RAWPT = (bf16*)Y;                     // overlay (26.2 MB <= 41.0 MB)

  prep_pt<<<dim3(1600, 6, 1), 128, 0, stream>>>(left, right, mid, PTe, MTe, SQ);
  pad_invn_kernel<<<dim3(1771, 4), 256, 0, stream>>>(X, SQ, INV);
  // Gram via three-term double-bf16 MFMA (K=384), writing padded 4D layout:
  gemm_nt<<<dim3(13, 13, 4), 256, 0, stream>>>(PTe, MTe, X, 1600, 1600, 384,
                                               1664L * 384, 1664L * 384, GPAD_Z, 1, 1);
  s1fuse1_fast<<<3200, 256, 0, stream>>>(X, INV, Y);             // Gpad -> S2 (qj 1..38)
  s1fuse1_slow<<<dim3(125, 4), 256, 0, stream>>>(X, INV, Y);     // qj in {0,39}
  fuse2_kernel<<<dim3(2500, 4), 256, 0, stream>>>(Y, X);         // S2 -> S3
  smax_part<<<dim3(25, 8, 4), 256, 0, stream>>>(X, Pm, Ps);
  smax_write<<<dim3(25, 25, 4), 256, 0, stream>>>(X, Pm, Ps, AT);   // S3 -> AT
  rawpt_kernel<<<dim3(25, 512, 4), 256, 0, stream>>>(rawL, rawR, RAWPT);  // S2 dead
  // Deconv GEMM: verified boundary-staging schedule + read-only ds prefetch
  gemm256_nt<<<dim3(8, 7, 4), 512, 0, stream>>>(RAWPT, AT, X, 2048, 1600, 1600,
                                                2048L * 1600, 1664L * 1600, 2048L * 1600, 1664);
  paste_kernel<<<800, 256, 0, stream>>>(X, out);
}

// Round 12
// 296.910 us; speedup vs baseline: 1.1186x; 1.0101x over previous
//
#include <hip/hip_runtime.h>
#include <hip/hip_bf16.h>

typedef __hip_bfloat16 bf16;
typedef __attribute__((ext_vector_type(8))) short short8;
typedef __attribute__((ext_vector_type(4))) float f32x4;
typedef float f32x4u __attribute__((ext_vector_type(4), aligned(4)));
typedef unsigned short ushort_t;

#define PI_F 3.14159265358979323846f
#define GPAD_Z 3111696L  // 1764*1764

#define GLOAD_LDS16(gp, lp)                                                    \
  __builtin_amdgcn_global_load_lds(                                            \
      (const __attribute__((address_space(1))) unsigned int*)(gp),             \
      (__attribute__((address_space(3))) unsigned int*)(lp), 16, 0, 0)

// ---------------------------------------------------------------------------
// K1: downsample (::2,::2) + transpose to [slice][q][384] bf16 with the
// three-term double-bf16 layout. Also per-pixel squared norms SQ (l/r).
// ---------------------------------------------------------------------------
__global__ __launch_bounds__(128) void prep_pt(const float* __restrict__ left,
                                               const float* __restrict__ right,
                                               const float* __restrict__ mid,
                                               bf16* __restrict__ PTe,
                                               bf16* __restrict__ MTe,
                                               float* __restrict__ SQ) {
  int q = blockIdx.x;          // 0..1599
  int y = blockIdx.y;          // 0..5
  int c = threadIdx.x;         // 0..127
  int qi = q / 40, qj = q - qi * 40;
  const float* src;
  bf16* dst;
  int b;
  bool aside = (y < 4);
  if (aside) {
    b = y & 1;
    src = (y < 2) ? left : right;
    dst = PTe + (long)y * 1664 * 384;
  } else {
    b = y - 4;
    src = mid;
    dst = MTe + (long)(y - 4) * 1664 * 384;
  }
  float v = src[(((long)b * 128 + c) * 80 + 2 * qi) * 80 + 2 * qj];
  bf16 hi = __float2bfloat16(v);
  bf16 lo = __float2bfloat16(v - __bfloat162float(hi));
  if (aside) {
    dst[(long)q * 384 + c] = hi;
    dst[(long)q * 384 + 128 + c] = lo;
    dst[(long)q * 384 + 256 + c] = hi;
  } else {
    dst[(long)q * 384 + c] = hi;
    dst[(long)q * 384 + 128 + c] = hi;
    dst[(long)q * 384 + 256 + c] = lo;
  }
  if (aside) {
    __shared__ float red[128];
    red[c] = v * v;
    __syncthreads();
    for (int s = 64; s > 0; s >>= 1) {
      if (c < s) red[c] += red[c + s];
      __syncthreads();
    }
    if (c == 0) SQ[y * 1600 + q] = red[0];
  }
}

// ---------------------------------------------------------------------------
// K2 merged: bx<1764 -> zero pad cells of Gpad row bx (z=by);
// bx>=1764 -> invN[z][q] = rsqrt( 3x3 box of SQ + 1152*EPS ), 7 blocks/z.
// ---------------------------------------------------------------------------
__global__ __launch_bounds__(256) void pad_invn_kernel(float* __restrict__ Gp,
                                                       const float* __restrict__ SQ,
                                                       float* __restrict__ INV) {
  int z = blockIdx.y;
  int bx = blockIdx.x;
  if (bx < 1764) {
    float* R = Gp + (long)z * GPAD_Z + (long)bx * 1764;
    int r42 = bx % 42;
    if (r42 == 0 || r42 == 41) {
      for (int c = threadIdx.x; c < 1764; c += 256) R[c] = 0.f;
    } else {
      for (int i = threadIdx.x; i < 84; i += 256) {
        int c = (i >> 1) * 42 + ((i & 1) ? 41 : 0);
        R[c] = 0.f;
      }
    }
  } else {
    int q = (bx - 1764) * 256 + threadIdx.x;
    if (q < 1600) {
      int qi = q / 40, qj = q - qi * 40;
      float s = 0.1152f;  // 128*3*3 * 1e-4
      #pragma unroll
      for (int di = -1; di <= 1; ++di)
        #pragma unroll
        for (int dj = -1; dj <= 1; ++dj) {
          int a = qi + di, b2 = qj + dj;
          if (a >= 0 && a < 40 && b2 >= 0 && b2 < 40) s += SQ[z * 1600 + a * 40 + b2];
        }
      INV[z * 1600 + q] = rsqrtf(s);
    }
  }
}

// ---------------------------------------------------------------------------
// K3: bf16 MFMA GEMM (m97 structure, BK=32) — Gram GEMM only (K=384, cpad).
// ---------------------------------------------------------------------------
__global__ __launch_bounds__(256) void gemm_nt(const bf16* __restrict__ A,
                                               const bf16* __restrict__ B,
                                               float* __restrict__ C,
                                               int M, int N, int K,
                                               long Az, long Bz, long Cz,
                                               int bmod, int cpad) {
  int z = blockIdx.z;
  A += (long)z * Az;
  B += (long)(bmod ? (z & 1) : z) * Bz;
  C += (long)z * Cz;
  __shared__ bf16 As[128 * 32];  // row-major [row][32], 64 B rows, 8 KB
  __shared__ bf16 Bs[128 * 32];
  int lane = threadIdx.x & 63;
  int w = threadIdx.x >> 6;
  int mb = blockIdx.x * 128;
  int nb = blockIdx.y * 128;
  int lr = lane >> 2;
  int gb = (lane & 3) ^ ((lane >> 3) & 3);  // XOR swizzle at stage time
  int lm = lane & 15;
  int swz = (lm >> 1) & 3;
  int kb = lane >> 4;                  // 0..3 (k block of 8)
  int pos = (kb ^ swz) * 8;            // mirrored swizzle at read time
  int warow = (w >> 1) * 64;
  int wbrow = (w & 1) * 64;
  f32x4 acc[4][4];
  #pragma unroll
  for (int i = 0; i < 4; ++i)
    #pragma unroll
    for (int j = 0; j < 4; ++j) {
      f32x4 zv = {0.f, 0.f, 0.f, 0.f};
      acc[i][j] = zv;
    }
  for (int k0 = 0; k0 < K; k0 += 32) {
    __syncthreads();
    #pragma unroll
    for (int t = 0; t < 2; ++t) {
      int r = (w * 2 + t) * 16 + lr;   // 0..127
      GLOAD_LDS16(A + (long)(mb + r) * K + k0 + gb * 8, As + (w * 2 + t) * 512);
      GLOAD_LDS16(B + (long)(nb + r) * K + k0 + gb * 8, Bs + (w * 2 + t) * 512);
    }
    __syncthreads();
    short8 af[4], bfr[4];
    #pragma unroll
    for (int i = 0; i < 4; ++i) {
      af[i]  = *reinterpret_cast<const short8*>(As + (warow + i * 16 + lm) * 32 + pos);
      bfr[i] = *reinterpret_cast<const short8*>(Bs + (wbrow + i * 16 + lm) * 32 + pos);
    }
    #pragma unroll
    for (int i = 0; i < 4; ++i)
      #pragma unroll
      for (int j = 0; j < 4; ++j)
        acc[i][j] = __builtin_amdgcn_mfma_f32_16x16x32_bf16(af[i], bfr[j], acc[i][j], 0, 0, 0);
  }
  int m0 = mb + warow;
  int n0 = nb + wbrow;
  int col = lane & 15;
  int r0 = (lane >> 4) * 4;
  #pragma unroll
  for (int i = 0; i < 4; ++i)
    #pragma unroll
    for (int j = 0; j < 4; ++j) {
      int n = n0 + j * 16 + col;
      if (n < N) {
        int nc = cpad ? ((n / 40) * 42 + (n - (n / 40) * 40) + 43) : n;
        #pragma unroll
        for (int r = 0; r < 4; ++r) {
          int m = m0 + i * 16 + r0 + r;
          if (m < M) {
            long mr = cpad ? ((long)((m / 40) * 42 + (m - (m / 40) * 40) + 43) * 1764)
                           : ((long)m * N);
            C[mr + nc] = acc[i][j][r];
          }
        }
      }
    }
}

// ---------------------------------------------------------------------------
// K9 round-12: PHASE-ALIGNED LDS HALVES + spread staging (m201-style).
// Root cause of rounds 7/8 failures found: staging half h (rows h*128..+127)
// did NOT equal the row set read by quadrant h — quadrant reads interleave
// both halves via wm/wn, so mid-tile stages overwrote rows still to be read.
// Fix: remap global row-groups so half h == exactly quadrant h's read set:
//   A half h = groups {(w>>2)*8 + (w&3) + h*4}  (reads: mh selects half)
//   B half h = groups {(w>>1)*4 + (w&1) + h*2}  (reads: nh selects half)
// Read offsets: A ((mh*8+wm*4+i)*2+kc)<<10, B ((nh*8+wn*2+j)*2+kc)<<10.
// Schedule (4 phases, stages spread 1/phase, no boundary mini-phase):
//   ph0 (0,0): read A-h0,B-h0; stage B1(t+1)[other buf]
//   ph1 (0,1): read B-h1;      stage A0(t+2)  [A-h0 reads closed ph0]
//   ph2 (1,0): read A-h1;      stage B0(t+2)  [B-h0 reads closed ph0]
//   ph3 (1,1): no reads;       stage A1(t+2)  [A-h1 reads closed ph2]; vmcnt(6)
// Ledger: enter t with {A0,B0,A1}(t+1)=6; +2/phase=14 at ph3; vmcnt(6)
// drains oldest 8 = all of t+1. Tail t=NT-2: vmcnt(0). Quadrants are
// disjoint accs, per-acc K order unchanged -> bit-identical output.
// XCD remap (round 4) kept.
// ---------------------------------------------------------------------------
#define BAR() __builtin_amdgcn_s_barrier()
#define LGKM0() asm volatile("s_waitcnt lgkmcnt(0)" ::: "memory")
#define STAGE_A(tt, h)                                                         \
  { long _k = (long)(tt) * 64;                                                 \
    char* _d = lds + (((tt) & 1) << 16) + (((h) * 8 + w) << 11);               \
    GLOAD_LDS16(a_row[h] + _k, _d);                                            \
    GLOAD_LDS16(a_row[h] + _k + 32, _d + 1024); }
#define STAGE_B(tt, h)                                                         \
  { long _k = (long)(tt) * 64;                                                 \
    char* _d = lds + (((tt) & 1) << 16) + 32768 + (((h) * 8 + w) << 11);       \
    GLOAD_LDS16(b_row[h] + _k, _d);                                            \
    GLOAD_LDS16(b_row[h] + _k + 32, _d + 1024); }
#define LD8(off) (*reinterpret_cast<const short8*>(lds + (off)))
#define LOAD_A(dst, bufo, mh)                                                  \
  { _Pragma("unroll") for (int i = 0; i < 4; ++i)                              \
      { _Pragma("unroll") for (int kc = 0; kc < 2; ++kc)                       \
          dst[i][kc] = LD8((bufo) + ((((mh) * 8 + wm * 4 + i) * 2 + kc) << 10) + rd_off); } }
#define LOAD_B(dst, bufo, nh)                                                  \
  { _Pragma("unroll") for (int j = 0; j < 2; ++j)                              \
      { _Pragma("unroll") for (int kc = 0; kc < 2; ++kc)                       \
          dst[j][kc] = LD8((bufo) + 32768 + ((((nh) * 8 + wn * 2 + j) * 2 + kc) << 10) + rd_off); } }
#define MFMA16(arr, mh, nh, bset)                                              \
  { _Pragma("unroll") for (int kc = 0; kc < 2; ++kc)                           \
      { _Pragma("unroll") for (int i = 0; i < 4; ++i)                          \
          { _Pragma("unroll") for (int j = 0; j < 2; ++j)                      \
              acc[(mh) * 4 + i][(nh) * 2 + j] = __builtin_amdgcn_mfma_f32_16x16x32_bf16( \
                  arr[i][kc], bset[j][kc], acc[(mh) * 4 + i][(nh) * 2 + j], 0, 0, 0); } } }

__global__ __launch_bounds__(512, 2) void gemm256_nt(const bf16* __restrict__ A,
                                                     const bf16* __restrict__ B,
                                                     float* __restrict__ C,
                                                     int M, int N, int K,
                                                     long Az, long Bz, long Cz,
                                                     int nballoc) {
  __shared__ __align__(16) char lds[131072];  // [buf2][op2][32 subtiles x 1024B]
  // XCD remap: linear id l, XCD = l&7 -> z = x>>1, M-half = x&1; j = l>>3:
  // N-tile = j>>2 (slow), M-sub = j&3 (fast) -> 4 M-tiles share each B panel.
  int l = blockIdx.x + (blockIdx.y << 3) + blockIdx.z * 56;
  int x = l & 7;
  int j7 = l >> 3;             // 0..27
  int z = x >> 1;
  int mb = (((x & 1) << 2) + (j7 & 3)) * 256;
  int nb = (j7 >> 2) * 256;
  A += (long)z * Az;
  B += (long)z * Bz;
  C += (long)z * Cz;
  int tid = threadIdx.x;
  int lane = tid & 63;
  int w = tid >> 6;          // wave 0..7
  int wm = w >> 2;           // 0..1 (M half)
  int wn = w & 3;            // 0..3 (N quarter)
  int NT = K >> 6;

  // stage: LDS dest linear (base + lane*16); global source inverse-swizzled
  int srcb = (lane << 4) ^ (lane & 32);  // byte in 1024B subtile
  int r_src = srcb >> 6;                 // 0..15
  int c_src = (srcb & 63) >> 1;          // element 0..31 (x8 granules)
  const bf16* a_row[2];
  const bf16* b_row[2];
  #pragma unroll
  for (int h = 0; h < 2; ++h) {
    int ga = (w >> 2) * 8 + (w & 3) + h * 4;   // A row-group in half h
    a_row[h] = A + (long)(mb + ga * 16 + r_src) * K + c_src;
    int gB = (w >> 1) * 4 + (w & 1) + h * 2;   // B row-group in half h
    int br = nb + gB * 16 + r_src;
    if (br > nballoc - 1) br = nballoc - 1;    // N-tail: clamp inside allocation
    b_row[h] = B + (long)br * K + c_src;
  }
  // read: swizzled byte offset within subtile (4-way after st_16x32)
  int rd_off = (((lane & 15) << 6) | ((lane >> 4) << 4)) ^ ((lane & 8) << 2);

  short8 a[4][2], p0[2][2], p1[2][2];
  f32x4 acc[8][4];
  #pragma unroll
  for (int i = 0; i < 8; ++i)
    #pragma unroll
    for (int j = 0; j < 4; ++j) {
      f32x4 zv = {0.f, 0.f, 0.f, 0.f};
      acc[i][j] = zv;
    }

  // prologue: tile0 fully + tile1 {A0,B0,A1}; wait tile0 (3 half-tiles in flight)
  STAGE_A(0, 0); STAGE_A(0, 1); STAGE_B(0, 0); STAGE_B(0, 1);
  STAGE_A(1, 0); STAGE_B(1, 0); STAGE_A(1, 1);
  asm volatile("s_waitcnt vmcnt(6)" ::: "memory");
  BAR();

  for (int t = 0; t < NT; ++t) {
    int bufo = (t & 1) << 16;
    // phase 0: quadrant (0,0); reads A-h0 + B-h0; stage B1(t+1) [other buf]
    LOAD_A(a, bufo, 0);
    LOAD_B(p0, bufo, 0);
    if (t + 1 < NT) STAGE_B(t + 1, 1);
    BAR(); LGKM0();
    __builtin_amdgcn_s_setprio(1); MFMA16(a, 0, 0, p0); __builtin_amdgcn_s_setprio(0);
    BAR();
    // phase 1: quadrant (0,1); reads B-h1; stage A0(t+2) [A-h0 closed ph0]
    LOAD_B(p1, bufo, 1);
    if (t + 2 < NT) STAGE_A(t + 2, 0);
    BAR(); LGKM0();
    __builtin_amdgcn_s_setprio(1); MFMA16(a, 0, 1, p1); __builtin_amdgcn_s_setprio(0);
    BAR();
    // phase 2: quadrant (1,0); reads A-h1; p0 register-resident;
    // stage B0(t+2) [B-h0 closed ph0]
    LOAD_A(a, bufo, 1);
    if (t + 2 < NT) STAGE_B(t + 2, 0);
    BAR(); LGKM0();
    __builtin_amdgcn_s_setprio(1); MFMA16(a, 1, 0, p0); __builtin_amdgcn_s_setprio(0);
    BAR();
    // phase 3: quadrant (1,1); no reads; stage A1(t+2) [A-h1 closed ph2];
    // counted vmcnt(6) drains all of tile t+1
    if (t + 2 < NT) {
      STAGE_A(t + 2, 1);
      asm volatile("s_waitcnt vmcnt(6)" ::: "memory");
    } else if (t + 1 < NT) {
      asm volatile("s_waitcnt vmcnt(0)" ::: "memory");  // tail: drain last prefetch
    }
    __builtin_amdgcn_s_setprio(1); MFMA16(a, 1, 1, p1); __builtin_amdgcn_s_setprio(0);
    BAR();
  }

  // epilogue: C/D frag = {col=lane&15, row=(lane>>4)*4+r}
  int col = lane & 15;
  int r0 = (lane >> 4) * 4;
  int m_base = mb + wm * 128;
  int n_base = nb + wn * 64;
  #pragma unroll
  for (int i = 0; i < 8; ++i)
    #pragma unroll
    for (int j = 0; j < 4; ++j) {
      int n = n_base + j * 16 + col;
      if (n < N) {
        #pragma unroll
        for (int r = 0; r < 4; ++r) {
          int m = m_base + i * 16 + r0 + r;
          C[(long)m * N + n] = acc[i][j][r];
        }
      }
    }
}

// ---------------------------------------------------------------------------
// helper: 9-tap diagonal patch sum at (q2,p2) in padded Gz (pads give zeros)
// ---------------------------------------------------------------------------
__device__ __forceinline__ float ps9(const float* __restrict__ Gz, int q2, int p2) {
  int qi2 = q2 / 40, qj2 = q2 - qi2 * 40;
  int pi2 = p2 / 40, pj2 = p2 - pi2 * 40;
  const float* base = Gz + (long)(qi2 * 42 + qj2 + 43) * 1764 + (pi2 * 42 + pj2 + 43);
  float t = 0.f;
  #pragma unroll
  for (int di = -1; di <= 1; ++di)
    #pragma unroll
    for (int dj = -1; dj <= 1; ++dj)
      t += base[(long)(di * 42 + dj) * 1765];
  return t;
}

// ---------------------------------------------------------------------------
// K4+K5 v5 FAST: LDS-tiled H42 sharing (verified round 5).
// ---------------------------------------------------------------------------
__global__ __launch_bounds__(256) void s1fuse1_fast(const float* __restrict__ Gp,
                                                    const float* __restrict__ INV,
                                                    float* __restrict__ S2) {
  __shared__ float Hs[23][176];
  __shared__ float IVs[21];
  int b = blockIdx.x;              // 0..3199
  int g = b % 10;                  // pi-group (pi0 = 4g)
  int half = (b / 10) & 1;
  int qi = (b / 20) % 40;
  int z = b / 800;
  int qj0 = half ? 20 : 1;
  int tau0 = qj0 - 2;              // -1 or 18
  int colL = 168 * g + 39;
  const float* Gz = Gp + (long)z * GPAD_Z;
  const float* IVz = INV + z * 1600;
  int tid = threadIdx.x;

  // stage H42 tile: 23 rows x 44 f32x4 (176 cols; cols 174,175 spare)
  for (int idx = tid; idx < 23 * 44; idx += 256) {
    int row = idx / 44;
    int cv = idx - row * 44;
    int gr = qi * 42 + 43 + tau0 + row;      // 42..1721
    int gc = colL + 4 * cv;
    const float* p1 = Gz + (long)gr * 1764 + gc;
    f32x4 v = *(const f32x4u*)(p1 - 42 * 1765) + *(const f32x4u*)(p1)
            + *(const f32x4u*)(p1 + 42 * 1765);
    *reinterpret_cast<f32x4*>(&Hs[row][4 * cv]) = v;
  }
  if (tid < 21) IVs[tid] = IVz[qi * 40 + qj0 - 1 + tid];
  __syncthreads();

  // compute: 760 quad-jobs (19 q x 40 quads)
  for (int j = tid; j < 760; j += 256) {
    int jq = j / 40;
    int jp = j - jq * 40;
    int pblk = jp / 10;
    int pj0 = (jp - pblk * 10) * 4;
    int C0loc = pblk * 42 + pj0 + 4;
    int p0 = g * 160 + jp * 4;
    int qj = qj0 + jq;
    int q = qi * 40 + qj;
    f32x4 hs[5];
    #pragma unroll
    for (int s2 = 0; s2 < 5; ++s2) {
      int tr = jq + s2;
      int cc = C0loc + s2 - 2;
      f32x4 hv = {Hs[tr][cc], Hs[tr][cc + 1], Hs[tr][cc + 2], Hs[tr][cc + 3]};
      hs[s2] = hv;
    }
    f32x4 c12 = hs[1] + hs[2];
    f32x4 c23 = hs[2] + hs[3];
    f32x4 psm = hs[0] + c12;
    f32x4 ps0 = c12 + hs[3];
    f32x4 psp = c23 + hs[4];
    if (pj0 == 0) {             // crossing (t=0,d=-1)
      float pv = 0.f;
      if (p0 >= 1) {
        int C2 = pblk * 42 + 1;
        #pragma unroll
        for (int dj = -1; dj <= 1; ++dj) pv += Hs[jq + 1 + dj][C2 + dj];
      }
      psm[0] = pv;
    } else if (pj0 == 36) {     // crossing (t=3,d=+1)
      float pv = 0.f;
      if (p0 + 4 < 1600) {
        int C2 = pblk * 42 + 46;
        #pragma unroll
        for (int dj = -1; dj <= 1; ++dj) pv += Hs[jq + 3 + dj][C2 + dj];
      }
      psp[3] = pv;
    }
    float wm = IVs[jq], w0 = IVs[jq + 1], wp = IVs[jq + 2];
    f32x4 outv = psm * wm + ps0 * w0 + psp * wp;
    *reinterpret_cast<f32x4*>(S2 + ((long)z * 1600 + q) * 1600 + p0) = outv;
  }
}

// ---------------------------------------------------------------------------
// K4b v5 SLOW: rows qj in {0,39} — exact v2 slow-path body (global ps9).
// ---------------------------------------------------------------------------
__global__ __launch_bounds__(256) void s1fuse1_slow(const float* __restrict__ Gp,
                                                    const float* __restrict__ INV,
                                                    float* __restrict__ S2) {
  int z = blockIdx.y;
  unsigned int gid = blockIdx.x * 256u + threadIdx.x;  // 0..31999
  int qidx = gid / 400u;          // 0..79
  int quad = gid - qidx * 400u;
  int qi = qidx >> 1;
  int qj = (qidx & 1) * 39;
  int q = qi * 40 + qj;
  int p0 = quad * 4;
  const float* Gz = Gp + (long)z * GPAD_Z;
  const float* IVz = INV + z * 1600;
  f32x4 outv;
  #pragma unroll
  for (int t = 0; t < 4; ++t) {
    int p = p0 + t;
    float s = 0.f;
    #pragma unroll
    for (int d = -1; d <= 1; ++d) {
      int q2 = q + d, p2 = p + d;
      bool ok = ((unsigned)q2 < 1600u) && ((unsigned)p2 < 1600u);
      if (ok) s += IVz[q2] * ps9(Gz, q2, p2);
    }
    outv[t] = s;
  }
  *reinterpret_cast<f32x4*>(S2 + ((long)z * 1600 + q) * 1600 + p0) = outv;
}

// ---------------------------------------------------------------------------
// K6 v2: fuse pass 2, quad-vectorized (unchanged).
// ---------------------------------------------------------------------------
__global__ __launch_bounds__(256) void fuse2_kernel(const float* __restrict__ S2,
                                                    float* __restrict__ S3) {
  int z = blockIdx.y;
  int bx = blockIdx.x;
  int xc = bx & 7, rest = bx >> 3;
  int lid = (xc < 4 ? xc * 313 : 1252 + (xc - 4) * 312) + rest;
  unsigned int gid = (unsigned int)lid * 256u + threadIdx.x;
  int q = gid / 400u;
  int quad = gid - q * 400u;
  int p0 = quad * 4;
  const float* S = S2 + (long)z * 2560000;
  int il = q / 40, jl = q - il * 40;
  int im = p0 / 40, jm = p0 - im * 40;
  int u = jl * 40 + il;
  f32x4 acc = {0.f, 0.f, 0.f, 0.f};
  #pragma unroll
  for (int d = -1; d <= 1; ++d) {
    int u2 = u + d;
    if ((unsigned)u2 >= 1600u) continue;
    int q2 = (u2 % 40) * 40 + u2 / 40;
    int imd = im + d;
    if ((unsigned)imd < 40u) {
      acc += *reinterpret_cast<const f32x4*>(S + (long)q2 * 1600 + imd * 40 + jm);
    } else {
      #pragma unroll
      for (int t = 0; t < 4; ++t) {
        int v2 = (jm + t) * 40 + im + d;
        if ((unsigned)v2 < 1600u) {
          int p2 = (v2 % 40) * 40 + v2 / 40;
          acc[t] += S[(long)q2 * 1600 + p2];
        }
      }
    }
  }
  *reinterpret_cast<f32x4*>(S3 + ((long)z * 1600 + q) * 1600 + p0) = acc;
}

// ---------------------------------------------------------------------------
// K7a: softmax partials over q-chunks of 200, per (z,p)
// ---------------------------------------------------------------------------
__global__ __launch_bounds__(256) void smax_part(const float* __restrict__ S3,
                                                 float* __restrict__ Pm,
                                                 float* __restrict__ Ps) {
  int z = blockIdx.z, qc = blockIdx.y;
  int pl = threadIdx.x & 63;
  int ql = threadIdx.x >> 6;
  int p = blockIdx.x * 64 + pl;
  const float* S = S3 + (long)z * 2560000;
  float m = -1e30f, s = 0.f;
  for (int i = 0; i < 50; ++i) {
    int q = qc * 200 + i * 4 + ql;
    float x = 10.f * S[(long)q * 1600 + p];
    if (x > m) { s *= __expf(m - x); m = x; }
    s += __expf(x - m);
  }
  __shared__ float lm[4][64], ls[4][64];
  lm[ql][pl] = m;
  ls[ql][pl] = s;
  __syncthreads();
  if (ql == 0) {
    float M = m, SS = s;
    #pragma unroll
    for (int j = 1; j < 4; ++j) {
      float mj = lm[j][pl], sj = ls[j][pl];
      if (mj > M) { SS = SS * __expf(M - mj) + sj; M = mj; }
      else SS += sj * __expf(mj - M);
    }
    Pm[((long)z * 8 + qc) * 1600 + p] = M;
    Ps[((long)z * 8 + qc) * 1600 + p] = SS;
  }
}

// ---------------------------------------------------------------------------
// K7b: combine partials (folded, per p) -> normalize S3 -> bf16 ->
// LDS-transpose -> AT[p][q]
// ---------------------------------------------------------------------------
__global__ __launch_bounds__(256) void smax_write(const float* __restrict__ S3,
                                                  const float* __restrict__ Pm,
                                                  const float* __restrict__ Ps,
                                                  bf16* __restrict__ AT) {
  int z = blockIdx.z;
  int p0 = blockIdx.x * 64, q0 = blockIdx.y * 64;
  int pl = threadIdx.x & 63, ql = threadIdx.x >> 6;
  __shared__ float lfm[64], lfs[64];
  if (ql == 0) {
    int p = p0 + pl;
    float M = -1e30f;
    #pragma unroll
    for (int c = 0; c < 8; ++c) M = fmaxf(M, Pm[((long)z * 8 + c) * 1600 + p]);
    float S = 0.f;
    #pragma unroll
    for (int c = 0; c < 8; ++c)
      S += Ps[((long)z * 8 + c) * 1600 + p] * __expf(Pm[((long)z * 8 + c) * 1600 + p] - M);
    lfm[pl] = M;
    lfs[pl] = 1.f / S;
  }
  __syncthreads();
  __shared__ ushort_t T[64][66];
  float fm = lfm[pl];
  float fs = lfs[pl];
  const float* S = S3 + (long)z * 2560000;
  #pragma unroll
  for (int i = 0; i < 16; ++i) {
    int qq = ql + i * 4;
    float x = 10.f * S[(long)(q0 + qq) * 1600 + p0 + pl];
    bf16 h = __float2bfloat16(__expf(x - fm) * fs);
    T[pl][qq] = *reinterpret_cast<ushort_t*>(&h);
  }
  __syncthreads();
  int rp = threadIdx.x >> 5;  // 0..7
  int j = threadIdx.x & 31;
  #pragma unroll
  for (int pass = 0; pass < 8; ++pass) {
    int row = pass * 8 + rp;
    unsigned int vv = (unsigned int)T[row][2 * j] | ((unsigned int)T[row][2 * j + 1] << 16);
    *reinterpret_cast<unsigned int*>(AT + ((long)z * 1664 + p0 + row) * 1600 + q0 + 2 * j) = vv;
  }
}

// ---------------------------------------------------------------------------
// K8: RAWPT[z][(c,i,j)][q] = bf16(raw[b][c][2qi+i-1][2qj+j-1])
// ---------------------------------------------------------------------------
__global__ __launch_bounds__(256) void rawpt_kernel(const float* __restrict__ rawL,
                                                    const float* __restrict__ rawR,
                                                    bf16* __restrict__ RAWPT) {
  int z = blockIdx.z;
  int r = blockIdx.y * 4 + (threadIdx.x >> 6);
  int q = blockIdx.x * 64 + (threadIdx.x & 63);
  const float* raw = ((z < 2) ? rawL : rawR) + (long)(z & 1) * 819200;
  int c = r >> 4, i = (r >> 2) & 3, j = r & 3;
  int qi = q / 40, qj = q - qi * 40;
  int y = 2 * qi + i - 1, x = 2 * qj + j - 1;
  float v = 0.f;
  if (y >= 0 && y < 80 && x >= 0 && x < 80) v = raw[((long)c * 80 + y) * 80 + x];
  RAWPT[((long)z * 2048 + r) * 1600 + q] = __float2bfloat16(v);
}

// ---------------------------------------------------------------------------
// K10 v2: overlap-add paste, 8 consecutive x per thread, vectorized.
// ---------------------------------------------------------------------------
__global__ __launch_bounds__(256) void paste_kernel(const float* __restrict__ Z,
                                                    float* __restrict__ out) {
  int t8 = blockIdx.x * 256 + threadIdx.x;  // 0..204799, exact
  int g = t8 % 10;
  int r = t8 / 10;                           // (b,c,y)
  int x0 = g * 8;
  int h = x0 >> 1;
  int y = r % 80;
  int cc = (r / 80) % 128;
  int b = r / (80 * 128);
  int imA = (y - 1) >> 1, ipA = y - 2 * imA + 1;  // a=0:(imA,ipA) a=1:(imA+1,ipA-2)
  const long zs = 2048L * 1600;
  const float* ZL = Z + (long)b * zs;
  const float* ZR = Z + (long)(2 + b) * zs;
  f32x4 EL = {0.f,0.f,0.f,0.f}, OL = {0.f,0.f,0.f,0.f};
  f32x4 ER = {0.f,0.f,0.f,0.f}, OR_ = {0.f,0.f,0.f,0.f};
  #pragma unroll
  for (int a = 0; a < 2; ++a) {
    int im = imA + a;
    if ((unsigned)im > 39u) continue;
    int ip = ipA - 2 * a;
    long rb = (long)(cc * 16 + ip * 4) * 1600 + im * 40;
    f32x4 l3 = *(const f32x4u*)(ZL + rb + 3 * 1600 + h - 1);
    f32x4 l1 = *(const f32x4u*)(ZL + rb + 1 * 1600 + h);
    f32x4 l2 = *(const f32x4u*)(ZL + rb + 2 * 1600 + h);
    f32x4 l0 = *(const f32x4u*)(ZL + rb + 0 * 1600 + h + 1);
    f32x4 r3 = *(const f32x4u*)(ZR + rb + 3 * 1600 + h - 1);
    f32x4 r1 = *(const f32x4u*)(ZR + rb + 1 * 1600 + h);
    f32x4 r2 = *(const f32x4u*)(ZR + rb + 2 * 1600 + h);
    f32x4 r0 = *(const f32x4u*)(ZR + rb + 0 * 1600 + h + 1);
    if (x0 == 0) { l3[0] = 0.f; r3[0] = 0.f; }    // jm=-1 invalid
    if (x0 == 72) { l0[3] = 0.f; r0[3] = 0.f; }   // jm=40 invalid
    EL += l3 + l1; OL += l2 + l0;
    ER += r3 + r1; OR_ += r2 + r0;
  }
  f32x4 o0, o1;
  #pragma unroll
  for (int k = 0; k < 4; ++k) {
    int xe = x0 + 2 * k, xo = xe + 1;
    float ce = cosf(PI_F * xe / 79.f);
    float co = cosf(PI_F * xo / 79.f);
    float ve = 0.25f * (0.5f * (1.f + ce) * EL[k] + 0.5f * (1.f - ce) * ER[k]);
    float vo = 0.25f * (0.5f * (1.f + co) * OL[k] + 0.5f * (1.f - co) * OR_[k]);
    if (k < 2) { o0[2 * k] = ve; o0[2 * k + 1] = vo; }
    else { o1[2 * (k - 2)] = ve; o1[2 * (k - 2) + 1] = vo; }
  }
  float* dst = out + (long)r * 80 + x0;
  *reinterpret_cast<f32x4*>(dst) = o0;
  *reinterpret_cast<f32x4*>(dst + 4) = o1;
}

// ---------------------------------------------------------------------------
extern "C" void kernel_launch(void* const* d_in, const int* in_sizes, int n_in,
                              void* d_out, int out_size, void* d_ws, size_t ws_size,
                              hipStream_t stream) {
  const float* left  = (const float*)d_in[0];
  const float* right = (const float*)d_in[1];
  const float* mid   = (const float*)d_in[2];
  const float* rawL  = (const float*)d_in[3];
  const float* rawR  = (const float*)d_in[4];
  float* out = (float*)d_out;
  char* ws = (char*)d_ws;

  bf16*  PTe   = (bf16*)(ws + 0);              // [4][1664][384] bf16 (hi|lo|hi)
  bf16*  MTe   = (bf16*)(ws + 5111808);        // [2][1664][384] bf16 (hi|hi|lo)
  float* SQ    = (float*)(ws + 7667712);       // [4][1600]
  float* INV   = (float*)(ws + 7693312);       // [4][1600]
  float* Pm    = (float*)(ws + 7718912);       // [4][8][1600]
  float* Ps    = (float*)(ws + 7923712);       // [4][8][1600]
  float* X     = (float*)(ws + 8179712);       // 52.4 MB pool: Gpad -> S3 -> Z
  float* Y     = (float*)(ws + 60608512);      // 41.0 MB pool: S2 -> RAWPT
  bf16*  AT    = (bf16*)(ws + 101568512);      // [4][1664][1600] bf16 (ends ~122.9MB)
  bf16*  RAWPT = (bf16*)Y;                     // overlay (26.2 MB <= 41.0 MB)

  prep_pt<<<dim3(1600, 6, 1), 128, 0, stream>>>(left, right, mid, PTe, MTe, SQ);
  pad_invn_kernel<<<dim3(1771, 4), 256, 0, stream>>>(X, SQ, INV);
  // Gram via three-term double-bf16 MFMA (K=384), writing padded 4D layout:
  gemm_nt<<<dim3(13, 13, 4), 256, 0, stream>>>(PTe, MTe, X, 1600, 1600, 384,
                                               1664L * 384, 1664L * 384, GPAD_Z, 1, 1);
  s1fuse1_fast<<<3200, 256, 0, stream>>>(X, INV, Y);             // Gpad -> S2 (qj 1..38)
  s1fuse1_slow<<<dim3(125, 4), 256, 0, stream>>>(X, INV, Y);     // qj in {0,39}
  fuse2_kernel<<<dim3(2500, 4), 256, 0, stream>>>(Y, X);         // S2 -> S3
  smax_part<<<dim3(25, 8, 4), 256, 0, stream>>>(X, Pm, Ps);
  smax_write<<<dim3(25, 25, 4), 256, 0, stream>>>(X, Pm, Ps, AT);   // S3 -> AT
  rawpt_kernel<<<dim3(25, 512, 4), 256, 0, stream>>>(rawL, rawR, RAWPT);  // S2 dead
  // Deconv GEMM: phase-aligned LDS halves + spread staging (m201-style)
  gemm256_nt<<<dim3(8, 7, 4), 512, 0, stream>>>(RAWPT, AT, X, 2048, 1600, 1600,
                                                2048L * 1600, 1664L * 1600, 2048L * 1600, 1664);
  paste_kernel<<<800, 256, 0, stream>>>(X, out);
}

// Round 13
// 289.088 us; speedup vs baseline: 1.1489x; 1.0271x over previous
//
#include <hip/hip_runtime.h>
#include <hip/hip_bf16.h>

typedef __hip_bfloat16 bf16;
typedef __attribute__((ext_vector_type(8))) short short8;
typedef __attribute__((ext_vector_type(4))) float f32x4;
typedef float f32x4u __attribute__((ext_vector_type(4), aligned(4)));
typedef unsigned short ushort_t;

#define PI_F 3.14159265358979323846f
#define GPAD_Z 3111696L  // 1764*1764

#define GLOAD_LDS16(gp, lp)                                                    \
  __builtin_amdgcn_global_load_lds(                                            \
      (const __attribute__((address_space(1))) unsigned int*)(gp),             \
      (__attribute__((address_space(3))) unsigned int*)(lp), 16, 0, 0)

// ---------------------------------------------------------------------------
// K1: downsample (::2,::2) + transpose to [slice][q][384] bf16 with the
// three-term double-bf16 layout. Also per-pixel squared norms SQ (l/r).
// ---------------------------------------------------------------------------
__global__ __launch_bounds__(128) void prep_pt(const float* __restrict__ left,
                                               const float* __restrict__ right,
                                               const float* __restrict__ mid,
                                               bf16* __restrict__ PTe,
                                               bf16* __restrict__ MTe,
                                               float* __restrict__ SQ) {
  int q = blockIdx.x;          // 0..1599
  int y = blockIdx.y;          // 0..5
  int c = threadIdx.x;         // 0..127
  int qi = q / 40, qj = q - qi * 40;
  const float* src;
  bf16* dst;
  int b;
  bool aside = (y < 4);
  if (aside) {
    b = y & 1;
    src = (y < 2) ? left : right;
    dst = PTe + (long)y * 1664 * 384;
  } else {
    b = y - 4;
    src = mid;
    dst = MTe + (long)(y - 4) * 1664 * 384;
  }
  float v = src[(((long)b * 128 + c) * 80 + 2 * qi) * 80 + 2 * qj];
  bf16 hi = __float2bfloat16(v);
  bf16 lo = __float2bfloat16(v - __bfloat162float(hi));
  if (aside) {
    dst[(long)q * 384 + c] = hi;
    dst[(long)q * 384 + 128 + c] = lo;
    dst[(long)q * 384 + 256 + c] = hi;
  } else {
    dst[(long)q * 384 + c] = hi;
    dst[(long)q * 384 + 128 + c] = hi;
    dst[(long)q * 384 + 256 + c] = lo;
  }
  if (aside) {
    __shared__ float red[128];
    red[c] = v * v;
    __syncthreads();
    for (int s = 64; s > 0; s >>= 1) {
      if (c < s) red[c] += red[c + s];
      __syncthreads();
    }
    if (c == 0) SQ[y * 1600 + q] = red[0];
  }
}

// ---------------------------------------------------------------------------
// K2 merged: bx<1764 -> zero pad cells of Gpad row bx (z=by);
// bx>=1764 -> invN[z][q] = rsqrt( 3x3 box of SQ + 1152*EPS ), 7 blocks/z.
// ---------------------------------------------------------------------------
__global__ __launch_bounds__(256) void pad_invn_kernel(float* __restrict__ Gp,
                                                       const float* __restrict__ SQ,
                                                       float* __restrict__ INV) {
  int z = blockIdx.y;
  int bx = blockIdx.x;
  if (bx < 1764) {
    float* R = Gp + (long)z * GPAD_Z + (long)bx * 1764;
    int r42 = bx % 42;
    if (r42 == 0 || r42 == 41) {
      for (int c = threadIdx.x; c < 1764; c += 256) R[c] = 0.f;
    } else {
      for (int i = threadIdx.x; i < 84; i += 256) {
        int c = (i >> 1) * 42 + ((i & 1) ? 41 : 0);
        R[c] = 0.f;
      }
    }
  } else {
    int q = (bx - 1764) * 256 + threadIdx.x;
    if (q < 1600) {
      int qi = q / 40, qj = q - qi * 40;
      float s = 0.1152f;  // 128*3*3 * 1e-4
      #pragma unroll
      for (int di = -1; di <= 1; ++di)
        #pragma unroll
        for (int dj = -1; dj <= 1; ++dj) {
          int a = qi + di, b2 = qj + dj;
          if (a >= 0 && a < 40 && b2 >= 0 && b2 < 40) s += SQ[z * 1600 + a * 40 + b2];
        }
      INV[z * 1600 + q] = rsqrtf(s);
    }
  }
}

// ---------------------------------------------------------------------------
// K3: bf16 MFMA GEMM (m97 structure, BK=32) — Gram GEMM only (K=384, cpad).
// ---------------------------------------------------------------------------
__global__ __launch_bounds__(256) void gemm_nt(const bf16* __restrict__ A,
                                               const bf16* __restrict__ B,
                                               float* __restrict__ C,
                                               int M, int N, int K,
                                               long Az, long Bz, long Cz,
                                               int bmod, int cpad) {
  int z = blockIdx.z;
  A += (long)z * Az;
  B += (long)(bmod ? (z & 1) : z) * Bz;
  C += (long)z * Cz;
  __shared__ bf16 As[128 * 32];  // row-major [row][32], 64 B rows, 8 KB
  __shared__ bf16 Bs[128 * 32];
  int lane = threadIdx.x & 63;
  int w = threadIdx.x >> 6;
  int mb = blockIdx.x * 128;
  int nb = blockIdx.y * 128;
  int lr = lane >> 2;
  int gb = (lane & 3) ^ ((lane >> 3) & 3);  // XOR swizzle at stage time
  int lm = lane & 15;
  int swz = (lm >> 1) & 3;
  int kb = lane >> 4;                  // 0..3 (k block of 8)
  int pos = (kb ^ swz) * 8;            // mirrored swizzle at read time
  int warow = (w >> 1) * 64;
  int wbrow = (w & 1) * 64;
  f32x4 acc[4][4];
  #pragma unroll
  for (int i = 0; i < 4; ++i)
    #pragma unroll
    for (int j = 0; j < 4; ++j) {
      f32x4 zv = {0.f, 0.f, 0.f, 0.f};
      acc[i][j] = zv;
    }
  for (int k0 = 0; k0 < K; k0 += 32) {
    __syncthreads();
    #pragma unroll
    for (int t = 0; t < 2; ++t) {
      int r = (w * 2 + t) * 16 + lr;   // 0..127
      GLOAD_LDS16(A + (long)(mb + r) * K + k0 + gb * 8, As + (w * 2 + t) * 512);
      GLOAD_LDS16(B + (long)(nb + r) * K + k0 + gb * 8, Bs + (w * 2 + t) * 512);
    }
    __syncthreads();
    short8 af[4], bfr[4];
    #pragma unroll
    for (int i = 0; i < 4; ++i) {
      af[i]  = *reinterpret_cast<const short8*>(As + (warow + i * 16 + lm) * 32 + pos);
      bfr[i] = *reinterpret_cast<const short8*>(Bs + (wbrow + i * 16 + lm) * 32 + pos);
    }
    #pragma unroll
    for (int i = 0; i < 4; ++i)
      #pragma unroll
      for (int j = 0; j < 4; ++j)
        acc[i][j] = __builtin_amdgcn_mfma_f32_16x16x32_bf16(af[i], bfr[j], acc[i][j], 0, 0, 0);
  }
  int m0 = mb + warow;
  int n0 = nb + wbrow;
  int col = lane & 15;
  int r0 = (lane >> 4) * 4;
  #pragma unroll
  for (int i = 0; i < 4; ++i)
    #pragma unroll
    for (int j = 0; j < 4; ++j) {
      int n = n0 + j * 16 + col;
      if (n < N) {
        int nc = cpad ? ((n / 40) * 42 + (n - (n / 40) * 40) + 43) : n;
        #pragma unroll
        for (int r = 0; r < 4; ++r) {
          int m = m0 + i * 16 + r0 + r;
          if (m < M) {
            long mr = cpad ? ((long)((m / 40) * 42 + (m - (m / 40) * 40) + 43) * 1764)
                           : ((long)m * N);
            C[mr + nc] = acc[i][j][r];
          }
        }
      }
    }
}

// ---------------------------------------------------------------------------
// K9 round-13: phase-aligned halves (round 12, verified) + SINGLE barrier
// per phase. BAR1 (between reads and MFMA) removed: MFMA consumes only the
// wave's OWN ds_read results, drained by lgkmcnt(0). The staging invariant
// needs only the end-of-phase BAR: each phase ends {lgkm0 -> MFMA -> BAR},
// so at BAR-exit ALL waves' reads of that phase's region are complete; any
// later-phase stage into that region is safe (ph1->A-h0 closed ph0;
// ph2->B-h0 closed ph0; ph3->A-h1 closed ph2; B1(t+1) other buffer).
// 4 barriers/tile (was 8). vmcnt ledger unchanged: tile t-1 ph3's vmcnt(6)
// drains the 8 oldest = {A0,B0,A1,B1}(t). Quadrant order & per-acc K-order
// unchanged -> bit-identical output. XCD remap (round 4) kept.
// ---------------------------------------------------------------------------
#define BAR() __builtin_amdgcn_s_barrier()
#define LGKM0() asm volatile("s_waitcnt lgkmcnt(0)" ::: "memory")
#define STAGE_A(tt, h)                                                         \
  { long _k = (long)(tt) * 64;                                                 \
    char* _d = lds + (((tt) & 1) << 16) + (((h) * 8 + w) << 11);               \
    GLOAD_LDS16(a_row[h] + _k, _d);                                            \
    GLOAD_LDS16(a_row[h] + _k + 32, _d + 1024); }
#define STAGE_B(tt, h)                                                         \
  { long _k = (long)(tt) * 64;                                                 \
    char* _d = lds + (((tt) & 1) << 16) + 32768 + (((h) * 8 + w) << 11);       \
    GLOAD_LDS16(b_row[h] + _k, _d);                                            \
    GLOAD_LDS16(b_row[h] + _k + 32, _d + 1024); }
#define LD8(off) (*reinterpret_cast<const short8*>(lds + (off)))
#define LOAD_A(dst, bufo, mh)                                                  \
  { _Pragma("unroll") for (int i = 0; i < 4; ++i)                              \
      { _Pragma("unroll") for (int kc = 0; kc < 2; ++kc)                       \
          dst[i][kc] = LD8((bufo) + ((((mh) * 8 + wm * 4 + i) * 2 + kc) << 10) + rd_off); } }
#define LOAD_B(dst, bufo, nh)                                                  \
  { _Pragma("unroll") for (int j = 0; j < 2; ++j)                              \
      { _Pragma("unroll") for (int kc = 0; kc < 2; ++kc)                       \
          dst[j][kc] = LD8((bufo) + 32768 + ((((nh) * 8 + wn * 2 + j) * 2 + kc) << 10) + rd_off); } }
#define MFMA16(arr, mh, nh, bset)                                              \
  { _Pragma("unroll") for (int kc = 0; kc < 2; ++kc)                           \
      { _Pragma("unroll") for (int i = 0; i < 4; ++i)                          \
          { _Pragma("unroll") for (int j = 0; j < 2; ++j)                      \
              acc[(mh) * 4 + i][(nh) * 2 + j] = __builtin_amdgcn_mfma_f32_16x16x32_bf16( \
                  arr[i][kc], bset[j][kc], acc[(mh) * 4 + i][(nh) * 2 + j], 0, 0, 0); } } }

__global__ __launch_bounds__(512, 2) void gemm256_nt(const bf16* __restrict__ A,
                                                     const bf16* __restrict__ B,
                                                     float* __restrict__ C,
                                                     int M, int N, int K,
                                                     long Az, long Bz, long Cz,
                                                     int nballoc) {
  __shared__ __align__(16) char lds[131072];  // [buf2][op2][32 subtiles x 1024B]
  // XCD remap: linear id l, XCD = l&7 -> z = x>>1, M-half = x&1; j = l>>3:
  // N-tile = j>>2 (slow), M-sub = j&3 (fast) -> 4 M-tiles share each B panel.
  int l = blockIdx.x + (blockIdx.y << 3) + blockIdx.z * 56;
  int x = l & 7;
  int j7 = l >> 3;             // 0..27
  int z = x >> 1;
  int mb = (((x & 1) << 2) + (j7 & 3)) * 256;
  int nb = (j7 >> 2) * 256;
  A += (long)z * Az;
  B += (long)z * Bz;
  C += (long)z * Cz;
  int tid = threadIdx.x;
  int lane = tid & 63;
  int w = tid >> 6;          // wave 0..7
  int wm = w >> 2;           // 0..1 (M half)
  int wn = w & 3;            // 0..3 (N quarter)
  int NT = K >> 6;

  // stage: LDS dest linear (base + lane*16); global source inverse-swizzled
  int srcb = (lane << 4) ^ (lane & 32);  // byte in 1024B subtile
  int r_src = srcb >> 6;                 // 0..15
  int c_src = (srcb & 63) >> 1;          // element 0..31 (x8 granules)
  const bf16* a_row[2];
  const bf16* b_row[2];
  #pragma unroll
  for (int h = 0; h < 2; ++h) {
    int ga = (w >> 2) * 8 + (w & 3) + h * 4;   // A row-group in half h
    a_row[h] = A + (long)(mb + ga * 16 + r_src) * K + c_src;
    int gB = (w >> 1) * 4 + (w & 1) + h * 2;   // B row-group in half h
    int br = nb + gB * 16 + r_src;
    if (br > nballoc - 1) br = nballoc - 1;    // N-tail: clamp inside allocation
    b_row[h] = B + (long)br * K + c_src;
  }
  // read: swizzled byte offset within subtile (4-way after st_16x32)
  int rd_off = (((lane & 15) << 6) | ((lane >> 4) << 4)) ^ ((lane & 8) << 2);

  short8 a[4][2], p0[2][2], p1[2][2];
  f32x4 acc[8][4];
  #pragma unroll
  for (int i = 0; i < 8; ++i)
    #pragma unroll
    for (int j = 0; j < 4; ++j) {
      f32x4 zv = {0.f, 0.f, 0.f, 0.f};
      acc[i][j] = zv;
    }

  // prologue: tile0 fully + tile1 {A0,B0,A1}; wait tile0 (3 half-tiles in flight)
  STAGE_A(0, 0); STAGE_A(0, 1); STAGE_B(0, 0); STAGE_B(0, 1);
  STAGE_A(1, 0); STAGE_B(1, 0); STAGE_A(1, 1);
  asm volatile("s_waitcnt vmcnt(6)" ::: "memory");
  BAR();

  for (int t = 0; t < NT; ++t) {
    int bufo = (t & 1) << 16;
    // phase 0: quadrant (0,0); reads A-h0 + B-h0; stage B1(t+1) [other buf]
    LOAD_A(a, bufo, 0);
    LOAD_B(p0, bufo, 0);
    if (t + 1 < NT) STAGE_B(t + 1, 1);
    LGKM0();
    __builtin_amdgcn_s_setprio(1); MFMA16(a, 0, 0, p0); __builtin_amdgcn_s_setprio(0);
    BAR();
    // phase 1: quadrant (0,1); reads B-h1; stage A0(t+2) [A-h0 closed ph0]
    LOAD_B(p1, bufo, 1);
    if (t + 2 < NT) STAGE_A(t + 2, 0);
    LGKM0();
    __builtin_amdgcn_s_setprio(1); MFMA16(a, 0, 1, p1); __builtin_amdgcn_s_setprio(0);
    BAR();
    // phase 2: quadrant (1,0); reads A-h1; p0 register-resident;
    // stage B0(t+2) [B-h0 closed ph0]
    LOAD_A(a, bufo, 1);
    if (t + 2 < NT) STAGE_B(t + 2, 0);
    LGKM0();
    __builtin_amdgcn_s_setprio(1); MFMA16(a, 1, 0, p0); __builtin_amdgcn_s_setprio(0);
    BAR();
    // phase 3: quadrant (1,1); no reads; stage A1(t+2) [A-h1 closed ph2];
    // counted vmcnt(6) drains all of tile t+1
    if (t + 2 < NT) {
      STAGE_A(t + 2, 1);
      asm volatile("s_waitcnt vmcnt(6)" ::: "memory");
    } else if (t + 1 < NT) {
      asm volatile("s_waitcnt vmcnt(0)" ::: "memory");  // tail: drain last prefetch
    }
    __builtin_amdgcn_s_setprio(1); MFMA16(a, 1, 1, p1); __builtin_amdgcn_s_setprio(0);
    BAR();
  }

  // epilogue: C/D frag = {col=lane&15, row=(lane>>4)*4+r}
  int col = lane & 15;
  int r0 = (lane >> 4) * 4;
  int m_base = mb + wm * 128;
  int n_base = nb + wn * 64;
  #pragma unroll
  for (int i = 0; i < 8; ++i)
    #pragma unroll
    for (int j = 0; j < 4; ++j) {
      int n = n_base + j * 16 + col;
      if (n < N) {
        #pragma unroll
        for (int r = 0; r < 4; ++r) {
          int m = m_base + i * 16 + r0 + r;
          C[(long)m * N + n] = acc[i][j][r];
        }
      }
    }
}

// ---------------------------------------------------------------------------
// helper: 9-tap diagonal patch sum at (q2,p2) in padded Gz (pads give zeros)
// ---------------------------------------------------------------------------
__device__ __forceinline__ float ps9(const float* __restrict__ Gz, int q2, int p2) {
  int qi2 = q2 / 40, qj2 = q2 - qi2 * 40;
  int pi2 = p2 / 40, pj2 = p2 - pi2 * 40;
  const float* base = Gz + (long)(qi2 * 42 + qj2 + 43) * 1764 + (pi2 * 42 + pj2 + 43);
  float t = 0.f;
  #pragma unroll
  for (int di = -1; di <= 1; ++di)
    #pragma unroll
    for (int dj = -1; dj <= 1; ++dj)
      t += base[(long)(di * 42 + dj) * 1765];
  return t;
}

// ---------------------------------------------------------------------------
// K4+K5 v5 FAST: LDS-tiled H42 sharing (verified round 5).
// ---------------------------------------------------------------------------
__global__ __launch_bounds__(256) void s1fuse1_fast(const float* __restrict__ Gp,
                                                    const float* __restrict__ INV,
                                                    float* __restrict__ S2) {
  __shared__ float Hs[23][176];
  __shared__ float IVs[21];
  int b = blockIdx.x;              // 0..3199
  int g = b % 10;                  // pi-group (pi0 = 4g)
  int half = (b / 10) & 1;
  int qi = (b / 20) % 40;
  int z = b / 800;
  int qj0 = half ? 20 : 1;
  int tau0 = qj0 - 2;              // -1 or 18
  int colL = 168 * g + 39;
  const float* Gz = Gp + (long)z * GPAD_Z;
  const float* IVz = INV + z * 1600;
  int tid = threadIdx.x;

  // stage H42 tile: 23 rows x 44 f32x4 (176 cols; cols 174,175 spare)
  for (int idx = tid; idx < 23 * 44; idx += 256) {
    int row = idx / 44;
    int cv = idx - row * 44;
    int gr = qi * 42 + 43 + tau0 + row;      // 42..1721
    int gc = colL + 4 * cv;
    const float* p1 = Gz + (long)gr * 1764 + gc;
    f32x4 v = *(const f32x4u*)(p1 - 42 * 1765) + *(const f32x4u*)(p1)
            + *(const f32x4u*)(p1 + 42 * 1765);
    *reinterpret_cast<f32x4*>(&Hs[row][4 * cv]) = v;
  }
  if (tid < 21) IVs[tid] = IVz[qi * 40 + qj0 - 1 + tid];
  __syncthreads();

  // compute: 760 quad-jobs (19 q x 40 quads)
  for (int j = tid; j < 760; j += 256) {
    int jq = j / 40;
    int jp = j - jq * 40;
    int pblk = jp / 10;
    int pj0 = (jp - pblk * 10) * 4;
    int C0loc = pblk * 42 + pj0 + 4;
    int p0 = g * 160 + jp * 4;
    int qj = qj0 + jq;
    int q = qi * 40 + qj;
    f32x4 hs[5];
    #pragma unroll
    for (int s2 = 0; s2 < 5; ++s2) {
      int tr = jq + s2;
      int cc = C0loc + s2 - 2;
      f32x4 hv = {Hs[tr][cc], Hs[tr][cc + 1], Hs[tr][cc + 2], Hs[tr][cc + 3]};
      hs[s2] = hv;
    }
    f32x4 c12 = hs[1] + hs[2];
    f32x4 c23 = hs[2] + hs[3];
    f32x4 psm = hs[0] + c12;
    f32x4 ps0 = c12 + hs[3];
    f32x4 psp = c23 + hs[4];
    if (pj0 == 0) {             // crossing (t=0,d=-1)
      float pv = 0.f;
      if (p0 >= 1) {
        int C2 = pblk * 42 + 1;
        #pragma unroll
        for (int dj = -1; dj <= 1; ++dj) pv += Hs[jq + 1 + dj][C2 + dj];
      }
      psm[0] = pv;
    } else if (pj0 == 36) {     // crossing (t=3,d=+1)
      float pv = 0.f;
      if (p0 + 4 < 1600) {
        int C2 = pblk * 42 + 46;
        #pragma unroll
        for (int dj = -1; dj <= 1; ++dj) pv += Hs[jq + 3 + dj][C2 + dj];
      }
      psp[3] = pv;
    }
    float wm = IVs[jq], w0 = IVs[jq + 1], wp = IVs[jq + 2];
    f32x4 outv = psm * wm + ps0 * w0 + psp * wp;
    *reinterpret_cast<f32x4*>(S2 + ((long)z * 1600 + q) * 1600 + p0) = outv;
  }
}

// ---------------------------------------------------------------------------
// K4b v5 SLOW: rows qj in {0,39} — exact v2 slow-path body (global ps9).
// ---------------------------------------------------------------------------
__global__ __launch_bounds__(256) void s1fuse1_slow(const float* __restrict__ Gp,
                                                    const float* __restrict__ INV,
                                                    float* __restrict__ S2) {
  int z = blockIdx.y;
  unsigned int gid = blockIdx.x * 256u + threadIdx.x;  // 0..31999
  int qidx = gid / 400u;          // 0..79
  int quad = gid - qidx * 400u;
  int qi = qidx >> 1;
  int qj = (qidx & 1) * 39;
  int q = qi * 40 + qj;
  int p0 = quad * 4;
  const float* Gz = Gp + (long)z * GPAD_Z;
  const float* IVz = INV + z * 1600;
  f32x4 outv;
  #pragma unroll
  for (int t = 0; t < 4; ++t) {
    int p = p0 + t;
    float s = 0.f;
    #pragma unroll
    for (int d = -1; d <= 1; ++d) {
      int q2 = q + d, p2 = p + d;
      bool ok = ((unsigned)q2 < 1600u) && ((unsigned)p2 < 1600u);
      if (ok) s += IVz[q2] * ps9(Gz, q2, p2);
    }
    outv[t] = s;
  }
  *reinterpret_cast<f32x4*>(S2 + ((long)z * 1600 + q) * 1600 + p0) = outv;
}

// ---------------------------------------------------------------------------
// K6 v2: fuse pass 2, quad-vectorized (unchanged).
// ---------------------------------------------------------------------------
__global__ __launch_bounds__(256) void fuse2_kernel(const float* __restrict__ S2,
                                                    float* __restrict__ S3) {
  int z = blockIdx.y;
  int bx = blockIdx.x;
  int xc = bx & 7, rest = bx >> 3;
  int lid = (xc < 4 ? xc * 313 : 1252 + (xc - 4) * 312) + rest;
  unsigned int gid = (unsigned int)lid * 256u + threadIdx.x;
  int q = gid / 400u;
  int quad = gid - q * 400u;
  int p0 = quad * 4;
  const float* S = S2 + (long)z * 2560000;
  int il = q / 40, jl = q - il * 40;
  int im = p0 / 40, jm = p0 - im * 40;
  int u = jl * 40 + il;
  f32x4 acc = {0.f, 0.f, 0.f, 0.f};
  #pragma unroll
  for (int d = -1; d <= 1; ++d) {
    int u2 = u + d;
    if ((unsigned)u2 >= 1600u) continue;
    int q2 = (u2 % 40) * 40 + u2 / 40;
    int imd = im + d;
    if ((unsigned)imd < 40u) {
      acc += *reinterpret_cast<const f32x4*>(S + (long)q2 * 1600 + imd * 40 + jm);
    } else {
      #pragma unroll
      for (int t = 0; t < 4; ++t) {
        int v2 = (jm + t) * 40 + im + d;
        if ((unsigned)v2 < 1600u) {
          int p2 = (v2 % 40) * 40 + v2 / 40;
          acc[t] += S[(long)q2 * 1600 + p2];
        }
      }
    }
  }
  *reinterpret_cast<f32x4*>(S3 + ((long)z * 1600 + q) * 1600 + p0) = acc;
}

// ---------------------------------------------------------------------------
// K7a: softmax partials over q-chunks of 200, per (z,p)
// ---------------------------------------------------------------------------
__global__ __launch_bounds__(256) void smax_part(const float* __restrict__ S3,
                                                 float* __restrict__ Pm,
                                                 float* __restrict__ Ps) {
  int z = blockIdx.z, qc = blockIdx.y;
  int pl = threadIdx.x & 63;
  int ql = threadIdx.x >> 6;
  int p = blockIdx.x * 64 + pl;
  const float* S = S3 + (long)z * 2560000;
  float m = -1e30f, s = 0.f;
  for (int i = 0; i < 50; ++i) {
    int q = qc * 200 + i * 4 + ql;
    float x = 10.f * S[(long)q * 1600 + p];
    if (x > m) { s *= __expf(m - x); m = x; }
    s += __expf(x - m);
  }
  __shared__ float lm[4][64], ls[4][64];
  lm[ql][pl] = m;
  ls[ql][pl] = s;
  __syncthreads();
  if (ql == 0) {
    float M = m, SS = s;
    #pragma unroll
    for (int j = 1; j < 4; ++j) {
      float mj = lm[j][pl], sj = ls[j][pl];
      if (mj > M) { SS = SS * __expf(M - mj) + sj; M = mj; }
      else SS += sj * __expf(mj - M);
    }
    Pm[((long)z * 8 + qc) * 1600 + p] = M;
    Ps[((long)z * 8 + qc) * 1600 + p] = SS;
  }
}

// ---------------------------------------------------------------------------
// K7b: combine partials (folded, per p) -> normalize S3 -> bf16 ->
// LDS-transpose -> AT[p][q]
// ---------------------------------------------------------------------------
__global__ __launch_bounds__(256) void smax_write(const float* __restrict__ S3,
                                                  const float* __restrict__ Pm,
                                                  const float* __restrict__ Ps,
                                                  bf16* __restrict__ AT) {
  int z = blockIdx.z;
  int p0 = blockIdx.x * 64, q0 = blockIdx.y * 64;
  int pl = threadIdx.x & 63, ql = threadIdx.x >> 6;
  __shared__ float lfm[64], lfs[64];
  if (ql == 0) {
    int p = p0 + pl;
    float M = -1e30f;
    #pragma unroll
    for (int c = 0; c < 8; ++c) M = fmaxf(M, Pm[((long)z * 8 + c) * 1600 + p]);
    float S = 0.f;
    #pragma unroll
    for (int c = 0; c < 8; ++c)
      S += Ps[((long)z * 8 + c) * 1600 + p] * __expf(Pm[((long)z * 8 + c) * 1600 + p] - M);
    lfm[pl] = M;
    lfs[pl] = 1.f / S;
  }
  __syncthreads();
  __shared__ ushort_t T[64][66];
  float fm = lfm[pl];
  float fs = lfs[pl];
  const float* S = S3 + (long)z * 2560000;
  #pragma unroll
  for (int i = 0; i < 16; ++i) {
    int qq = ql + i * 4;
    float x = 10.f * S[(long)(q0 + qq) * 1600 + p0 + pl];
    bf16 h = __float2bfloat16(__expf(x - fm) * fs);
    T[pl][qq] = *reinterpret_cast<ushort_t*>(&h);
  }
  __syncthreads();
  int rp = threadIdx.x >> 5;  // 0..7
  int j = threadIdx.x & 31;
  #pragma unroll
  for (int pass = 0; pass < 8; ++pass) {
    int row = pass * 8 + rp;
    unsigned int vv = (unsigned int)T[row][2 * j] | ((unsigned int)T[row][2 * j + 1] << 16);
    *reinterpret_cast<unsigned int*>(AT + ((long)z * 1664 + p0 + row) * 1600 + q0 + 2 * j) = vv;
  }
}

// ---------------------------------------------------------------------------
// K8: RAWPT[z][(c,i,j)][q] = bf16(raw[b][c][2qi+i-1][2qj+j-1])
// ---------------------------------------------------------------------------
__global__ __launch_bounds__(256) void rawpt_kernel(const float* __restrict__ rawL,
                                                    const float* __restrict__ rawR,
                                                    bf16* __restrict__ RAWPT) {
  int z = blockIdx.z;
  int r = blockIdx.y * 4 + (threadIdx.x >> 6);
  int q = blockIdx.x * 64 + (threadIdx.x & 63);
  const float* raw = ((z < 2) ? rawL : rawR) + (long)(z & 1) * 819200;
  int c = r >> 4, i = (r >> 2) & 3, j = r & 3;
  int qi = q / 40, qj = q - qi * 40;
  int y = 2 * qi + i - 1, x = 2 * qj + j - 1;
  float v = 0.f;
  if (y >= 0 && y < 80 && x >= 0 && x < 80) v = raw[((long)c * 80 + y) * 80 + x];
  RAWPT[((long)z * 2048 + r) * 1600 + q] = __float2bfloat16(v);
}

// ---------------------------------------------------------------------------
// K10 v2: overlap-add paste, 8 consecutive x per thread, vectorized.
// ---------------------------------------------------------------------------
__global__ __launch_bounds__(256) void paste_kernel(const float* __restrict__ Z,
                                                    float* __restrict__ out) {
  int t8 = blockIdx.x * 256 + threadIdx.x;  // 0..204799, exact
  int g = t8 % 10;
  int r = t8 / 10;                           // (b,c,y)
  int x0 = g * 8;
  int h = x0 >> 1;
  int y = r % 80;
  int cc = (r / 80) % 128;
  int b = r / (80 * 128);
  int imA = (y - 1) >> 1, ipA = y - 2 * imA + 1;  // a=0:(imA,ipA) a=1:(imA+1,ipA-2)
  const long zs = 2048L * 1600;
  const float* ZL = Z + (long)b * zs;
  const float* ZR = Z + (long)(2 + b) * zs;
  f32x4 EL = {0.f,0.f,0.f,0.f}, OL = {0.f,0.f,0.f,0.f};
  f32x4 ER = {0.f,0.f,0.f,0.f}, OR_ = {0.f,0.f,0.f,0.f};
  #pragma unroll
  for (int a = 0; a < 2; ++a) {
    int im = imA + a;
    if ((unsigned)im > 39u) continue;
    int ip = ipA - 2 * a;
    long rb = (long)(cc * 16 + ip * 4) * 1600 + im * 40;
    f32x4 l3 = *(const f32x4u*)(ZL + rb + 3 * 1600 + h - 1);
    f32x4 l1 = *(const f32x4u*)(ZL + rb + 1 * 1600 + h);
    f32x4 l2 = *(const f32x4u*)(ZL + rb + 2 * 1600 + h);
    f32x4 l0 = *(const f32x4u*)(ZL + rb + 0 * 1600 + h + 1);
    f32x4 r3 = *(const f32x4u*)(ZR + rb + 3 * 1600 + h - 1);
    f32x4 r1 = *(const f32x4u*)(ZR + rb + 1 * 1600 + h);
    f32x4 r2 = *(const f32x4u*)(ZR + rb + 2 * 1600 + h);
    f32x4 r0 = *(const f32x4u*)(ZR + rb + 0 * 1600 + h + 1);
    if (x0 == 0) { l3[0] = 0.f; r3[0] = 0.f; }    // jm=-1 invalid
    if (x0 == 72) { l0[3] = 0.f; r0[3] = 0.f; }   // jm=40 invalid
    EL += l3 + l1; OL += l2 + l0;
    ER += r3 + r1; OR_ += r2 + r0;
  }
  f32x4 o0, o1;
  #pragma unroll
  for (int k = 0; k < 4; ++k) {
    int xe = x0 + 2 * k, xo = xe + 1;
    float ce = cosf(PI_F * xe / 79.f);
    float co = cosf(PI_F * xo / 79.f);
    float ve = 0.25f * (0.5f * (1.f + ce) * EL[k] + 0.5f * (1.f - ce) * ER[k]);
    float vo = 0.25f * (0.5f * (1.f + co) * OL[k] + 0.5f * (1.f - co) * OR_[k]);
    if (k < 2) { o0[2 * k] = ve; o0[2 * k + 1] = vo; }
    else { o1[2 * (k - 2)] = ve; o1[2 * (k - 2) + 1] = vo; }
  }
  float* dst = out + (long)r * 80 + x0;
  *reinterpret_cast<f32x4*>(dst) = o0;
  *reinterpret_cast<f32x4*>(dst + 4) = o1;
}

// ---------------------------------------------------------------------------
extern "C" void kernel_launch(void* const* d_in, const int* in_sizes, int n_in,
                              void* d_out, int out_size, void* d_ws, size_t ws_size,
                              hipStream_t stream) {
  const float* left  = (const float*)d_in[0];
  const float* right = (const float*)d_in[1];
  const float* mid   = (const float*)d_in[2];
  const float* rawL  = (const float*)d_in[3];
  const float* rawR  = (const float*)d_in[4];
  float* out = (float*)d_out;
  char* ws = (char*)d_ws;

  bf16*  PTe   = (bf16*)(ws + 0);              // [4][1664][384] bf16 (hi|lo|hi)
  bf16*  MTe   = (bf16*)(ws + 5111808);        // [2][1664][384] bf16 (hi|hi|lo)
  float* SQ    = (float*)(ws + 7667712);       // [4][1600]
  float* INV   = (float*)(ws + 7693312);       // [4][1600]
  float* Pm    = (float*)(ws + 7718912);       // [4][8][1600]
  float* Ps    = (float*)(ws + 7923712);       // [4][8][1600]
  float* X     = (float*)(ws + 8179712);       // 52.4 MB pool: Gpad -> S3 -> Z
  float* Y     = (float*)(ws + 60608512);      // 41.0 MB pool: S2 -> RAWPT
  bf16*  AT    = (bf16*)(ws + 101568512);      // [4][1664][1600] bf16 (ends ~122.9MB)
  bf16*  RAWPT = (bf16*)Y;                     // overlay (26.2 MB <= 41.0 MB)

  prep_pt<<<dim3(1600, 6, 1), 128, 0, stream>>>(left, right, mid, PTe, MTe, SQ);
  pad_invn_kernel<<<dim3(1771, 4), 256, 0, stream>>>(X, SQ, INV);
  // Gram via three-term double-bf16 MFMA (K=384), writing padded 4D layout:
  gemm_nt<<<dim3(13, 13, 4), 256, 0, stream>>>(PTe, MTe, X, 1600, 1600, 384,
                                               1664L * 384, 1664L * 384, GPAD_Z, 1, 1);
  s1fuse1_fast<<<3200, 256, 0, stream>>>(X, INV, Y);             // Gpad -> S2 (qj 1..38)
  s1fuse1_slow<<<dim3(125, 4), 256, 0, stream>>>(X, INV, Y);     // qj in {0,39}
  fuse2_kernel<<<dim3(2500, 4), 256, 0, stream>>>(Y, X);         // S2 -> S3
  smax_part<<<dim3(25, 8, 4), 256, 0, stream>>>(X, Pm, Ps);
  smax_write<<<dim3(25, 25, 4), 256, 0, stream>>>(X, Pm, Ps, AT);   // S3 -> AT
  rawpt_kernel<<<dim3(25, 512, 4), 256, 0, stream>>>(rawL, rawR, RAWPT);  // S2 dead
  // Deconv GEMM: phase-aligned halves + spread staging + 1 barrier/phase
  gemm256_nt<<<dim3(8, 7, 4), 512, 0, stream>>>(RAWPT, AT, X, 2048, 1600, 1600,
                                                2048L * 1600, 1664L * 1600, 2048L * 1600, 1664);
  paste_kernel<<<800, 256, 0, stream>>>(X, out);
}